// Round 2
// baseline (825.435 us; speedup 1.0000x reference)
//
#include <hip/hip_runtime.h>
#include <hip/hip_bf16.h>

// Problem constants (from reference)
#define NN 50000
#define NE 1000000
#define FIN0 30
#define C 64
#define ED 11
#define NG 1024
#define DOUT 256

// ---------------- CSR build ----------------
__global__ void hist_kernel(const int* __restrict__ idx, int n, int* __restrict__ cnt){
  for(int i=blockIdx.x*blockDim.x+threadIdx.x;i<n;i+=gridDim.x*blockDim.x)
    atomicAdd(&cnt[idx[i]],1);
}

// single-block exclusive scan (n up to ~64k); also clones ptr into cursor
__global__ __launch_bounds__(1024) void scan_kernel(const int* __restrict__ cnt,
    int* __restrict__ ptr, int* __restrict__ cursor, int n){
  __shared__ int part[1024];
  int t=threadIdx.x;
  int chunk=(n+1023)>>10;
  int lo=t*chunk, hi=min(n,lo+chunk);
  int s=0;
  for(int i=lo;i<hi;++i) s+=cnt[i];
  part[t]=s;
  __syncthreads();
  for(int off=1;off<1024;off<<=1){
    int v=(t>=off)?part[t-off]:0;
    __syncthreads();
    part[t]+=v;
    __syncthreads();
  }
  int run=(t==0)?0:part[t-1];
  for(int i=lo;i<hi;++i){ ptr[i]=run; if(cursor) cursor[i]=run; run+=cnt[i]; }
  if(t==1023) ptr[n]=part[1023];
}

__global__ void scatter_kernel(const int* __restrict__ dst, int* __restrict__ cursor,
    int* __restrict__ csr, int n){
  for(int e=blockIdx.x*blockDim.x+threadIdx.x;e<n;e+=gridDim.x*blockDim.x){
    int pos=atomicAdd(&cursor[dst[e]],1);
    csr[pos]=e;
  }
}

// ---------------- per-layer: h = in@W, res = in@Wres + b, alpha dots ----------------
template<int FIN>
__global__ __launch_bounds__(256) void feat_kernel(const float* __restrict__ in,
    const float* __restrict__ W, const float* __restrict__ Wres,
    const float* __restrict__ bvec, const float* __restrict__ av_src,
    const float* __restrict__ av_dst,
    float* __restrict__ hW, float* __restrict__ outb,
    float* __restrict__ as_, float* __restrict__ ad_){
  __shared__ float sW[FIN*C], sR[FIN*C];
  __shared__ float sx[4*C];
  __shared__ float sb[C], ss[C], sd[C];
  int tid=threadIdx.x;
  if(tid<C){ sb[tid]=bvec[tid]; ss[tid]=av_src[tid]; sd[tid]=av_dst[tid]; }
  for(int i=tid;i<FIN*C;i+=256){ sW[i]=W[i]; sR[i]=Wres[i]; }
  int w=tid>>6, lane=tid&63;
  int nidx=blockIdx.x*4+w;
  if(nidx<NN){
    sx[w*C+lane]=(lane<FIN)?in[(size_t)nidx*FIN+lane]:0.f;
  }
  __syncthreads();
  if(nidx>=NN) return;
  float hw=0.f, hr=0.f;
  #pragma unroll
  for(int k=0;k<FIN;++k){
    float xv=sx[w*C+k];
    hw=fmaf(xv,sW[k*C+lane],hw);
    hr=fmaf(xv,sR[k*C+lane],hr);
  }
  hW[(size_t)nidx*C+lane]=hw;
  outb[(size_t)nidx*C+lane]=hr+sb[lane];
  float ps=hw*ss[lane], pd=hw*sd[lane];
  #pragma unroll
  for(int off=32;off;off>>=1){ ps+=__shfl_xor(ps,off,64); pd+=__shfl_xor(pd,off,64); }
  if(lane==0){ as_[nidx]=ps; ad_[nidx]=pd; }
}

// ---------------- per-layer: per-edge attention logit ----------------
__global__ __launch_bounds__(256) void alpha_kernel(const float* __restrict__ edge_attr,
    const float* __restrict__ We, const float* __restrict__ ae,
    const int* __restrict__ src, const int* __restrict__ dst,
    const float* __restrict__ as_, const float* __restrict__ ad_,
    float* __restrict__ alpha_e){
  __shared__ float sweae[ED];
  int tid=threadIdx.x;
  if(tid<ED){
    float s=0.f;
    for(int c=0;c<C;++c) s+=We[tid*C+c]*ae[c];
    sweae[tid]=s;
  }
  __syncthreads();
  for(int e=blockIdx.x*blockDim.x+tid;e<NE;e+=gridDim.x*blockDim.x){
    float ed=0.f;
    #pragma unroll
    for(int j=0;j<ED;++j) ed+=edge_attr[(size_t)e*ED+j]*sweae[j];
    float a=as_[src[e]]+ad_[dst[e]]+ed;
    alpha_e[e]=(a>0.f)?a:0.2f*a;  // leaky_relu 0.2
  }
}

// ---------------- per-layer: wave-per-dst-node online-softmax aggregation ----------------
__global__ __launch_bounds__(256) void agg_kernel(const int* __restrict__ rowptr,
    const int* __restrict__ csr, const int* __restrict__ src,
    const float* __restrict__ alpha_e, const float* __restrict__ hW,
    float* __restrict__ outb, int relu){
  int w=threadIdx.x>>6, lane=threadIdx.x&63;
  int nidx=blockIdx.x*4+w;
  if(nidx>=NN) return;
  int beg=rowptr[nidx], end=rowptr[nidx+1];
  float m=-INFINITY, s=0.f, acc=0.f;
  for(int base=beg;base<end;base+=64){
    int j=base+lane;
    float al=-INFINITY; int sl=0;
    if(j<end){ int eid=csr[j]; sl=src[eid]; al=alpha_e[eid]; }
    float cm=al;
    #pragma unroll
    for(int off=32;off;off>>=1) cm=fmaxf(cm,__shfl_xor(cm,off,64));
    float mn=fmaxf(m,cm);
    float scale=(m==-INFINITY)?0.f:__expf(m-mn);
    s*=scale; acc*=scale;
    float wl=(j<end)?__expf(al-mn):0.f;
    float cs=wl;
    #pragma unroll
    for(int off=32;off;off>>=1) cs+=__shfl_xor(cs,off,64);
    s+=cs; m=mn;
    int cnt=min(64,end-base);
    for(int t=0;t<cnt;++t){
      float at=__shfl(wl,t,64);
      int st=__shfl(sl,t,64);
      acc=fmaf(at,hW[(size_t)st*C+lane],acc);
    }
  }
  float val=acc/(s+1e-16f)+outb[(size_t)nidx*C+lane];
  if(relu) val=(val>0.f)?val:0.01f*val;
  outb[(size_t)nidx*C+lane]=val;
}

// ---------------- pooling (max + mean per graph) ----------------
__global__ __launch_bounds__(256) void pool_kernel(const float* __restrict__ h,
    const int* __restrict__ growptr, float* __restrict__ pooled){
  int w=threadIdx.x>>6, lane=threadIdx.x&63;
  int g=blockIdx.x*4+w;
  if(g>=NG) return;
  int beg=growptr[g], end=growptr[g+1];
  float mx=-INFINITY, sm=0.f;
  for(int n=beg;n<end;++n){ float v=h[(size_t)n*C+lane]; mx=fmaxf(mx,v); sm+=v; }
  int cnt=end-beg;
  float gm=(cnt==0)?0.f:mx;              // isfinite fix for empty graphs
  float mean=sm/fmaxf((float)cnt,1.f);
  gm=(gm>0.f)?gm:0.01f*gm;               // leaky_relu 0.01 on pooled
  mean=(mean>0.f)?mean:0.01f*mean;
  pooled[(size_t)g*128+lane]=gm;
  pooled[(size_t)g*128+64+lane]=mean;
}

// ---------------- final linear: [G,128] @ [128,256] + bias -> f32 out ----------------
__global__ __launch_bounds__(256) void out_kernel(const float* __restrict__ pooled,
    const float* __restrict__ Wout, const float* __restrict__ bout,
    float* __restrict__ out){
  __shared__ float sp[128];
  int g=blockIdx.x, d=threadIdx.x;
  if(d<128) sp[d]=pooled[(size_t)g*128+d];
  __syncthreads();
  float o=bout[d];
  for(int k=0;k<128;++k) o=fmaf(sp[k],Wout[k*DOUT+d],o);
  out[(size_t)g*DOUT+d]=o;
}

extern "C" void kernel_launch(void* const* d_in, const int* in_sizes, int n_in,
                              void* d_out, int out_size, void* d_ws, size_t ws_size,
                              hipStream_t stream){
  const float* x        =(const float*)d_in[0];
  const float* edge_attr=(const float*)d_in[1];
  const float* W0       =(const float*)d_in[2];
  const float* asrc0    =(const float*)d_in[3];
  const float* adst0    =(const float*)d_in[4];
  const float* We0      =(const float*)d_in[5];
  const float* ae0      =(const float*)d_in[6];
  const float* Wres0    =(const float*)d_in[7];
  const float* b0       =(const float*)d_in[8];
  const float* W        =(const float*)d_in[9];
  const float* asrc     =(const float*)d_in[10];
  const float* adst     =(const float*)d_in[11];
  const float* We       =(const float*)d_in[12];
  const float* ae       =(const float*)d_in[13];
  const float* Wres     =(const float*)d_in[14];
  const float* b        =(const float*)d_in[15];
  const float* Wout     =(const float*)d_in[16];
  const float* bout     =(const float*)d_in[17];
  const int* edge_index =(const int*)d_in[18];
  const int* batch_index=(const int*)d_in[19];
  const int* src=edge_index;
  const int* dst=edge_index+NE;

  // workspace carve (~48 MB total)
  char* p=(char*)d_ws;
  auto take=[&](size_t bytes)->void*{ void* r=(void*)p; p+=(bytes+255)&~(size_t)255; return r; };
  int* deg     =(int*)take((size_t)NN*4);
  int* rowptr  =(int*)take((size_t)(NN+1)*4);
  int* cursor  =(int*)take((size_t)NN*4);
  int* gcnt    =(int*)take((size_t)NG*4);
  int* growptr =(int*)take((size_t)(NG+1)*4);
  int* csr     =(int*)take((size_t)NE*4);
  float* as_   =(float*)take((size_t)NN*4);
  float* ad_   =(float*)take((size_t)NN*4);
  float* alpha_e=(float*)take((size_t)NE*4);
  float* hW    =(float*)take((size_t)NN*C*4);
  float* bufA  =(float*)take((size_t)NN*C*4);
  float* bufB  =(float*)take((size_t)NN*C*4);
  float* pooled=(float*)take((size_t)NG*128*4);
  (void)ws_size; (void)in_sizes; (void)n_in; (void)out_size;

  hipMemsetAsync(deg,0,(size_t)NN*4,stream);
  hipMemsetAsync(gcnt,0,(size_t)NG*4,stream);
  hist_kernel<<<2048,256,0,stream>>>(dst,NE,deg);
  hist_kernel<<<256,256,0,stream>>>(batch_index,NN,gcnt);
  scan_kernel<<<1,1024,0,stream>>>(deg,rowptr,cursor,NN);
  scan_kernel<<<1,1024,0,stream>>>(gcnt,growptr,nullptr,NG);
  scatter_kernel<<<2048,256,0,stream>>>(dst,cursor,csr,NE);

  const int nblk=(NN+3)/4;
  // layer 0 (F=30)
  feat_kernel<FIN0><<<nblk,256,0,stream>>>(x,W0,Wres0,b0,asrc0,adst0,hW,bufA,as_,ad_);
  alpha_kernel<<<2048,256,0,stream>>>(edge_attr,We0,ae0,src,dst,as_,ad_,alpha_e);
  agg_kernel<<<nblk,256,0,stream>>>(rowptr,csr,src,alpha_e,hW,bufA,1);
  // layers 1..3 (f32 ping-pong buffers)
  float* bin=bufA; float* bo=bufB;
  for(int i=0;i<3;++i){
    feat_kernel<C><<<nblk,256,0,stream>>>(bin,W+(size_t)i*C*C,Wres+(size_t)i*C*C,
        b+(size_t)i*C,asrc+(size_t)i*C,adst+(size_t)i*C,hW,bo,as_,ad_);
    alpha_kernel<<<2048,256,0,stream>>>(edge_attr,We+(size_t)i*ED*C,ae+(size_t)i*C,
        src,dst,as_,ad_,alpha_e);
    agg_kernel<<<nblk,256,0,stream>>>(rowptr,csr,src,alpha_e,hW,bo,(i<2)?1:0);
    float* t=bin; bin=bo; bo=t;
  }
  // bin now holds final node features
  pool_kernel<<<(NG+3)/4,256,0,stream>>>(bin,growptr,pooled);
  out_kernel<<<NG,256,0,stream>>>(pooled,Wout,bout,(float*)d_out);
}

// Round 3
// 676.899 us; speedup vs baseline: 1.2194x; 1.2194x over previous
//
#include <hip/hip_runtime.h>

// Problem constants (from reference)
#define NN 50000
#define NE 1000000
#define FIN0 30
#define C 64
#define ED 11
#define NG 1024
#define DOUT 256

// ---------------- CSR build ----------------
__global__ void hist_kernel(const int* __restrict__ idx, int n, int* __restrict__ cnt){
  for(int i=blockIdx.x*blockDim.x+threadIdx.x;i<n;i+=gridDim.x*blockDim.x)
    atomicAdd(&cnt[idx[i]],1);
}

// 3-stage multi-block exclusive scan over n elements (tile = 256)
__global__ __launch_bounds__(256) void scan_part(const int* __restrict__ cnt, int n,
    int* __restrict__ bsum){
  int t=threadIdx.x, i=blockIdx.x*256+t;
  int v=(i<n)?cnt[i]:0;
  #pragma unroll
  for(int off=32;off;off>>=1) v+=__shfl_xor(v,off,64);
  __shared__ int ws[4];
  if((t&63)==0) ws[t>>6]=v;
  __syncthreads();
  if(t==0) bsum[blockIdx.x]=ws[0]+ws[1]+ws[2]+ws[3];
}

__global__ __launch_bounds__(256) void scan_top(int* __restrict__ bsum, int nb){
  __shared__ int p[256];
  int t=threadIdx.x;
  int v=(t<nb)?bsum[t]:0;
  p[t]=v; __syncthreads();
  #pragma unroll
  for(int off=1;off<256;off<<=1){
    int u=(t>=off)?p[t-off]:0;
    __syncthreads(); p[t]+=u; __syncthreads();
  }
  if(t<nb) bsum[t]=p[t]-v;   // exclusive block offsets
}

__global__ __launch_bounds__(256) void scan_final(const int* __restrict__ cnt,
    const int* __restrict__ boff, int n, int* __restrict__ ptr, int* __restrict__ cursor){
  int t=threadIdx.x, b=blockIdx.x, i=b*256+t;
  int v=(i<n)?cnt[i]:0;
  __shared__ int p[256];
  p[t]=v; __syncthreads();
  #pragma unroll
  for(int off=1;off<256;off<<=1){
    int u=(t>=off)?p[t-off]:0;
    __syncthreads(); p[t]+=u; __syncthreads();
  }
  int ex=boff[b]+p[t]-v;
  if(i<n){
    ptr[i]=ex;
    if(cursor) cursor[i]=ex;
    if(i==n-1) ptr[n]=ex+v;
  }
}

__global__ void scatter_kernel(const int* __restrict__ dst, int* __restrict__ cursor,
    int* __restrict__ csr, int n){
  for(int e=blockIdx.x*blockDim.x+threadIdx.x;e<n;e+=gridDim.x*blockDim.x){
    int pos=atomicAdd(&cursor[dst[e]],1);
    csr[pos]=e;
  }
}

// ---------------- edge_attr dot for ALL 4 layers, one coalesced pass ----------------
// ed4[e*4+l] = edge_attr[e,:] . (We_l @ ae_l)
__global__ __launch_bounds__(256) void edprep_kernel(const float* __restrict__ edge_attr,
    const float* __restrict__ We0, const float* __restrict__ ae0,
    const float* __restrict__ We,  const float* __restrict__ ae,
    float* __restrict__ ed4){
  __shared__ float sw[4][ED];
  __shared__ float tile[256*ED];
  int t=threadIdx.x;
  if(t<4*ED){
    int l=t/ED, j=t%ED;
    const float* wp=(l==0)? (We0+(size_t)j*C) : (We+((size_t)(l-1)*ED+j)*C);
    const float* ap=(l==0)? ae0 : (ae+(size_t)(l-1)*C);
    float s=0.f;
    for(int c=0;c<C;++c) s+=wp[c]*ap[c];
    sw[l][j]=s;
  }
  __syncthreads();
  size_t e0=(size_t)blockIdx.x*256;
  int cnt=(int)min((size_t)256,(size_t)NE-e0);
  for(int i=t;i<cnt*ED;i+=256) tile[i]=edge_attr[e0*ED+i];
  __syncthreads();
  if(t<cnt){
    float4 r;
    float d0=0,d1=0,d2=0,d3=0;
    #pragma unroll
    for(int j=0;j<ED;++j){
      float ev=tile[t*ED+j];
      d0=fmaf(ev,sw[0][j],d0);
      d1=fmaf(ev,sw[1][j],d1);
      d2=fmaf(ev,sw[2][j],d2);
      d3=fmaf(ev,sw[3][j],d3);
    }
    r.x=d0; r.y=d1; r.z=d2; r.w=d3;
    *(float4*)&ed4[(e0+t)*4]=r;
  }
}

// ---------------- reorder src + ed into CSR (dst-row) order ----------------
__global__ void reorder_kernel(const int* __restrict__ csr, const int* __restrict__ src,
    const float* __restrict__ ed4, int* __restrict__ src_csr, float* __restrict__ edc){
  for(int j=blockIdx.x*blockDim.x+threadIdx.x;j<NE;j+=gridDim.x*blockDim.x){
    int eid=csr[j];
    src_csr[j]=src[eid];
    float4 v=*(const float4*)&ed4[(size_t)eid*4];
    edc[j]=v.x; edc[NE+j]=v.y; edc[2*(size_t)NE+j]=v.z; edc[3*(size_t)NE+j]=v.w;
  }
}

// ---------------- per-layer: h = in@W, res = in@Wres + b, alpha dots ----------------
template<int FIN>
__global__ __launch_bounds__(256) void feat_kernel(const float* __restrict__ in,
    const float* __restrict__ W, const float* __restrict__ Wres,
    const float* __restrict__ bvec, const float* __restrict__ av_src,
    const float* __restrict__ av_dst,
    float* __restrict__ hW, float* __restrict__ outb,
    float* __restrict__ as_, float* __restrict__ ad_){
  __shared__ float sW[FIN*C], sR[FIN*C];
  __shared__ float sx[4*C];
  __shared__ float sb[C], ss[C], sd[C];
  int tid=threadIdx.x;
  if(tid<C){ sb[tid]=bvec[tid]; ss[tid]=av_src[tid]; sd[tid]=av_dst[tid]; }
  for(int i=tid;i<FIN*C;i+=256){ sW[i]=W[i]; sR[i]=Wres[i]; }
  int w=tid>>6, lane=tid&63;
  int nidx=blockIdx.x*4+w;
  if(nidx<NN){
    sx[w*C+lane]=(lane<FIN)?in[(size_t)nidx*FIN+lane]:0.f;
  }
  __syncthreads();
  if(nidx>=NN) return;
  float hw=0.f, hr=0.f;
  #pragma unroll
  for(int k=0;k<FIN;++k){
    float xv=sx[w*C+k];
    hw=fmaf(xv,sW[k*C+lane],hw);
    hr=fmaf(xv,sR[k*C+lane],hr);
  }
  hW[(size_t)nidx*C+lane]=hw;
  outb[(size_t)nidx*C+lane]=hr+sb[lane];
  float ps=hw*ss[lane], pd=hw*sd[lane];
  #pragma unroll
  for(int off=32;off;off>>=1){ ps+=__shfl_xor(ps,off,64); pd+=__shfl_xor(pd,off,64); }
  if(lane==0){ as_[nidx]=ps; ad_[nidx]=pd; }
}

// ------- fused alpha + online-softmax aggregation: one wave per dst node -------
__global__ __launch_bounds__(256) void agg_kernel(const int* __restrict__ rowptr,
    const int* __restrict__ src_csr, const float* __restrict__ edc_l,
    const float* __restrict__ as_, const float* __restrict__ ad_,
    const float* __restrict__ hW, float* __restrict__ outb, int relu){
  int w=threadIdx.x>>6, lane=threadIdx.x&63;
  int nidx=blockIdx.x*4+w;
  if(nidx>=NN) return;
  int beg=rowptr[nidx], end=rowptr[nidx+1];
  float ad_n=ad_[nidx];
  float m=-INFINITY, s=0.f, acc=0.f;
  for(int base=beg;base<end;base+=64){
    int j=base+lane;
    float al=-INFINITY; int sl=0;
    if(j<end){
      sl=src_csr[j];
      float a=as_[sl]+ad_n+edc_l[j];
      al=(a>0.f)?a:0.2f*a;            // leaky_relu 0.2
    }
    float cm=al;
    #pragma unroll
    for(int off=32;off;off>>=1) cm=fmaxf(cm,__shfl_xor(cm,off,64));
    float mn=fmaxf(m,cm);
    float scale=(m==-INFINITY)?0.f:__expf(m-mn);
    s*=scale; acc*=scale;
    float wl=(j<end)?__expf(al-mn):0.f;
    float cs=wl;
    #pragma unroll
    for(int off=32;off;off>>=1) cs+=__shfl_xor(cs,off,64);
    s+=cs; m=mn;
    int cnt=min(64,end-base);
    for(int t=0;t<cnt;++t){
      float at=__shfl(wl,t,64);
      int st=__shfl(sl,t,64);
      acc=fmaf(at,hW[(size_t)st*C+lane],acc);
    }
  }
  float val=acc/(s+1e-16f)+outb[(size_t)nidx*C+lane];
  if(relu) val=(val>0.f)?val:0.01f*val;
  outb[(size_t)nidx*C+lane]=val;
}

// ---------------- pooling (max + mean per graph) ----------------
__global__ __launch_bounds__(256) void pool_kernel(const float* __restrict__ h,
    const int* __restrict__ growptr, float* __restrict__ pooled){
  int w=threadIdx.x>>6, lane=threadIdx.x&63;
  int g=blockIdx.x*4+w;
  if(g>=NG) return;
  int beg=growptr[g], end=growptr[g+1];
  float mx=-INFINITY, sm=0.f;
  for(int n=beg;n<end;++n){ float v=h[(size_t)n*C+lane]; mx=fmaxf(mx,v); sm+=v; }
  int cnt=end-beg;
  float gm=(cnt==0)?0.f:mx;              // isfinite fix for empty graphs
  float mean=sm/fmaxf((float)cnt,1.f);
  gm=(gm>0.f)?gm:0.01f*gm;               // leaky_relu 0.01 on pooled
  mean=(mean>0.f)?mean:0.01f*mean;
  pooled[(size_t)g*128+lane]=gm;
  pooled[(size_t)g*128+64+lane]=mean;
}

// ---------------- final linear: [G,128] @ [128,256] + bias ----------------
__global__ __launch_bounds__(256) void out_kernel(const float* __restrict__ pooled,
    const float* __restrict__ Wout, const float* __restrict__ bout,
    float* __restrict__ out){
  __shared__ float sp[128];
  int g=blockIdx.x, d=threadIdx.x;
  if(d<128) sp[d]=pooled[(size_t)g*128+d];
  __syncthreads();
  float o=bout[d];
  for(int k=0;k<128;++k) o=fmaf(sp[k],Wout[k*DOUT+d],o);
  out[(size_t)g*DOUT+d]=o;
}

extern "C" void kernel_launch(void* const* d_in, const int* in_sizes, int n_in,
                              void* d_out, int out_size, void* d_ws, size_t ws_size,
                              hipStream_t stream){
  const float* x        =(const float*)d_in[0];
  const float* edge_attr=(const float*)d_in[1];
  const float* W0       =(const float*)d_in[2];
  const float* asrc0    =(const float*)d_in[3];
  const float* adst0    =(const float*)d_in[4];
  const float* We0      =(const float*)d_in[5];
  const float* ae0      =(const float*)d_in[6];
  const float* Wres0    =(const float*)d_in[7];
  const float* b0       =(const float*)d_in[8];
  const float* W        =(const float*)d_in[9];
  const float* asrc     =(const float*)d_in[10];
  const float* adst     =(const float*)d_in[11];
  const float* We       =(const float*)d_in[12];
  const float* ae       =(const float*)d_in[13];
  const float* Wres     =(const float*)d_in[14];
  const float* b        =(const float*)d_in[15];
  const float* Wout     =(const float*)d_in[16];
  const float* bout     =(const float*)d_in[17];
  const int* edge_index =(const int*)d_in[18];
  const int* batch_index=(const int*)d_in[19];
  const int* src=edge_index;
  const int* dst=edge_index+NE;

  // workspace carve (~64 MB)
  char* p=(char*)d_ws;
  auto take=[&](size_t bytes)->void*{ void* r=(void*)p; p+=(bytes+255)&~(size_t)255; return r; };
  int* deg     =(int*)take((size_t)NN*4);
  int* rowptr  =(int*)take((size_t)(NN+1)*4);
  int* cursor  =(int*)take((size_t)NN*4);
  int* gcnt    =(int*)take((size_t)NG*4);
  int* growptr =(int*)take((size_t)(NG+1)*4);
  int* bsumN   =(int*)take((size_t)256*4);
  int* bsumG   =(int*)take((size_t)256*4);
  int* csr     =(int*)take((size_t)NE*4);
  int* src_csr =(int*)take((size_t)NE*4);
  float* as_   =(float*)take((size_t)NN*4);
  float* ad_   =(float*)take((size_t)NN*4);
  float* edc   =(float*)take((size_t)NE*4*4);   // 4 layers x NE, CSR order
  float* hW    =(float*)take((size_t)NN*C*4);
  float* bufA  =(float*)take((size_t)NN*C*4);
  float* bufB  =(float*)take((size_t)NN*C*4);
  float* pooled=(float*)take((size_t)NG*128*4);
  // ed4 (16 MB, dead after reorder) aliases hW+bufA (written only later)
  float* ed4   =hW;
  (void)ws_size; (void)in_sizes; (void)n_in; (void)out_size;

  hipMemsetAsync(deg,0,(size_t)NN*4,stream);
  hipMemsetAsync(gcnt,0,(size_t)NG*4,stream);
  hist_kernel<<<2048,256,0,stream>>>(dst,NE,deg);
  hist_kernel<<<256,256,0,stream>>>(batch_index,NN,gcnt);

  const int nbN=(NN+255)/256;      // 196
  const int nbG=(NG+255)/256;      // 4
  scan_part<<<nbN,256,0,stream>>>(deg,NN,bsumN);
  scan_top<<<1,256,0,stream>>>(bsumN,nbN);
  scan_final<<<nbN,256,0,stream>>>(deg,bsumN,NN,rowptr,cursor);
  scan_part<<<nbG,256,0,stream>>>(gcnt,NG,bsumG);
  scan_top<<<1,256,0,stream>>>(bsumG,nbG);
  scan_final<<<nbG,256,0,stream>>>(gcnt,bsumG,NG,growptr,nullptr);

  scatter_kernel<<<2048,256,0,stream>>>(dst,cursor,csr,NE);
  edprep_kernel<<<(NE+255)/256,256,0,stream>>>(edge_attr,We0,ae0,We,ae,ed4);
  reorder_kernel<<<2048,256,0,stream>>>(csr,src,ed4,src_csr,edc);

  const int nblk=(NN+3)/4;
  // layer 0 (F=30)
  feat_kernel<FIN0><<<nblk,256,0,stream>>>(x,W0,Wres0,b0,asrc0,adst0,hW,bufA,as_,ad_);
  agg_kernel<<<nblk,256,0,stream>>>(rowptr,src_csr,edc,as_,ad_,hW,bufA,1);
  // layers 1..3 (ping-pong)
  float* bin=bufA; float* bo=bufB;
  for(int i=0;i<3;++i){
    feat_kernel<C><<<nblk,256,0,stream>>>(bin,W+(size_t)i*C*C,Wres+(size_t)i*C*C,
        b+(size_t)i*C,asrc+(size_t)i*C,adst+(size_t)i*C,hW,bo,as_,ad_);
    agg_kernel<<<nblk,256,0,stream>>>(rowptr,src_csr,edc+(size_t)(i+1)*NE,as_,ad_,hW,bo,(i<2)?1:0);
    float* t=bin; bin=bo; bo=t;
  }
  pool_kernel<<<(NG+3)/4,256,0,stream>>>(bin,growptr,pooled);
  out_kernel<<<NG,256,0,stream>>>(pooled,Wout,bout,(float*)d_out);
}

// Round 4
// 543.246 us; speedup vs baseline: 1.5195x; 1.2460x over previous
//
#include <hip/hip_runtime.h>
#include <hip/hip_fp16.h>

// Problem constants (from reference)
#define NN 50000
#define NE 1000000
#define FIN0 30
#define C 64
#define ED 11
#define NG 1024
#define DOUT 256

typedef unsigned long long ull;

// ---------------- CSR build ----------------
__global__ void hist_kernel(const int* __restrict__ idx, int n, int* __restrict__ cnt){
  for(int i=blockIdx.x*blockDim.x+threadIdx.x;i<n;i+=gridDim.x*blockDim.x)
    atomicAdd(&cnt[idx[i]],1);
}

// 3-stage multi-block exclusive scan over n elements (tile = 256)
__global__ __launch_bounds__(256) void scan_part(const int* __restrict__ cnt, int n,
    int* __restrict__ bsum){
  int t=threadIdx.x, i=blockIdx.x*256+t;
  int v=(i<n)?cnt[i]:0;
  #pragma unroll
  for(int off=32;off;off>>=1) v+=__shfl_xor(v,off,64);
  __shared__ int ws[4];
  if((t&63)==0) ws[t>>6]=v;
  __syncthreads();
  if(t==0) bsum[blockIdx.x]=ws[0]+ws[1]+ws[2]+ws[3];
}

__global__ __launch_bounds__(256) void scan_top(int* __restrict__ bsum, int nb){
  __shared__ int p[256];
  int t=threadIdx.x;
  int v=(t<nb)?bsum[t]:0;
  p[t]=v; __syncthreads();
  #pragma unroll
  for(int off=1;off<256;off<<=1){
    int u=(t>=off)?p[t-off]:0;
    __syncthreads(); p[t]+=u; __syncthreads();
  }
  if(t<nb) bsum[t]=p[t]-v;   // exclusive block offsets
}

__global__ __launch_bounds__(256) void scan_final(const int* __restrict__ cnt,
    const int* __restrict__ boff, int n, int* __restrict__ ptr, int* __restrict__ cursor){
  int t=threadIdx.x, b=blockIdx.x, i=b*256+t;
  int v=(i<n)?cnt[i]:0;
  __shared__ int p[256];
  p[t]=v; __syncthreads();
  #pragma unroll
  for(int off=1;off<256;off<<=1){
    int u=(t>=off)?p[t-off]:0;
    __syncthreads(); p[t]+=u; __syncthreads();
  }
  int ex=boff[b]+p[t]-v;
  if(i<n){
    ptr[i]=ex;
    if(cursor) cursor[i]=ex;
    if(i==n-1) ptr[n]=ex+v;
  }
}

// scatter (eid, src) pair -> csr position (8B payload, same line traffic as 4B)
__global__ void scatter_kernel(const int* __restrict__ dst, const int* __restrict__ src,
    int* __restrict__ cursor, ull* __restrict__ csrp, int n){
  for(int e=blockIdx.x*blockDim.x+threadIdx.x;e<n;e+=gridDim.x*blockDim.x){
    int pos=atomicAdd(&cursor[dst[e]],1);
    csrp[pos]=((ull)(unsigned)e<<32)|(unsigned)src[e];
  }
}

// ---------------- edge_attr dot for ALL 4 layers, one coalesced pass ----------------
__global__ __launch_bounds__(256) void edprep_kernel(const float* __restrict__ edge_attr,
    const float* __restrict__ We0, const float* __restrict__ ae0,
    const float* __restrict__ We,  const float* __restrict__ ae,
    float* __restrict__ ed4){
  __shared__ float sw[4][ED];
  __shared__ float tile[256*ED];
  int t=threadIdx.x;
  if(t<4*ED){
    int l=t/ED, j=t%ED;
    const float* wp=(l==0)? (We0+(size_t)j*C) : (We+((size_t)(l-1)*ED+j)*C);
    const float* ap=(l==0)? ae0 : (ae+(size_t)(l-1)*C);
    float s=0.f;
    for(int c=0;c<C;++c) s+=wp[c]*ap[c];
    sw[l][j]=s;
  }
  __syncthreads();
  size_t e0=(size_t)blockIdx.x*256;
  int cnt=(int)min((size_t)256,(size_t)NE-e0);
  for(int i=t;i<cnt*ED;i+=256) tile[i]=edge_attr[e0*ED+i];
  __syncthreads();
  if(t<cnt){
    float4 r;
    float d0=0,d1=0,d2=0,d3=0;
    #pragma unroll
    for(int j=0;j<ED;++j){
      float ev=tile[t*ED+j];
      d0=fmaf(ev,sw[0][j],d0);
      d1=fmaf(ev,sw[1][j],d1);
      d2=fmaf(ev,sw[2][j],d2);
      d3=fmaf(ev,sw[3][j],d3);
    }
    r.x=d0; r.y=d1; r.z=d2; r.w=d3;
    *(float4*)&ed4[(e0+t)*4]=r;
  }
}

// ---------------- reorder ed into CSR order; src comes free from the pair ----------------
__global__ void reorder_kernel(const ull* __restrict__ csrp,
    const float* __restrict__ ed4, int* __restrict__ src_csr, float* __restrict__ edc){
  for(int j=blockIdx.x*blockDim.x+threadIdx.x;j<NE;j+=gridDim.x*blockDim.x){
    ull pr=csrp[j];
    int eid=(int)(pr>>32);
    src_csr[j]=(int)(pr&0xffffffffu);
    float4 v=*(const float4*)&ed4[(size_t)eid*4];
    edc[j]=v.x; edc[NE+j]=v.y; edc[2*(size_t)NE+j]=v.z; edc[3*(size_t)NE+j]=v.w;
  }
}

// ---------------- per-layer: h = in@W (->f16), res = in@Wres + b, alpha dots ----------------
// 64 nodes per block: stage weights ONCE, iterate 16x with 4 waves.
template<int FIN>
__global__ __launch_bounds__(256) void feat_kernel(const float* __restrict__ in,
    const float* __restrict__ W, const float* __restrict__ Wres,
    const float* __restrict__ bvec, const float* __restrict__ av_src,
    const float* __restrict__ av_dst,
    __half* __restrict__ hW16, float* __restrict__ outb,
    float* __restrict__ as_, float* __restrict__ ad_){
  __shared__ float sW[FIN*C], sR[FIN*C];
  __shared__ float sx[4*C];
  __shared__ float sb[C], ss[C], sd[C];
  int tid=threadIdx.x;
  if(tid<C){ sb[tid]=bvec[tid]; ss[tid]=av_src[tid]; sd[tid]=av_dst[tid]; }
  for(int i=tid;i<FIN*C;i+=256){ sW[i]=W[i]; sR[i]=Wres[i]; }
  __syncthreads();
  int w=tid>>6, lane=tid&63;
  for(int it=0;it<16;++it){
    int nidx=blockIdx.x*64+it*4+w;
    if(nidx>=NN) continue;             // wave-uniform
    // wave-private LDS slice: no barrier needed
    sx[w*C+lane]=(lane<FIN)?in[(size_t)nidx*FIN+lane]:0.f;
    float hw=0.f, hr=0.f;
    #pragma unroll
    for(int k=0;k<FIN;++k){
      float xv=sx[w*C+k];
      hw=fmaf(xv,sW[k*C+lane],hw);
      hr=fmaf(xv,sR[k*C+lane],hr);
    }
    hW16[(size_t)nidx*C+lane]=__float2half(hw);
    outb[(size_t)nidx*C+lane]=hr+sb[lane];
    float ps=hw*ss[lane], pd=hw*sd[lane];
    #pragma unroll
    for(int off=32;off;off>>=1){ ps+=__shfl_xor(ps,off,64); pd+=__shfl_xor(pd,off,64); }
    if(lane==0){ as_[nidx]=ps; ad_[nidx]=pd; }
  }
}

// ------- fused alpha + online-softmax aggregation -------
// wave per dst node; inner loop: group g=lane>>4 takes edge t+g, lane&15 owns 4 f16 channels
__global__ __launch_bounds__(256) void agg_kernel(const int* __restrict__ rowptr,
    const int* __restrict__ src_csr, const float* __restrict__ edc_l,
    const float* __restrict__ as_, const float* __restrict__ ad_,
    const __half* __restrict__ hW16, float* __restrict__ outb, int relu){
  int w=threadIdx.x>>6, lane=threadIdx.x&63;
  int nidx=blockIdx.x*4+w;
  if(nidx>=NN) return;
  int beg=rowptr[nidx], end=rowptr[nidx+1];
  float ad_n=ad_[nidx];
  int g=lane>>4, gl=lane&15;
  const uint2* hw2=(const uint2*)hW16;   // 4 halves per uint2; row = 16 uint2
  float m=-INFINITY, s=0.f;
  float ax=0.f, ay=0.f, az=0.f, aw=0.f;
  for(int base=beg;base<end;base+=64){
    int j=base+lane;
    float al=-INFINITY; int sl=0; float wl;
    if(j<end){
      sl=src_csr[j];
      float a=as_[sl]+ad_n+edc_l[j];
      al=(a>0.f)?a:0.2f*a;               // leaky_relu 0.2
    }
    float cm=al;
    #pragma unroll
    for(int off=32;off;off>>=1) cm=fmaxf(cm,__shfl_xor(cm,off,64));
    float mn=fmaxf(m,cm);
    float scale=(m==-INFINITY)?0.f:__expf(m-mn);
    s*=scale; ax*=scale; ay*=scale; az*=scale; aw*=scale;
    wl=(j<end)?__expf(al-mn):0.f;
    float cs=wl;
    #pragma unroll
    for(int off=32;off;off>>=1) cs+=__shfl_xor(cs,off,64);
    s+=cs; m=mn;
    int cnt=min(64,end-base);
    for(int t=0;t<cnt;t+=4){
      int tt=t+g;                         // invalid tails have wl==0 -> add 0
      float at=__shfl(wl,tt,64);
      int   st=__shfl(sl,tt,64);
      uint2 u=hw2[(size_t)st*16+gl];
      __half2 h0=*(__half2*)&u.x;
      __half2 h1=*(__half2*)&u.y;
      float2 f0=__half22float2(h0);
      float2 f1=__half22float2(h1);
      ax=fmaf(at,f0.x,ax);
      ay=fmaf(at,f0.y,ay);
      az=fmaf(at,f1.x,az);
      aw=fmaf(at,f1.y,aw);
    }
  }
  // combine the 4 groups: lanes l, l+16, l+32, l+48 hold same channels
  #pragma unroll
  for(int off=16;off<64;off<<=1){
    ax+=__shfl_xor(ax,off,64);
    ay+=__shfl_xor(ay,off,64);
    az+=__shfl_xor(az,off,64);
    aw+=__shfl_xor(aw,off,64);
  }
  if(g==0){
    float inv=s+1e-16f;
    float4 o=*(float4*)&outb[(size_t)nidx*C+gl*4];
    float4 v;
    v.x=ax/inv+o.x; v.y=ay/inv+o.y; v.z=az/inv+o.z; v.w=aw/inv+o.w;
    if(relu){
      v.x=(v.x>0.f)?v.x:0.01f*v.x;
      v.y=(v.y>0.f)?v.y:0.01f*v.y;
      v.z=(v.z>0.f)?v.z:0.01f*v.z;
      v.w=(v.w>0.f)?v.w:0.01f*v.w;
    }
    *(float4*)&outb[(size_t)nidx*C+gl*4]=v;
  }
}

// ---------------- pooling (max + mean per graph) ----------------
__global__ __launch_bounds__(256) void pool_kernel(const float* __restrict__ h,
    const int* __restrict__ growptr, float* __restrict__ pooled){
  int w=threadIdx.x>>6, lane=threadIdx.x&63;
  int g=blockIdx.x*4+w;
  if(g>=NG) return;
  int beg=growptr[g], end=growptr[g+1];
  float mx=-INFINITY, sm=0.f;
  for(int n=beg;n<end;++n){ float v=h[(size_t)n*C+lane]; mx=fmaxf(mx,v); sm+=v; }
  int cnt=end-beg;
  float gm=(cnt==0)?0.f:mx;              // isfinite fix for empty graphs
  float mean=sm/fmaxf((float)cnt,1.f);
  gm=(gm>0.f)?gm:0.01f*gm;               // leaky_relu 0.01 on pooled
  mean=(mean>0.f)?mean:0.01f*mean;
  pooled[(size_t)g*128+lane]=gm;
  pooled[(size_t)g*128+64+lane]=mean;
}

// ---------------- final linear: [G,128] @ [128,256] + bias ----------------
__global__ __launch_bounds__(256) void out_kernel(const float* __restrict__ pooled,
    const float* __restrict__ Wout, const float* __restrict__ bout,
    float* __restrict__ out){
  __shared__ float sp[128];
  int g=blockIdx.x, d=threadIdx.x;
  if(d<128) sp[d]=pooled[(size_t)g*128+d];
  __syncthreads();
  float o=bout[d];
  for(int k=0;k<128;++k) o=fmaf(sp[k],Wout[k*DOUT+d],o);
  out[(size_t)g*DOUT+d]=o;
}

extern "C" void kernel_launch(void* const* d_in, const int* in_sizes, int n_in,
                              void* d_out, int out_size, void* d_ws, size_t ws_size,
                              hipStream_t stream){
  const float* x        =(const float*)d_in[0];
  const float* edge_attr=(const float*)d_in[1];
  const float* W0       =(const float*)d_in[2];
  const float* asrc0    =(const float*)d_in[3];
  const float* adst0    =(const float*)d_in[4];
  const float* We0      =(const float*)d_in[5];
  const float* ae0      =(const float*)d_in[6];
  const float* Wres0    =(const float*)d_in[7];
  const float* b0       =(const float*)d_in[8];
  const float* W        =(const float*)d_in[9];
  const float* asrc     =(const float*)d_in[10];
  const float* adst     =(const float*)d_in[11];
  const float* We       =(const float*)d_in[12];
  const float* ae       =(const float*)d_in[13];
  const float* Wres     =(const float*)d_in[14];
  const float* b        =(const float*)d_in[15];
  const float* Wout     =(const float*)d_in[16];
  const float* bout     =(const float*)d_in[17];
  const int* edge_index =(const int*)d_in[18];
  const int* batch_index=(const int*)d_in[19];
  const int* src=edge_index;
  const int* dst=edge_index+NE;

  // workspace carve (~62 MB)
  char* p=(char*)d_ws;
  auto take=[&](size_t bytes)->void*{ void* r=(void*)p; p+=(bytes+255)&~(size_t)255; return r; };
  int* deg     =(int*)take((size_t)NN*4);
  int* rowptr  =(int*)take((size_t)(NN+1)*4);
  int* cursor  =(int*)take((size_t)NN*4);
  int* gcnt    =(int*)take((size_t)NG*4);
  int* growptr =(int*)take((size_t)(NG+1)*4);
  int* bsumN   =(int*)take((size_t)256*4);
  int* bsumG   =(int*)take((size_t)256*4);
  ull* csrp    =(ull*)take((size_t)NE*8);
  int* src_csr =(int*)take((size_t)NE*4);
  float* as_   =(float*)take((size_t)NN*4);
  float* ad_   =(float*)take((size_t)NN*4);
  float* edc   =(float*)take((size_t)NE*4*4);   // 4 layers x NE, CSR order (SoA)
  __half* hW16 =(__half*)take((size_t)NN*C*2);
  float* bufA  =(float*)take((size_t)NN*C*4);
  float* bufB  =(float*)take((size_t)NN*C*4);
  float* pooled=(float*)take((size_t)NG*128*4);
  // ed4 (16 MB, dead before feat L0 writes bufA/bufB) aliases bufA..bufB
  float* ed4   =bufA;
  (void)ws_size; (void)in_sizes; (void)n_in; (void)out_size;

  hipMemsetAsync(deg,0,(size_t)NN*4,stream);
  hipMemsetAsync(gcnt,0,(size_t)NG*4,stream);
  hist_kernel<<<2048,256,0,stream>>>(dst,NE,deg);
  hist_kernel<<<256,256,0,stream>>>(batch_index,NN,gcnt);

  const int nbN=(NN+255)/256;      // 196
  const int nbG=(NG+255)/256;      // 4
  scan_part<<<nbN,256,0,stream>>>(deg,NN,bsumN);
  scan_top<<<1,256,0,stream>>>(bsumN,nbN);
  scan_final<<<nbN,256,0,stream>>>(deg,bsumN,NN,rowptr,cursor);
  scan_part<<<nbG,256,0,stream>>>(gcnt,NG,bsumG);
  scan_top<<<1,256,0,stream>>>(bsumG,nbG);
  scan_final<<<nbG,256,0,stream>>>(gcnt,bsumG,NG,growptr,nullptr);

  scatter_kernel<<<2048,256,0,stream>>>(dst,src,cursor,csrp,NE);
  edprep_kernel<<<(NE+255)/256,256,0,stream>>>(edge_attr,We0,ae0,We,ae,ed4);
  reorder_kernel<<<2048,256,0,stream>>>(csrp,ed4,src_csr,edc);

  const int nblkF=(NN+63)/64;      // 782
  const int nblkA=(NN+3)/4;        // 12500
  // layer 0 (F=30)
  feat_kernel<FIN0><<<nblkF,256,0,stream>>>(x,W0,Wres0,b0,asrc0,adst0,hW16,bufA,as_,ad_);
  agg_kernel<<<nblkA,256,0,stream>>>(rowptr,src_csr,edc,as_,ad_,hW16,bufA,1);
  // layers 1..3 (ping-pong)
  float* bin=bufA; float* bo=bufB;
  for(int i=0;i<3;++i){
    feat_kernel<C><<<nblkF,256,0,stream>>>(bin,W+(size_t)i*C*C,Wres+(size_t)i*C*C,
        b+(size_t)i*C,asrc+(size_t)i*C,adst+(size_t)i*C,hW16,bo,as_,ad_);
    agg_kernel<<<nblkA,256,0,stream>>>(rowptr,src_csr,edc+(size_t)(i+1)*NE,as_,ad_,hW16,bo,(i<2)?1:0);
    float* t=bin; bin=bo; bo=t;
  }
  pool_kernel<<<(NG+3)/4,256,0,stream>>>(bin,growptr,pooled);
  out_kernel<<<NG,256,0,stream>>>(pooled,Wout,bout,(float*)d_out);
}

// Round 5
// 539.651 us; speedup vs baseline: 1.5296x; 1.0067x over previous
//
#include <hip/hip_runtime.h>
#include <hip/hip_fp16.h>

// Problem constants (from reference)
#define NN 50000
#define NE 1000000
#define FIN0 30
#define C 64
#define ED 11
#define NG 1024
#define DOUT 256

typedef unsigned long long ull;

// ---------------- CSR build ----------------
__global__ void hist_kernel(const int* __restrict__ idx, int n, int* __restrict__ cnt){
  for(int i=blockIdx.x*blockDim.x+threadIdx.x;i<n;i+=gridDim.x*blockDim.x)
    atomicAdd(&cnt[idx[i]],1);
}

// 3-stage multi-block exclusive scan over n elements (tile = 256)
__global__ __launch_bounds__(256) void scan_part(const int* __restrict__ cnt, int n,
    int* __restrict__ bsum){
  int t=threadIdx.x, i=blockIdx.x*256+t;
  int v=(i<n)?cnt[i]:0;
  #pragma unroll
  for(int off=32;off;off>>=1) v+=__shfl_xor(v,off,64);
  __shared__ int ws[4];
  if((t&63)==0) ws[t>>6]=v;
  __syncthreads();
  if(t==0) bsum[blockIdx.x]=ws[0]+ws[1]+ws[2]+ws[3];
}

__global__ __launch_bounds__(256) void scan_top(int* __restrict__ bsum, int nb){
  __shared__ int p[256];
  int t=threadIdx.x;
  int v=(t<nb)?bsum[t]:0;
  p[t]=v; __syncthreads();
  #pragma unroll
  for(int off=1;off<256;off<<=1){
    int u=(t>=off)?p[t-off]:0;
    __syncthreads(); p[t]+=u; __syncthreads();
  }
  if(t<nb) bsum[t]=p[t]-v;   // exclusive block offsets
}

__global__ __launch_bounds__(256) void scan_final(const int* __restrict__ cnt,
    const int* __restrict__ boff, int n, int* __restrict__ ptr, int* __restrict__ cursor){
  int t=threadIdx.x, b=blockIdx.x, i=b*256+t;
  int v=(i<n)?cnt[i]:0;
  __shared__ int p[256];
  p[t]=v; __syncthreads();
  #pragma unroll
  for(int off=1;off<256;off<<=1){
    int u=(t>=off)?p[t-off]:0;
    __syncthreads(); p[t]+=u; __syncthreads();
  }
  int ex=boff[b]+p[t]-v;
  if(i<n){
    ptr[i]=ex;
    if(cursor) cursor[i]=ex;
    if(i==n-1) ptr[n]=ex+v;
  }
}

// scatter (eid, src) pair -> csr position (8B payload, same line traffic as 4B)
__global__ void scatter_kernel(const int* __restrict__ dst, const int* __restrict__ src,
    int* __restrict__ cursor, ull* __restrict__ csrp, int n){
  for(int e=blockIdx.x*blockDim.x+threadIdx.x;e<n;e+=gridDim.x*blockDim.x){
    int pos=atomicAdd(&cursor[dst[e]],1);
    csrp[pos]=((ull)(unsigned)e<<32)|(unsigned)src[e];
  }
}

// ---------------- edge_attr dot for ALL 4 layers, one coalesced pass ----------------
__global__ __launch_bounds__(256) void edprep_kernel(const float* __restrict__ edge_attr,
    const float* __restrict__ We0, const float* __restrict__ ae0,
    const float* __restrict__ We,  const float* __restrict__ ae,
    float* __restrict__ ed4){
  __shared__ float sw[4][ED];
  __shared__ float tile[256*ED];
  int t=threadIdx.x;
  if(t<4*ED){
    int l=t/ED, j=t%ED;
    const float* wp=(l==0)? (We0+(size_t)j*C) : (We+((size_t)(l-1)*ED+j)*C);
    const float* ap=(l==0)? ae0 : (ae+(size_t)(l-1)*C);
    float s=0.f;
    for(int c=0;c<C;++c) s+=wp[c]*ap[c];
    sw[l][j]=s;
  }
  __syncthreads();
  size_t e0=(size_t)blockIdx.x*256;
  int cnt=(int)min((size_t)256,(size_t)NE-e0);
  for(int i=t;i<cnt*ED;i+=256) tile[i]=edge_attr[e0*ED+i];
  __syncthreads();
  if(t<cnt){
    float4 r;
    float d0=0,d1=0,d2=0,d3=0;
    #pragma unroll
    for(int j=0;j<ED;++j){
      float ev=tile[t*ED+j];
      d0=fmaf(ev,sw[0][j],d0);
      d1=fmaf(ev,sw[1][j],d1);
      d2=fmaf(ev,sw[2][j],d2);
      d3=fmaf(ev,sw[3][j],d3);
    }
    r.x=d0; r.y=d1; r.z=d2; r.w=d3;
    *(float4*)&ed4[(e0+t)*4]=r;
  }
}

// ---------------- reorder ed into CSR order; src comes free from the pair ----------------
__global__ void reorder_kernel(const ull* __restrict__ csrp,
    const float* __restrict__ ed4, int* __restrict__ src_csr, float* __restrict__ edc){
  for(int j=blockIdx.x*blockDim.x+threadIdx.x;j<NE;j+=gridDim.x*blockDim.x){
    ull pr=csrp[j];
    int eid=(int)(pr>>32);
    src_csr[j]=(int)(pr&0xffffffffu);
    float4 v=*(const float4*)&ed4[(size_t)eid*4];
    edc[j]=v.x; edc[NE+j]=v.y; edc[2*(size_t)NE+j]=v.z; edc[3*(size_t)NE+j]=v.w;
  }
}

// ---------------- per-layer: h = in@W (->f16), res = in@Wres + b, alpha dots ----------------
// 64 nodes per block: stage weights ONCE, iterate 16x with 4 waves.
template<int FIN>
__global__ __launch_bounds__(256) void feat_kernel(const float* __restrict__ in,
    const float* __restrict__ W, const float* __restrict__ Wres,
    const float* __restrict__ bvec, const float* __restrict__ av_src,
    const float* __restrict__ av_dst,
    __half* __restrict__ hW16, float* __restrict__ outb,
    float* __restrict__ as_, float* __restrict__ ad_){
  __shared__ float sW[FIN*C], sR[FIN*C];
  __shared__ float sx[4*C];
  __shared__ float sb[C], ss[C], sd[C];
  int tid=threadIdx.x;
  if(tid<C){ sb[tid]=bvec[tid]; ss[tid]=av_src[tid]; sd[tid]=av_dst[tid]; }
  for(int i=tid;i<FIN*C;i+=256){ sW[i]=W[i]; sR[i]=Wres[i]; }
  __syncthreads();
  int w=tid>>6, lane=tid&63;
  for(int it=0;it<16;++it){
    int nidx=blockIdx.x*64+it*4+w;
    if(nidx>=NN) continue;             // wave-uniform
    sx[w*C+lane]=(lane<FIN)?in[(size_t)nidx*FIN+lane]:0.f;
    float hw=0.f, hr=0.f;
    #pragma unroll
    for(int k=0;k<FIN;++k){
      float xv=sx[w*C+k];
      hw=fmaf(xv,sW[k*C+lane],hw);
      hr=fmaf(xv,sR[k*C+lane],hr);
    }
    hW16[(size_t)nidx*C+lane]=__float2half(hw);
    outb[(size_t)nidx*C+lane]=hr+sb[lane];
    float ps=hw*ss[lane], pd=hw*sd[lane];
    #pragma unroll
    for(int off=32;off;off>>=1){ ps+=__shfl_xor(ps,off,64); pd+=__shfl_xor(pd,off,64); }
    if(lane==0){ as_[nidx]=ps; ad_[nidx]=pd; }
  }
}

// ------- fused alpha + softmax aggregation, wave per dst node -------
// Fast path (deg<=64, ~always): single-chunk softmax, (wl,sl) staged in LDS,
// inner loop reads one ds_read_b64 per 4 edges (group-uniform broadcast).
__global__ __launch_bounds__(256) void agg_kernel(const int* __restrict__ rowptr,
    const int* __restrict__ src_csr, const float* __restrict__ edc_l,
    const float* __restrict__ as_, const float* __restrict__ ad_,
    const __half* __restrict__ hW16, float* __restrict__ outb, int relu){
  __shared__ float2 sws[4][64];          // per-wave (wl, sl-as-bits)
  int w=threadIdx.x>>6, lane=threadIdx.x&63;
  int nidx=blockIdx.x*4+w;
  if(nidx>=NN) return;
  int beg=rowptr[nidx], end=rowptr[nidx+1];
  int deg=end-beg;
  float ad_n=ad_[nidx];
  int g=lane>>4, gl=lane&15;
  const uint2* hw2=(const uint2*)hW16;   // row = 16 uint2 (4 halves each)
  float s=0.f;
  float ax=0.f, ay=0.f, az=0.f, aw=0.f;

  if(deg<=64){
    // ---- fast path: one chunk covers the row; no online rescale ----
    int j=beg+lane;
    float al=-INFINITY; int sl=0;
    if(lane<deg){
      sl=src_csr[j];
      float a=as_[sl]+ad_n+edc_l[j];
      al=(a>0.f)?a:0.2f*a;               // leaky_relu 0.2
    }
    float mn=al;
    #pragma unroll
    for(int off=32;off;off>>=1) mn=fmaxf(mn,__shfl_xor(mn,off,64));
    float wl=(lane<deg)?__expf(al-mn):0.f;
    s=wl;
    #pragma unroll
    for(int off=32;off;off>>=1) s+=__shfl_xor(s,off,64);
    float2 pr; pr.x=wl; pr.y=__int_as_float(sl);
    sws[w][lane]=pr;                     // wave-private slice: no barrier
    for(int t=g;t<deg;t+=4){
      float2 r=sws[w][t];                // group-uniform addr -> broadcast
      float at=r.x;
      int   st=__float_as_int(r.y);
      uint2 u=hw2[(size_t)st*16+gl];
      __half2 h0=*(__half2*)&u.x;
      __half2 h1=*(__half2*)&u.y;
      float2 f0=__half22float2(h0);
      float2 f1=__half22float2(h1);
      ax=fmaf(at,f0.x,ax);
      ay=fmaf(at,f0.y,ay);
      az=fmaf(at,f1.x,az);
      aw=fmaf(at,f1.y,aw);
    }
  } else {
    // ---- fallback: online softmax over 64-edge chunks (rare) ----
    float m=-INFINITY;
    for(int base=beg;base<end;base+=64){
      int j=base+lane;
      float al=-INFINITY; int sl=0;
      if(j<end){
        sl=src_csr[j];
        float a=as_[sl]+ad_n+edc_l[j];
        al=(a>0.f)?a:0.2f*a;
      }
      float cm=al;
      #pragma unroll
      for(int off=32;off;off>>=1) cm=fmaxf(cm,__shfl_xor(cm,off,64));
      float mn=fmaxf(m,cm);
      float scale=(m==-INFINITY)?0.f:__expf(m-mn);
      s*=scale; ax*=scale; ay*=scale; az*=scale; aw*=scale;
      float wl=(j<end)?__expf(al-mn):0.f;
      float cs=wl;
      #pragma unroll
      for(int off=32;off;off>>=1) cs+=__shfl_xor(cs,off,64);
      s+=cs; m=mn;
      float2 pr; pr.x=wl; pr.y=__int_as_float(sl);
      sws[w][lane]=pr;
      int cnt=min(64,end-base);
      for(int t=g;t<cnt;t+=4){
        float2 r=sws[w][t];
        float at=r.x;
        int   st=__float_as_int(r.y);
        uint2 u=hw2[(size_t)st*16+gl];
        __half2 h0=*(__half2*)&u.x;
        __half2 h1=*(__half2*)&u.y;
        float2 f0=__half22float2(h0);
        float2 f1=__half22float2(h1);
        ax=fmaf(at,f0.x,ax);
        ay=fmaf(at,f0.y,ay);
        az=fmaf(at,f1.x,az);
        aw=fmaf(at,f1.y,aw);
      }
    }
  }

  // combine the 4 groups: lanes l, l+16, l+32, l+48 hold same channels
  #pragma unroll
  for(int off=16;off<64;off<<=1){
    ax+=__shfl_xor(ax,off,64);
    ay+=__shfl_xor(ay,off,64);
    az+=__shfl_xor(az,off,64);
    aw+=__shfl_xor(aw,off,64);
  }
  if(g==0){
    float inv=s+1e-16f;
    float4 o=*(float4*)&outb[(size_t)nidx*C+gl*4];
    float4 v;
    v.x=ax/inv+o.x; v.y=ay/inv+o.y; v.z=az/inv+o.z; v.w=aw/inv+o.w;
    if(relu){
      v.x=(v.x>0.f)?v.x:0.01f*v.x;
      v.y=(v.y>0.f)?v.y:0.01f*v.y;
      v.z=(v.z>0.f)?v.z:0.01f*v.z;
      v.w=(v.w>0.f)?v.w:0.01f*v.w;
    }
    *(float4*)&outb[(size_t)nidx*C+gl*4]=v;
  }
}

// ---------------- pooling (max + mean per graph) ----------------
__global__ __launch_bounds__(256) void pool_kernel(const float* __restrict__ h,
    const int* __restrict__ growptr, float* __restrict__ pooled){
  int w=threadIdx.x>>6, lane=threadIdx.x&63;
  int g=blockIdx.x*4+w;
  if(g>=NG) return;
  int beg=growptr[g], end=growptr[g+1];
  float mx=-INFINITY, sm=0.f;
  for(int n=beg;n<end;++n){ float v=h[(size_t)n*C+lane]; mx=fmaxf(mx,v); sm+=v; }
  int cnt=end-beg;
  float gm=(cnt==0)?0.f:mx;              // isfinite fix for empty graphs
  float mean=sm/fmaxf((float)cnt,1.f);
  gm=(gm>0.f)?gm:0.01f*gm;               // leaky_relu 0.01 on pooled
  mean=(mean>0.f)?mean:0.01f*mean;
  pooled[(size_t)g*128+lane]=gm;
  pooled[(size_t)g*128+64+lane]=mean;
}

// ---------------- final linear: [G,128] @ [128,256] + bias ----------------
__global__ __launch_bounds__(256) void out_kernel(const float* __restrict__ pooled,
    const float* __restrict__ Wout, const float* __restrict__ bout,
    float* __restrict__ out){
  __shared__ float sp[128];
  int g=blockIdx.x, d=threadIdx.x;
  if(d<128) sp[d]=pooled[(size_t)g*128+d];
  __syncthreads();
  float o=bout[d];
  for(int k=0;k<128;++k) o=fmaf(sp[k],Wout[k*DOUT+d],o);
  out[(size_t)g*DOUT+d]=o;
}

extern "C" void kernel_launch(void* const* d_in, const int* in_sizes, int n_in,
                              void* d_out, int out_size, void* d_ws, size_t ws_size,
                              hipStream_t stream){
  const float* x        =(const float*)d_in[0];
  const float* edge_attr=(const float*)d_in[1];
  const float* W0       =(const float*)d_in[2];
  const float* asrc0    =(const float*)d_in[3];
  const float* adst0    =(const float*)d_in[4];
  const float* We0      =(const float*)d_in[5];
  const float* ae0      =(const float*)d_in[6];
  const float* Wres0    =(const float*)d_in[7];
  const float* b0       =(const float*)d_in[8];
  const float* W        =(const float*)d_in[9];
  const float* asrc     =(const float*)d_in[10];
  const float* adst     =(const float*)d_in[11];
  const float* We       =(const float*)d_in[12];
  const float* ae       =(const float*)d_in[13];
  const float* Wres     =(const float*)d_in[14];
  const float* b        =(const float*)d_in[15];
  const float* Wout     =(const float*)d_in[16];
  const float* bout     =(const float*)d_in[17];
  const int* edge_index =(const int*)d_in[18];
  const int* batch_index=(const int*)d_in[19];
  const int* src=edge_index;
  const int* dst=edge_index+NE;

  // workspace carve (~62 MB)
  char* p=(char*)d_ws;
  auto take=[&](size_t bytes)->void*{ void* r=(void*)p; p+=(bytes+255)&~(size_t)255; return r; };
  int* deg     =(int*)take((size_t)NN*4);
  int* rowptr  =(int*)take((size_t)(NN+1)*4);
  int* cursor  =(int*)take((size_t)NN*4);
  int* gcnt    =(int*)take((size_t)NG*4);
  int* growptr =(int*)take((size_t)(NG+1)*4);
  int* bsumN   =(int*)take((size_t)256*4);
  int* bsumG   =(int*)take((size_t)256*4);
  ull* csrp    =(ull*)take((size_t)NE*8);
  int* src_csr =(int*)take((size_t)NE*4);
  float* as_   =(float*)take((size_t)NN*4);
  float* ad_   =(float*)take((size_t)NN*4);
  float* edc   =(float*)take((size_t)NE*4*4);   // 4 layers x NE, CSR order (SoA)
  __half* hW16 =(__half*)take((size_t)NN*C*2);
  float* bufA  =(float*)take((size_t)NN*C*4);
  float* bufB  =(float*)take((size_t)NN*C*4);
  float* pooled=(float*)take((size_t)NG*128*4);
  // ed4 (16 MB, dead before feat L0 writes bufA/bufB) aliases bufA..bufB
  float* ed4   =bufA;
  (void)ws_size; (void)in_sizes; (void)n_in; (void)out_size;

  hipMemsetAsync(deg,0,(size_t)NN*4,stream);
  hipMemsetAsync(gcnt,0,(size_t)NG*4,stream);
  hist_kernel<<<2048,256,0,stream>>>(dst,NE,deg);
  hist_kernel<<<256,256,0,stream>>>(batch_index,NN,gcnt);

  const int nbN=(NN+255)/256;      // 196
  const int nbG=(NG+255)/256;      // 4
  scan_part<<<nbN,256,0,stream>>>(deg,NN,bsumN);
  scan_top<<<1,256,0,stream>>>(bsumN,nbN);
  scan_final<<<nbN,256,0,stream>>>(deg,bsumN,NN,rowptr,cursor);
  scan_part<<<nbG,256,0,stream>>>(gcnt,NG,bsumG);
  scan_top<<<1,256,0,stream>>>(bsumG,nbG);
  scan_final<<<nbG,256,0,stream>>>(gcnt,bsumG,NG,growptr,nullptr);

  scatter_kernel<<<2048,256,0,stream>>>(dst,src,cursor,csrp,NE);
  edprep_kernel<<<(NE+255)/256,256,0,stream>>>(edge_attr,We0,ae0,We,ae,ed4);
  reorder_kernel<<<2048,256,0,stream>>>(csrp,ed4,src_csr,edc);

  const int nblkF=(NN+63)/64;      // 782
  const int nblkA=(NN+3)/4;        // 12500
  // layer 0 (F=30)
  feat_kernel<FIN0><<<nblkF,256,0,stream>>>(x,W0,Wres0,b0,asrc0,adst0,hW16,bufA,as_,ad_);
  agg_kernel<<<nblkA,256,0,stream>>>(rowptr,src_csr,edc,as_,ad_,hW16,bufA,1);
  // layers 1..3 (ping-pong)
  float* bin=bufA; float* bo=bufB;
  for(int i=0;i<3;++i){
    feat_kernel<C><<<nblkF,256,0,stream>>>(bin,W+(size_t)i*C*C,Wres+(size_t)i*C*C,
        b+(size_t)i*C,asrc+(size_t)i*C,adst+(size_t)i*C,hW16,bo,as_,ad_);
    agg_kernel<<<nblkA,256,0,stream>>>(rowptr,src_csr,edc+(size_t)(i+1)*NE,as_,ad_,hW16,bo,(i<2)?1:0);
    float* t=bin; bin=bo; bo=t;
  }
  pool_kernel<<<(NG+3)/4,256,0,stream>>>(bin,growptr,pooled);
  out_kernel<<<NG,256,0,stream>>>(pooled,Wout,bout,(float*)d_out);
}

// Round 6
// 518.529 us; speedup vs baseline: 1.5919x; 1.0407x over previous
//
#include <hip/hip_runtime.h>
#include <hip/hip_fp16.h>

// Problem constants (from reference)
#define NN 50000
#define NE 1000000
#define FIN0 30
#define C 64
#define ED 11
#define NG 1024
#define DOUT 256
#define NBIN 196            // ceil(NN/256)
#define PA_EDGES 2048       // edges per partition block

typedef unsigned long long ull;

// ---------------- histograms ----------------
__global__ void hist_kernel(const int* __restrict__ idx, int n, int* __restrict__ cnt){
  for(int i=blockIdx.x*blockDim.x+threadIdx.x;i<n;i+=gridDim.x*blockDim.x)
    atomicAdd(&cnt[idx[i]],1);
}

// 3-stage multi-block exclusive scan over n elements (tile = 256)
__global__ __launch_bounds__(256) void scan_part(const int* __restrict__ cnt, int n,
    int* __restrict__ bsum){
  int t=threadIdx.x, i=blockIdx.x*256+t;
  int v=(i<n)?cnt[i]:0;
  #pragma unroll
  for(int off=32;off;off>>=1) v+=__shfl_xor(v,off,64);
  __shared__ int ws[4];
  if((t&63)==0) ws[t>>6]=v;
  __syncthreads();
  if(t==0) bsum[blockIdx.x]=ws[0]+ws[1]+ws[2]+ws[3];
}

__global__ __launch_bounds__(256) void scan_top(int* __restrict__ bsum, int nb){
  __shared__ int p[256];
  int t=threadIdx.x;
  int v=(t<nb)?bsum[t]:0;
  p[t]=v; __syncthreads();
  #pragma unroll
  for(int off=1;off<256;off<<=1){
    int u=(t>=off)?p[t-off]:0;
    __syncthreads(); p[t]+=u; __syncthreads();
  }
  if(t<nb) bsum[t]=p[t]-v;   // exclusive block offsets
}

__global__ __launch_bounds__(256) void scan_final(const int* __restrict__ cnt,
    const int* __restrict__ boff, int n, int* __restrict__ ptr){
  int t=threadIdx.x, b=blockIdx.x, i=b*256+t;
  int v=(i<n)?cnt[i]:0;
  __shared__ int p[256];
  p[t]=v; __syncthreads();
  #pragma unroll
  for(int off=1;off<256;off<<=1){
    int u=(t>=off)?p[t-off]:0;
    __syncthreads(); p[t]+=u; __syncthreads();
  }
  int ex=boff[b]+p[t]-v;
  if(i<n){
    ptr[i]=ex;
    if(i==n-1) ptr[n]=ex+v;
  }
}

// gcur[b] = start of bin b's region (= CSR offset of node b*256)
__global__ void binit_kernel(const int* __restrict__ rowptr, int* __restrict__ gcur){
  int t=threadIdx.x;
  if(t<NBIN) gcur[t]=rowptr[t<<8];
  else gcur[t]=0;
}

// ---------------- edge_attr dot for ALL 4 layers, one coalesced pass ----------------
__global__ __launch_bounds__(256) void edprep_kernel(const float* __restrict__ edge_attr,
    const float* __restrict__ We0, const float* __restrict__ ae0,
    const float* __restrict__ We,  const float* __restrict__ ae,
    float* __restrict__ ed4){
  __shared__ float sw[4][ED];
  __shared__ float tile[256*ED];
  int t=threadIdx.x;
  if(t<4*ED){
    int l=t/ED, j=t%ED;
    const float* wp=(l==0)? (We0+(size_t)j*C) : (We+((size_t)(l-1)*ED+j)*C);
    const float* ap=(l==0)? ae0 : (ae+(size_t)(l-1)*C);
    float s=0.f;
    for(int c=0;c<C;++c) s+=wp[c]*ap[c];
    sw[l][j]=s;
  }
  __syncthreads();
  size_t e0=(size_t)blockIdx.x*256;
  int cnt=(int)min((size_t)256,(size_t)NE-e0);
  for(int i=t;i<cnt*ED;i+=256) tile[i]=edge_attr[e0*ED+i];
  __syncthreads();
  if(t<cnt){
    float4 r;
    float d0=0,d1=0,d2=0,d3=0;
    #pragma unroll
    for(int j=0;j<ED;++j){
      float ev=tile[t*ED+j];
      d0=fmaf(ev,sw[0][j],d0);
      d1=fmaf(ev,sw[1][j],d1);
      d2=fmaf(ev,sw[2][j],d2);
      d3=fmaf(ev,sw[3][j],d3);
    }
    r.x=d0; r.y=d1; r.z=d2; r.w=d3;
    *(float4*)&ed4[(e0+t)*4]=r;
  }
}

// ---------------- Pass A: block counting-sort partition into 196 dst-bins ----------------
// Coalesced writes: records staged bin-sorted in LDS, flushed sequentially.
__global__ __launch_bounds__(256) void part_kernel(const int* __restrict__ dst,
    const int* __restrict__ src, const float* __restrict__ ed4,
    int* __restrict__ gcur,
    ull* __restrict__ pdst_src, float2* __restrict__ ped01, float2* __restrict__ ped23){
  __shared__ ull    ldst_src[PA_EDGES];      // 16KB
  __shared__ float2 led01[PA_EDGES];         // 16KB
  __shared__ float2 led23[PA_EDGES];         // 16KB
  __shared__ unsigned char lbin[PA_EDGES];   // 2KB
  __shared__ int hist[256], p[256], sc[256], lofs[256], bbase[256];
  int t=threadIdx.x;
  hist[t]=0;
  __syncthreads();
  size_t e0=(size_t)blockIdx.x*PA_EDGES;
  int cnt=(int)min((size_t)PA_EDGES,(size_t)NE-e0);
  // 1) histogram bins
  for(int i=t;i<cnt;i+=256) atomicAdd(&hist[dst[e0+i]>>8],1);
  __syncthreads();
  // 2) exclusive scan of hist
  p[t]=hist[t]; __syncthreads();
  #pragma unroll
  for(int off=1;off<256;off<<=1){
    int u=(t>=off)?p[t-off]:0;
    __syncthreads(); p[t]+=u; __syncthreads();
  }
  sc[t]=p[t]-hist[t];
  lofs[t]=sc[t];
  // 3) reserve global ranges (one atomic per non-empty bin)
  bbase[t]=(hist[t]>0)?atomicAdd(&gcur[t],hist[t]):0;
  __syncthreads();
  // 4) place records bin-sorted into LDS
  for(int i=t;i<cnt;i+=256){
    int d=dst[e0+i], s=src[e0+i];
    int b=d>>8;
    int slot=atomicAdd(&lofs[b],1);
    ldst_src[slot]=((ull)(unsigned)d<<32)|(unsigned)s;
    float4 v=*(const float4*)&ed4[(e0+i)*4];
    led01[slot]=make_float2(v.x,v.y);
    led23[slot]=make_float2(v.z,v.w);
    lbin[slot]=(unsigned char)b;
  }
  __syncthreads();
  // 5) coalesced flush (consecutive LDS slots -> consecutive global)
  for(int i=t;i<cnt;i+=256){
    int b=lbin[i];
    int g=bbase[b]+i-sc[b];
    pdst_src[g]=ldst_src[i];
    ped01[g]=led01[i];
    ped23[g]=led23[i];
  }
}

// ---------------- Pass B: bin -> exact CSR slots (writes stay in ~20KB L2 windows) ----------------
__global__ __launch_bounds__(256) void build_kernel(const ull* __restrict__ pdst_src,
    const float2* __restrict__ ped01, const float2* __restrict__ ped23,
    const int* __restrict__ rowptr,
    int* __restrict__ src_csr, float* __restrict__ edc){
  __shared__ int cur[256];
  int t=threadIdx.x, b=blockIdx.x;
  int n0=b<<8;
  cur[t]=(n0+t<NN)?rowptr[n0+t]:0;
  __syncthreads();
  int n1=min(NN,n0+256);
  int beg=rowptr[n0], endd=rowptr[n1];
  for(int j=beg+t;j<endd;j+=256){
    ull ds=pdst_src[j];
    int d=(int)(ds>>32);
    int s=(int)(ds&0xffffffffu);
    int pos=atomicAdd(&cur[d-n0],1);
    src_csr[pos]=s;
    float2 a=ped01[j], c=ped23[j];
    edc[pos]=a.x;
    edc[(size_t)NE+pos]=a.y;
    edc[2*(size_t)NE+pos]=c.x;
    edc[3*(size_t)NE+pos]=c.y;
  }
}

// ---------------- per-layer: h = in@W (->f16), res = in@Wres + b, alpha dots ----------------
template<int FIN>
__global__ __launch_bounds__(256) void feat_kernel(const float* __restrict__ in,
    const float* __restrict__ W, const float* __restrict__ Wres,
    const float* __restrict__ bvec, const float* __restrict__ av_src,
    const float* __restrict__ av_dst,
    __half* __restrict__ hW16, float* __restrict__ outb,
    float* __restrict__ as_, float* __restrict__ ad_){
  __shared__ float sW[FIN*C], sR[FIN*C];
  __shared__ float sx[4*C];
  __shared__ float sb[C], ss[C], sd[C];
  int tid=threadIdx.x;
  if(tid<C){ sb[tid]=bvec[tid]; ss[tid]=av_src[tid]; sd[tid]=av_dst[tid]; }
  for(int i=tid;i<FIN*C;i+=256){ sW[i]=W[i]; sR[i]=Wres[i]; }
  __syncthreads();
  int w=tid>>6, lane=tid&63;
  for(int it=0;it<16;++it){
    int nidx=blockIdx.x*64+it*4+w;
    if(nidx>=NN) continue;             // wave-uniform
    sx[w*C+lane]=(lane<FIN)?in[(size_t)nidx*FIN+lane]:0.f;
    float hw=0.f, hr=0.f;
    #pragma unroll
    for(int k=0;k<FIN;++k){
      float xv=sx[w*C+k];
      hw=fmaf(xv,sW[k*C+lane],hw);
      hr=fmaf(xv,sR[k*C+lane],hr);
    }
    hW16[(size_t)nidx*C+lane]=__float2half(hw);
    outb[(size_t)nidx*C+lane]=hr+sb[lane];
    float ps=hw*ss[lane], pd=hw*sd[lane];
    #pragma unroll
    for(int off=32;off;off>>=1){ ps+=__shfl_xor(ps,off,64); pd+=__shfl_xor(pd,off,64); }
    if(lane==0){ as_[nidx]=ps; ad_[nidx]=pd; }
  }
}

// ------- fused alpha + softmax aggregation, wave per dst node -------
__global__ __launch_bounds__(256) void agg_kernel(const int* __restrict__ rowptr,
    const int* __restrict__ src_csr, const float* __restrict__ edc_l,
    const float* __restrict__ as_, const float* __restrict__ ad_,
    const __half* __restrict__ hW16, float* __restrict__ outb, int relu){
  __shared__ float2 sws[4][64];          // per-wave (wl, sl-as-bits)
  int w=threadIdx.x>>6, lane=threadIdx.x&63;
  int nidx=blockIdx.x*4+w;
  if(nidx>=NN) return;
  int beg=rowptr[nidx], end=rowptr[nidx+1];
  int deg=end-beg;
  float ad_n=ad_[nidx];
  int g=lane>>4, gl=lane&15;
  const uint2* hw2=(const uint2*)hW16;   // row = 16 uint2 (4 halves each)
  float s=0.f;
  float ax=0.f, ay=0.f, az=0.f, aw=0.f;

  if(deg<=64){
    // ---- fast path: one chunk covers the row; no online rescale ----
    int j=beg+lane;
    float al=-INFINITY; int sl=0;
    if(lane<deg){
      sl=src_csr[j];
      float a=as_[sl]+ad_n+edc_l[j];
      al=(a>0.f)?a:0.2f*a;               // leaky_relu 0.2
    }
    float mn=al;
    #pragma unroll
    for(int off=32;off;off>>=1) mn=fmaxf(mn,__shfl_xor(mn,off,64));
    float wl=(lane<deg)?__expf(al-mn):0.f;
    s=wl;
    #pragma unroll
    for(int off=32;off;off>>=1) s+=__shfl_xor(s,off,64);
    float2 pr; pr.x=wl; pr.y=__int_as_float(sl);
    sws[w][lane]=pr;                     // wave-private slice: no barrier
    for(int t=g;t<deg;t+=4){
      float2 r=sws[w][t];                // group-uniform addr -> broadcast
      float at=r.x;
      int   st=__float_as_int(r.y);
      uint2 u=hw2[(size_t)st*16+gl];
      __half2 h0=*(__half2*)&u.x;
      __half2 h1=*(__half2*)&u.y;
      float2 f0=__half22float2(h0);
      float2 f1=__half22float2(h1);
      ax=fmaf(at,f0.x,ax);
      ay=fmaf(at,f0.y,ay);
      az=fmaf(at,f1.x,az);
      aw=fmaf(at,f1.y,aw);
    }
  } else {
    // ---- fallback: online softmax over 64-edge chunks (rare) ----
    float m=-INFINITY;
    for(int base=beg;base<end;base+=64){
      int j=base+lane;
      float al=-INFINITY; int sl=0;
      if(j<end){
        sl=src_csr[j];
        float a=as_[sl]+ad_n+edc_l[j];
        al=(a>0.f)?a:0.2f*a;
      }
      float cm=al;
      #pragma unroll
      for(int off=32;off;off>>=1) cm=fmaxf(cm,__shfl_xor(cm,off,64));
      float mn=fmaxf(m,cm);
      float scale=(m==-INFINITY)?0.f:__expf(m-mn);
      s*=scale; ax*=scale; ay*=scale; az*=scale; aw*=scale;
      float wl=(j<end)?__expf(al-mn):0.f;
      float cs=wl;
      #pragma unroll
      for(int off=32;off;off>>=1) cs+=__shfl_xor(cs,off,64);
      s+=cs; m=mn;
      float2 pr; pr.x=wl; pr.y=__int_as_float(sl);
      sws[w][lane]=pr;
      int cnt=min(64,end-base);
      for(int t=g;t<cnt;t+=4){
        float2 r=sws[w][t];
        float at=r.x;
        int   st=__float_as_int(r.y);
        uint2 u=hw2[(size_t)st*16+gl];
        __half2 h0=*(__half2*)&u.x;
        __half2 h1=*(__half2*)&u.y;
        float2 f0=__half22float2(h0);
        float2 f1=__half22float2(h1);
        ax=fmaf(at,f0.x,ax);
        ay=fmaf(at,f0.y,ay);
        az=fmaf(at,f1.x,az);
        aw=fmaf(at,f1.y,aw);
      }
    }
  }

  // combine the 4 groups: lanes l, l+16, l+32, l+48 hold same channels
  #pragma unroll
  for(int off=16;off<64;off<<=1){
    ax+=__shfl_xor(ax,off,64);
    ay+=__shfl_xor(ay,off,64);
    az+=__shfl_xor(az,off,64);
    aw+=__shfl_xor(aw,off,64);
  }
  if(g==0){
    float inv=s+1e-16f;
    float4 o=*(float4*)&outb[(size_t)nidx*C+gl*4];
    float4 v;
    v.x=ax/inv+o.x; v.y=ay/inv+o.y; v.z=az/inv+o.z; v.w=aw/inv+o.w;
    if(relu){
      v.x=(v.x>0.f)?v.x:0.01f*v.x;
      v.y=(v.y>0.f)?v.y:0.01f*v.y;
      v.z=(v.z>0.f)?v.z:0.01f*v.z;
      v.w=(v.w>0.f)?v.w:0.01f*v.w;
    }
    *(float4*)&outb[(size_t)nidx*C+gl*4]=v;
  }
}

// ---------------- pooling (max + mean per graph) ----------------
__global__ __launch_bounds__(256) void pool_kernel(const float* __restrict__ h,
    const int* __restrict__ growptr, float* __restrict__ pooled){
  int w=threadIdx.x>>6, lane=threadIdx.x&63;
  int g=blockIdx.x*4+w;
  if(g>=NG) return;
  int beg=growptr[g], end=growptr[g+1];
  float mx=-INFINITY, sm=0.f;
  for(int n=beg;n<end;++n){ float v=h[(size_t)n*C+lane]; mx=fmaxf(mx,v); sm+=v; }
  int cnt=end-beg;
  float gm=(cnt==0)?0.f:mx;              // isfinite fix for empty graphs
  float mean=sm/fmaxf((float)cnt,1.f);
  gm=(gm>0.f)?gm:0.01f*gm;               // leaky_relu 0.01 on pooled
  mean=(mean>0.f)?mean:0.01f*mean;
  pooled[(size_t)g*128+lane]=gm;
  pooled[(size_t)g*128+64+lane]=mean;
}

// ---------------- final linear: [G,128] @ [128,256] + bias ----------------
__global__ __launch_bounds__(256) void out_kernel(const float* __restrict__ pooled,
    const float* __restrict__ Wout, const float* __restrict__ bout,
    float* __restrict__ out){
  __shared__ float sp[128];
  int g=blockIdx.x, d=threadIdx.x;
  if(d<128) sp[d]=pooled[(size_t)g*128+d];
  __syncthreads();
  float o=bout[d];
  for(int k=0;k<128;++k) o=fmaf(sp[k],Wout[k*DOUT+d],o);
  out[(size_t)g*DOUT+d]=o;
}

extern "C" void kernel_launch(void* const* d_in, const int* in_sizes, int n_in,
                              void* d_out, int out_size, void* d_ws, size_t ws_size,
                              hipStream_t stream){
  const float* x        =(const float*)d_in[0];
  const float* edge_attr=(const float*)d_in[1];
  const float* W0       =(const float*)d_in[2];
  const float* asrc0    =(const float*)d_in[3];
  const float* adst0    =(const float*)d_in[4];
  const float* We0      =(const float*)d_in[5];
  const float* ae0      =(const float*)d_in[6];
  const float* Wres0    =(const float*)d_in[7];
  const float* b0       =(const float*)d_in[8];
  const float* W        =(const float*)d_in[9];
  const float* asrc     =(const float*)d_in[10];
  const float* adst     =(const float*)d_in[11];
  const float* We       =(const float*)d_in[12];
  const float* ae       =(const float*)d_in[13];
  const float* Wres     =(const float*)d_in[14];
  const float* b        =(const float*)d_in[15];
  const float* Wout     =(const float*)d_in[16];
  const float* bout     =(const float*)d_in[17];
  const int* edge_index =(const int*)d_in[18];
  const int* batch_index=(const int*)d_in[19];
  const int* src=edge_index;
  const int* dst=edge_index+NE;

  // workspace carve (~67 MB, with aliased regions)
  char* p=(char*)d_ws;
  auto take=[&](size_t bytes)->void*{ void* r=(void*)p; p+=(bytes+255)&~(size_t)255; return r; };
  int* deg     =(int*)take((size_t)NN*4);
  int* rowptr  =(int*)take((size_t)(NN+1)*4);
  int* gcnt    =(int*)take((size_t)NG*4);
  int* growptr =(int*)take((size_t)(NG+1)*4);
  int* bsumN   =(int*)take((size_t)256*4);
  int* bsumG   =(int*)take((size_t)256*4);
  int* gcur    =(int*)take((size_t)256*4);
  int* src_csr =(int*)take((size_t)NE*4);
  float* as_   =(float*)take((size_t)NN*4);
  float* ad_   =(float*)take((size_t)NN*4);
  float* edc   =(float*)take((size_t)NE*4*4);     // 4 layers x NE, CSR order (SoA)
  __half* hW16 =(__half*)take((size_t)NN*C*2);
  // region R1: ed4 (16MB) -> later bufA (12.8MB)
  float* ed4   =(float*)take((size_t)NE*4*4);
  float* bufA  =ed4;
  // region R2: pdst_src (8MB) -> later pooled (0.5MB)
  ull* pdst_src=(ull*)take((size_t)NE*8);
  float* pooled=(float*)pdst_src;
  // region R3: ped01+ped23 (16MB) -> later bufB (12.8MB)
  float2* ped01=(float2*)take((size_t)NE*8);
  float2* ped23=(float2*)take((size_t)NE*8);
  float* bufB  =(float*)ped01;
  (void)ws_size; (void)in_sizes; (void)n_in; (void)out_size;

  hipMemsetAsync(deg,0,(size_t)NN*4,stream);
  hipMemsetAsync(gcnt,0,(size_t)NG*4,stream);
  hist_kernel<<<2048,256,0,stream>>>(dst,NE,deg);
  hist_kernel<<<256,256,0,stream>>>(batch_index,NN,gcnt);

  const int nbN=(NN+255)/256;      // 196
  const int nbG=(NG+255)/256;      // 4
  scan_part<<<nbN,256,0,stream>>>(deg,NN,bsumN);
  scan_top<<<1,256,0,stream>>>(bsumN,nbN);
  scan_final<<<nbN,256,0,stream>>>(deg,bsumN,NN,rowptr);
  scan_part<<<nbG,256,0,stream>>>(gcnt,NG,bsumG);
  scan_top<<<1,256,0,stream>>>(bsumG,nbG);
  scan_final<<<nbG,256,0,stream>>>(gcnt,bsumG,NG,growptr);
  binit_kernel<<<1,256,0,stream>>>(rowptr,gcur);

  edprep_kernel<<<(NE+255)/256,256,0,stream>>>(edge_attr,We0,ae0,We,ae,ed4);
  part_kernel<<<(NE+PA_EDGES-1)/PA_EDGES,256,0,stream>>>(dst,src,ed4,gcur,
      pdst_src,ped01,ped23);
  build_kernel<<<NBIN,256,0,stream>>>(pdst_src,ped01,ped23,rowptr,src_csr,edc);

  const int nblkF=(NN+63)/64;      // 782
  const int nblkA=(NN+3)/4;        // 12500
  // layer 0 (F=30)
  feat_kernel<FIN0><<<nblkF,256,0,stream>>>(x,W0,Wres0,b0,asrc0,adst0,hW16,bufA,as_,ad_);
  agg_kernel<<<nblkA,256,0,stream>>>(rowptr,src_csr,edc,as_,ad_,hW16,bufA,1);
  // layers 1..3 (ping-pong)
  float* bin=bufA; float* bo=bufB;
  for(int i=0;i<3;++i){
    feat_kernel<C><<<nblkF,256,0,stream>>>(bin,W+(size_t)i*C*C,Wres+(size_t)i*C*C,
        b+(size_t)i*C,asrc+(size_t)i*C,adst+(size_t)i*C,hW16,bo,as_,ad_);
    agg_kernel<<<nblkA,256,0,stream>>>(rowptr,src_csr,edc+(size_t)(i+1)*NE,as_,ad_,hW16,bo,(i<2)?1:0);
    float* t=bin; bin=bo; bo=t;
  }
  pool_kernel<<<(NG+3)/4,256,0,stream>>>(bin,growptr,pooled);
  out_kernel<<<NG,256,0,stream>>>(pooled,Wout,bout,(float*)d_out);
}

// Round 7
// 405.941 us; speedup vs baseline: 2.0334x; 1.2774x over previous
//
#include <hip/hip_runtime.h>
#include <hip/hip_fp16.h>

// Problem constants (from reference)
#define NN 50000
#define NE 1000000
#define FIN0 30
#define C 64
#define ED 11
#define NG 1024
#define DOUT 256
#define NBIN 196            // ceil(NN/256)
#define PA_EDGES 2048       // edges per partition block

typedef unsigned long long ull;

// ---------------- histograms ----------------
__global__ void hist_kernel(const int* __restrict__ idx, int n, int* __restrict__ cnt){
  for(int i=blockIdx.x*blockDim.x+threadIdx.x;i<n;i+=gridDim.x*blockDim.x)
    atomicAdd(&cnt[idx[i]],1);
}

// 3-stage multi-block exclusive scan over n elements (tile = 256)
__global__ __launch_bounds__(256) void scan_part(const int* __restrict__ cnt, int n,
    int* __restrict__ bsum){
  int t=threadIdx.x, i=blockIdx.x*256+t;
  int v=(i<n)?cnt[i]:0;
  #pragma unroll
  for(int off=32;off;off>>=1) v+=__shfl_xor(v,off,64);
  __shared__ int ws[4];
  if((t&63)==0) ws[t>>6]=v;
  __syncthreads();
  if(t==0) bsum[blockIdx.x]=ws[0]+ws[1]+ws[2]+ws[3];
}

__global__ __launch_bounds__(256) void scan_top(int* __restrict__ bsum, int nb){
  __shared__ int p[256];
  int t=threadIdx.x;
  int v=(t<nb)?bsum[t]:0;
  p[t]=v; __syncthreads();
  #pragma unroll
  for(int off=1;off<256;off<<=1){
    int u=(t>=off)?p[t-off]:0;
    __syncthreads(); p[t]+=u; __syncthreads();
  }
  if(t<nb) bsum[t]=p[t]-v;   // exclusive block offsets
}

__global__ __launch_bounds__(256) void scan_final(const int* __restrict__ cnt,
    const int* __restrict__ boff, int n, int* __restrict__ ptr){
  int t=threadIdx.x, b=blockIdx.x, i=b*256+t;
  int v=(i<n)?cnt[i]:0;
  __shared__ int p[256];
  p[t]=v; __syncthreads();
  #pragma unroll
  for(int off=1;off<256;off<<=1){
    int u=(t>=off)?p[t-off]:0;
    __syncthreads(); p[t]+=u; __syncthreads();
  }
  int ex=boff[b]+p[t]-v;
  if(i<n){
    ptr[i]=ex;
    if(i==n-1) ptr[n]=ex+v;
  }
}

// gcur[b] = start of bin b's region (= CSR offset of node b*256)
__global__ void binit_kernel(const int* __restrict__ rowptr, int* __restrict__ gcur){
  int t=threadIdx.x;
  if(t<NBIN) gcur[t]=rowptr[t<<8];
  else gcur[t]=0;
}

// ---------------- edge_attr dot for ALL 4 layers, one coalesced pass ----------------
__global__ __launch_bounds__(256) void edprep_kernel(const float* __restrict__ edge_attr,
    const float* __restrict__ We0, const float* __restrict__ ae0,
    const float* __restrict__ We,  const float* __restrict__ ae,
    float* __restrict__ ed4){
  __shared__ float sw[4][ED];
  __shared__ float tile[256*ED];
  int t=threadIdx.x;
  if(t<4*ED){
    int l=t/ED, j=t%ED;
    const float* wp=(l==0)? (We0+(size_t)j*C) : (We+((size_t)(l-1)*ED+j)*C);
    const float* ap=(l==0)? ae0 : (ae+(size_t)(l-1)*C);
    float s=0.f;
    for(int c=0;c<C;++c) s+=wp[c]*ap[c];
    sw[l][j]=s;
  }
  __syncthreads();
  size_t e0=(size_t)blockIdx.x*256;
  int cnt=(int)min((size_t)256,(size_t)NE-e0);
  for(int i=t;i<cnt*ED;i+=256) tile[i]=edge_attr[e0*ED+i];
  __syncthreads();
  if(t<cnt){
    float4 r;
    float d0=0,d1=0,d2=0,d3=0;
    #pragma unroll
    for(int j=0;j<ED;++j){
      float ev=tile[t*ED+j];
      d0=fmaf(ev,sw[0][j],d0);
      d1=fmaf(ev,sw[1][j],d1);
      d2=fmaf(ev,sw[2][j],d2);
      d3=fmaf(ev,sw[3][j],d3);
    }
    r.x=d0; r.y=d1; r.z=d2; r.w=d3;
    *(float4*)&ed4[(e0+t)*4]=r;
  }
}

// ---------------- Pass A: block counting-sort partition into 196 dst-bins ----------------
__global__ __launch_bounds__(256) void part_kernel(const int* __restrict__ dst,
    const int* __restrict__ src, const float* __restrict__ ed4,
    int* __restrict__ gcur,
    ull* __restrict__ pdst_src, float2* __restrict__ ped01, float2* __restrict__ ped23){
  __shared__ ull    ldst_src[PA_EDGES];      // 16KB
  __shared__ float2 led01[PA_EDGES];         // 16KB
  __shared__ float2 led23[PA_EDGES];         // 16KB
  __shared__ unsigned char lbin[PA_EDGES];   // 2KB
  __shared__ int hist[256], p[256], sc[256], lofs[256], bbase[256];
  int t=threadIdx.x;
  hist[t]=0;
  __syncthreads();
  size_t e0=(size_t)blockIdx.x*PA_EDGES;
  int cnt=(int)min((size_t)PA_EDGES,(size_t)NE-e0);
  for(int i=t;i<cnt;i+=256) atomicAdd(&hist[dst[e0+i]>>8],1);
  __syncthreads();
  p[t]=hist[t]; __syncthreads();
  #pragma unroll
  for(int off=1;off<256;off<<=1){
    int u=(t>=off)?p[t-off]:0;
    __syncthreads(); p[t]+=u; __syncthreads();
  }
  sc[t]=p[t]-hist[t];
  lofs[t]=sc[t];
  bbase[t]=(hist[t]>0)?atomicAdd(&gcur[t],hist[t]):0;
  __syncthreads();
  for(int i=t;i<cnt;i+=256){
    int d=dst[e0+i], s=src[e0+i];
    int b=d>>8;
    int slot=atomicAdd(&lofs[b],1);
    ldst_src[slot]=((ull)(unsigned)d<<32)|(unsigned)s;
    float4 v=*(const float4*)&ed4[(e0+i)*4];
    led01[slot]=make_float2(v.x,v.y);
    led23[slot]=make_float2(v.z,v.w);
    lbin[slot]=(unsigned char)b;
  }
  __syncthreads();
  for(int i=t;i<cnt;i+=256){
    int b=lbin[i];
    int g=bbase[b]+i-sc[b];
    pdst_src[g]=ldst_src[i];
    ped01[g]=led01[i];
    ped23[g]=led23[i];
  }
}

// ---------------- Pass B: bin -> exact CSR slots ----------------
__global__ __launch_bounds__(256) void build_kernel(const ull* __restrict__ pdst_src,
    const float2* __restrict__ ped01, const float2* __restrict__ ped23,
    const int* __restrict__ rowptr,
    int* __restrict__ src_csr, float* __restrict__ edc){
  __shared__ int cur[256];
  int t=threadIdx.x, b=blockIdx.x;
  int n0=b<<8;
  cur[t]=(n0+t<NN)?rowptr[n0+t]:0;
  __syncthreads();
  int n1=min(NN,n0+256);
  int beg=rowptr[n0], endd=rowptr[n1];
  for(int j=beg+t;j<endd;j+=256){
    ull ds=pdst_src[j];
    int d=(int)(ds>>32);
    int s=(int)(ds&0xffffffffu);
    int pos=atomicAdd(&cur[d-n0],1);
    src_csr[pos]=s;
    float2 a=ped01[j], c=ped23[j];
    edc[pos]=a.x;
    edc[(size_t)NE+pos]=a.y;
    edc[2*(size_t)NE+pos]=c.x;
    edc[3*(size_t)NE+pos]=c.y;
  }
}

// ---------------- per-layer features: register-blocked vector GEMM ----------------
// Block = 64 nodes. Lane computes 4 nodes x 4 cols (32 f32 accums).
// Per k: 2x ds_read_b128 (W,Wres) + 4x broadcast ds_read_b32 (x) feed 32 FMAs.
template<int FIN, int SXS>
__global__ __launch_bounds__(256) void feat_kernel(const float* __restrict__ in,
    const float* __restrict__ W, const float* __restrict__ Wres,
    const float* __restrict__ bvec, const float* __restrict__ av_src,
    const float* __restrict__ av_dst,
    __half* __restrict__ hW16, float* __restrict__ outb,
    float* __restrict__ as_, float* __restrict__ ad_){
  __shared__ float sW[FIN*C], sR[FIN*C];
  __shared__ float sx[64*SXS];
  __shared__ float sb[C], ss[C], sd[C];
  int tid=threadIdx.x;
  if(tid<C){ sb[tid]=bvec[tid]; ss[tid]=av_src[tid]; sd[tid]=av_dst[tid]; }
  for(int i=tid;i<FIN*C;i+=256){ sW[i]=W[i]; sR[i]=Wres[i]; }
  int nbase=blockIdx.x*64;
  int nvalid=min(64,NN-nbase);
  // stage x[64][FIN] -> sx (stride SXS; SXS%8==4 so node-groups split banks 2-way = free)
  if constexpr (FIN==64){
    const float4* in4=(const float4*)(in+(size_t)nbase*64);
    for(int i=tid;i<1024;i+=256){
      int n=i>>4, k=(i&15)*4;
      float4 v=(n<nvalid)?in4[i]:make_float4(0.f,0.f,0.f,0.f);
      *(float4*)&sx[n*SXS+k]=v;
    }
  } else {
    for(int i=tid;i<64*FIN;i+=256){
      int n=i/FIN, k=i-n*FIN;
      sx[n*SXS+k]=(n<nvalid)?in[(size_t)(nbase+n)*FIN+k]:0.f;
    }
  }
  __syncthreads();
  int w=tid>>6, lane=tid&63;
  int ng=lane>>4, cl=lane&15;
  int n0=w*16+ng*4;                  // block-local first node of this lane's 4
  int c0=cl*4;
  float hw[4][4]={}, hr[4][4]={};
  const float* sxp=&sx[n0*SXS];
  #pragma unroll 4
  for(int k=0;k<FIN;++k){
    float4 wv=*(const float4*)&sW[k*C+c0];
    float4 rv=*(const float4*)&sR[k*C+c0];
    float xr[4]={sxp[k],sxp[SXS+k],sxp[2*SXS+k],sxp[3*SXS+k]};
    #pragma unroll
    for(int r=0;r<4;++r){
      hw[r][0]=fmaf(xr[r],wv.x,hw[r][0]);
      hw[r][1]=fmaf(xr[r],wv.y,hw[r][1]);
      hw[r][2]=fmaf(xr[r],wv.z,hw[r][2]);
      hw[r][3]=fmaf(xr[r],wv.w,hw[r][3]);
      hr[r][0]=fmaf(xr[r],rv.x,hr[r][0]);
      hr[r][1]=fmaf(xr[r],rv.y,hr[r][1]);
      hr[r][2]=fmaf(xr[r],rv.z,hr[r][2]);
      hr[r][3]=fmaf(xr[r],rv.w,hr[r][3]);
    }
  }
  float s0=ss[c0], s1=ss[c0+1], s2=ss[c0+2], s3=ss[c0+3];
  float d0=sd[c0], d1=sd[c0+1], d2=sd[c0+2], d3=sd[c0+3];
  float b0v=sb[c0], b1v=sb[c0+1], b2v=sb[c0+2], b3v=sb[c0+3];
  #pragma unroll
  for(int r=0;r<4;++r){
    int n=n0+r;
    float ps=hw[r][0]*s0+hw[r][1]*s1+hw[r][2]*s2+hw[r][3]*s3;
    float pd=hw[r][0]*d0+hw[r][1]*d1+hw[r][2]*d2+hw[r][3]*d3;
    #pragma unroll
    for(int off=1;off<16;off<<=1){ ps+=__shfl_xor(ps,off,64); pd+=__shfl_xor(pd,off,64); }
    if(n<nvalid){
      size_t gn=(size_t)(nbase+n);
      ushort4 hv;
      hv.x=__half_as_ushort(__float2half(hw[r][0]));
      hv.y=__half_as_ushort(__float2half(hw[r][1]));
      hv.z=__half_as_ushort(__float2half(hw[r][2]));
      hv.w=__half_as_ushort(__float2half(hw[r][3]));
      *(ushort4*)&hW16[gn*C+c0]=hv;
      float4 ov;
      ov.x=hr[r][0]+b0v; ov.y=hr[r][1]+b1v; ov.z=hr[r][2]+b2v; ov.w=hr[r][3]+b3v;
      *(float4*)&outb[gn*C+c0]=ov;
      if(cl==0){ as_[gn]=ps; ad_[gn]=pd; }
    }
  }
}

// ------- fused alpha + softmax aggregation, wave per dst node -------
__global__ __launch_bounds__(256) void agg_kernel(const int* __restrict__ rowptr,
    const int* __restrict__ src_csr, const float* __restrict__ edc_l,
    const float* __restrict__ as_, const float* __restrict__ ad_,
    const __half* __restrict__ hW16, float* __restrict__ outb, int relu){
  __shared__ float2 sws[4][64];          // per-wave (wl, sl-as-bits)
  int w=threadIdx.x>>6, lane=threadIdx.x&63;
  int nidx=blockIdx.x*4+w;
  if(nidx>=NN) return;
  int beg=rowptr[nidx], end=rowptr[nidx+1];
  int deg=end-beg;
  float ad_n=ad_[nidx];
  int g=lane>>4, gl=lane&15;
  const uint2* hw2=(const uint2*)hW16;   // row = 16 uint2 (4 halves each)
  float s=0.f;
  float ax=0.f, ay=0.f, az=0.f, aw=0.f;

  if(deg<=64){
    int j=beg+lane;
    float al=-INFINITY; int sl=0;
    if(lane<deg){
      sl=src_csr[j];
      float a=as_[sl]+ad_n+edc_l[j];
      al=(a>0.f)?a:0.2f*a;               // leaky_relu 0.2
    }
    float mn=al;
    #pragma unroll
    for(int off=32;off;off>>=1) mn=fmaxf(mn,__shfl_xor(mn,off,64));
    float wl=(lane<deg)?__expf(al-mn):0.f;
    s=wl;
    #pragma unroll
    for(int off=32;off;off>>=1) s+=__shfl_xor(s,off,64);
    float2 pr; pr.x=wl; pr.y=__int_as_float(sl);
    sws[w][lane]=pr;                     // wave-private slice: no barrier
    for(int t=g;t<deg;t+=4){
      float2 r=sws[w][t];                // group-uniform addr -> broadcast
      float at=r.x;
      int   st=__float_as_int(r.y);
      uint2 u=hw2[(size_t)st*16+gl];
      __half2 h0=*(__half2*)&u.x;
      __half2 h1=*(__half2*)&u.y;
      float2 f0=__half22float2(h0);
      float2 f1=__half22float2(h1);
      ax=fmaf(at,f0.x,ax);
      ay=fmaf(at,f0.y,ay);
      az=fmaf(at,f1.x,az);
      aw=fmaf(at,f1.y,aw);
    }
  } else {
    float m=-INFINITY;
    for(int base=beg;base<end;base+=64){
      int j=base+lane;
      float al=-INFINITY; int sl=0;
      if(j<end){
        sl=src_csr[j];
        float a=as_[sl]+ad_n+edc_l[j];
        al=(a>0.f)?a:0.2f*a;
      }
      float cm=al;
      #pragma unroll
      for(int off=32;off;off>>=1) cm=fmaxf(cm,__shfl_xor(cm,off,64));
      float mn=fmaxf(m,cm);
      float scale=(m==-INFINITY)?0.f:__expf(m-mn);
      s*=scale; ax*=scale; ay*=scale; az*=scale; aw*=scale;
      float wl=(j<end)?__expf(al-mn):0.f;
      float cs=wl;
      #pragma unroll
      for(int off=32;off;off>>=1) cs+=__shfl_xor(cs,off,64);
      s+=cs; m=mn;
      float2 pr; pr.x=wl; pr.y=__int_as_float(sl);
      sws[w][lane]=pr;
      int cnt=min(64,end-base);
      for(int t=g;t<cnt;t+=4){
        float2 r=sws[w][t];
        float at=r.x;
        int   st=__float_as_int(r.y);
        uint2 u=hw2[(size_t)st*16+gl];
        __half2 h0=*(__half2*)&u.x;
        __half2 h1=*(__half2*)&u.y;
        float2 f0=__half22float2(h0);
        float2 f1=__half22float2(h1);
        ax=fmaf(at,f0.x,ax);
        ay=fmaf(at,f0.y,ay);
        az=fmaf(at,f1.x,az);
        aw=fmaf(at,f1.y,aw);
      }
    }
  }

  #pragma unroll
  for(int off=16;off<64;off<<=1){
    ax+=__shfl_xor(ax,off,64);
    ay+=__shfl_xor(ay,off,64);
    az+=__shfl_xor(az,off,64);
    aw+=__shfl_xor(aw,off,64);
  }
  if(g==0){
    float inv=s+1e-16f;
    float4 o=*(float4*)&outb[(size_t)nidx*C+gl*4];
    float4 v;
    v.x=ax/inv+o.x; v.y=ay/inv+o.y; v.z=az/inv+o.z; v.w=aw/inv+o.w;
    if(relu){
      v.x=(v.x>0.f)?v.x:0.01f*v.x;
      v.y=(v.y>0.f)?v.y:0.01f*v.y;
      v.z=(v.z>0.f)?v.z:0.01f*v.z;
      v.w=(v.w>0.f)?v.w:0.01f*v.w;
    }
    *(float4*)&outb[(size_t)nidx*C+gl*4]=v;
  }
}

// ---------------- pooling (max + mean per graph) ----------------
__global__ __launch_bounds__(256) void pool_kernel(const float* __restrict__ h,
    const int* __restrict__ growptr, float* __restrict__ pooled){
  int w=threadIdx.x>>6, lane=threadIdx.x&63;
  int g=blockIdx.x*4+w;
  if(g>=NG) return;
  int beg=growptr[g], end=growptr[g+1];
  float mx=-INFINITY, sm=0.f;
  for(int n=beg;n<end;++n){ float v=h[(size_t)n*C+lane]; mx=fmaxf(mx,v); sm+=v; }
  int cnt=end-beg;
  float gm=(cnt==0)?0.f:mx;              // isfinite fix for empty graphs
  float mean=sm/fmaxf((float)cnt,1.f);
  gm=(gm>0.f)?gm:0.01f*gm;               // leaky_relu 0.01 on pooled
  mean=(mean>0.f)?mean:0.01f*mean;
  pooled[(size_t)g*128+lane]=gm;
  pooled[(size_t)g*128+64+lane]=mean;
}

// ---------------- final linear: [G,128] @ [128,256] + bias ----------------
__global__ __launch_bounds__(256) void out_kernel(const float* __restrict__ pooled,
    const float* __restrict__ Wout, const float* __restrict__ bout,
    float* __restrict__ out){
  __shared__ float sp[128];
  int g=blockIdx.x, d=threadIdx.x;
  if(d<128) sp[d]=pooled[(size_t)g*128+d];
  __syncthreads();
  float o=bout[d];
  for(int k=0;k<128;++k) o=fmaf(sp[k],Wout[k*DOUT+d],o);
  out[(size_t)g*DOUT+d]=o;
}

extern "C" void kernel_launch(void* const* d_in, const int* in_sizes, int n_in,
                              void* d_out, int out_size, void* d_ws, size_t ws_size,
                              hipStream_t stream){
  const float* x        =(const float*)d_in[0];
  const float* edge_attr=(const float*)d_in[1];
  const float* W0       =(const float*)d_in[2];
  const float* asrc0    =(const float*)d_in[3];
  const float* adst0    =(const float*)d_in[4];
  const float* We0      =(const float*)d_in[5];
  const float* ae0      =(const float*)d_in[6];
  const float* Wres0    =(const float*)d_in[7];
  const float* b0       =(const float*)d_in[8];
  const float* W        =(const float*)d_in[9];
  const float* asrc     =(const float*)d_in[10];
  const float* adst     =(const float*)d_in[11];
  const float* We       =(const float*)d_in[12];
  const float* ae       =(const float*)d_in[13];
  const float* Wres     =(const float*)d_in[14];
  const float* b        =(const float*)d_in[15];
  const float* Wout     =(const float*)d_in[16];
  const float* bout     =(const float*)d_in[17];
  const int* edge_index =(const int*)d_in[18];
  const int* batch_index=(const int*)d_in[19];
  const int* src=edge_index;
  const int* dst=edge_index+NE;

  // workspace carve (~67 MB, with aliased regions)
  char* p=(char*)d_ws;
  auto take=[&](size_t bytes)->void*{ void* r=(void*)p; p+=(bytes+255)&~(size_t)255; return r; };
  int* deg     =(int*)take((size_t)NN*4);
  int* rowptr  =(int*)take((size_t)(NN+1)*4);
  int* gcnt    =(int*)take((size_t)NG*4);
  int* growptr =(int*)take((size_t)(NG+1)*4);
  int* bsumN   =(int*)take((size_t)256*4);
  int* bsumG   =(int*)take((size_t)256*4);
  int* gcur    =(int*)take((size_t)256*4);
  int* src_csr =(int*)take((size_t)NE*4);
  float* as_   =(float*)take((size_t)NN*4);
  float* ad_   =(float*)take((size_t)NN*4);
  float* edc   =(float*)take((size_t)NE*4*4);     // 4 layers x NE, CSR order (SoA)
  __half* hW16 =(__half*)take((size_t)NN*C*2);
  // region R1: ed4 (16MB) -> later bufA (12.8MB)
  float* ed4   =(float*)take((size_t)NE*4*4);
  float* bufA  =ed4;
  // region R2: pdst_src (8MB) -> later pooled (0.5MB)
  ull* pdst_src=(ull*)take((size_t)NE*8);
  float* pooled=(float*)pdst_src;
  // region R3: ped01+ped23 (16MB) -> later bufB (12.8MB)
  float2* ped01=(float2*)take((size_t)NE*8);
  float2* ped23=(float2*)take((size_t)NE*8);
  float* bufB  =(float*)ped01;
  (void)ws_size; (void)in_sizes; (void)n_in; (void)out_size;

  hipMemsetAsync(deg,0,(size_t)NN*4,stream);
  hipMemsetAsync(gcnt,0,(size_t)NG*4,stream);
  hist_kernel<<<2048,256,0,stream>>>(dst,NE,deg);
  hist_kernel<<<256,256,0,stream>>>(batch_index,NN,gcnt);

  const int nbN=(NN+255)/256;      // 196
  const int nbG=(NG+255)/256;      // 4
  scan_part<<<nbN,256,0,stream>>>(deg,NN,bsumN);
  scan_top<<<1,256,0,stream>>>(bsumN,nbN);
  scan_final<<<nbN,256,0,stream>>>(deg,bsumN,NN,rowptr);
  scan_part<<<nbG,256,0,stream>>>(gcnt,NG,bsumG);
  scan_top<<<1,256,0,stream>>>(bsumG,nbG);
  scan_final<<<nbG,256,0,stream>>>(gcnt,bsumG,NG,growptr);
  binit_kernel<<<1,256,0,stream>>>(rowptr,gcur);

  edprep_kernel<<<(NE+255)/256,256,0,stream>>>(edge_attr,We0,ae0,We,ae,ed4);
  part_kernel<<<(NE+PA_EDGES-1)/PA_EDGES,256,0,stream>>>(dst,src,ed4,gcur,
      pdst_src,ped01,ped23);
  build_kernel<<<NBIN,256,0,stream>>>(pdst_src,ped01,ped23,rowptr,src_csr,edc);

  const int nblkF=(NN+63)/64;      // 782
  const int nblkA=(NN+3)/4;        // 12500
  // layer 0 (F=30, sx stride 36)
  feat_kernel<FIN0,36><<<nblkF,256,0,stream>>>(x,W0,Wres0,b0,asrc0,adst0,hW16,bufA,as_,ad_);
  agg_kernel<<<nblkA,256,0,stream>>>(rowptr,src_csr,edc,as_,ad_,hW16,bufA,1);
  // layers 1..3 (ping-pong; sx stride 68)
  float* bin=bufA; float* bo=bufB;
  for(int i=0;i<3;++i){
    feat_kernel<C,68><<<nblkF,256,0,stream>>>(bin,W+(size_t)i*C*C,Wres+(size_t)i*C*C,
        b+(size_t)i*C,asrc+(size_t)i*C,adst+(size_t)i*C,hW16,bo,as_,ad_);
    agg_kernel<<<nblkA,256,0,stream>>>(rowptr,src_csr,edc+(size_t)(i+1)*NE,as_,ad_,hW16,bo,(i<2)?1:0);
    float* t=bin; bin=bo; bo=t;
  }
  pool_kernel<<<(NG+3)/4,256,0,stream>>>(bin,growptr,pooled);
  out_kernel<<<NG,256,0,stream>>>(pooled,Wout,bout,(float*)d_out);
}

// Round 8
// 355.656 us; speedup vs baseline: 2.3209x; 1.1414x over previous
//
#include <hip/hip_runtime.h>
#include <hip/hip_fp16.h>

// Problem constants (from reference)
#define NN 50000
#define NE 1000000
#define FIN0 30
#define C 64
#define ED 11
#define NG 1024
#define DOUT 256
#define NBIN 196            // ceil(NN/256)
#define PA_EDGES 2048       // edges per partition block

typedef unsigned long long ull;

// ---------------- bin histogram (196 bins, LDS-privatized) ----------------
__global__ __launch_bounds__(256) void hist196_kernel(const int* __restrict__ dst,
    int* __restrict__ bcnt){
  __shared__ int h[256];
  int t=threadIdx.x;
  h[t]=0;
  __syncthreads();
  for(int i=blockIdx.x*256+t;i<NE;i+=gridDim.x*256)
    atomicAdd(&h[dst[i]>>8],1);
  __syncthreads();
  if(h[t]) atomicAdd(&bcnt[t],h[t]);
}

// single block: exclusive scan of 256 bin counts -> bbase (197 used) + gcur copy
__global__ __launch_bounds__(256) void scan196_kernel(const int* __restrict__ bcnt,
    int* __restrict__ bbase, int* __restrict__ gcur){
  __shared__ int p[256];
  int t=threadIdx.x;
  int v=bcnt[t];
  p[t]=v; __syncthreads();
  #pragma unroll
  for(int off=1;off<256;off<<=1){
    int u=(t>=off)?p[t-off]:0;
    __syncthreads(); p[t]+=u; __syncthreads();
  }
  int ex=p[t]-v;
  if(t<=NBIN) bbase[t]=ex;
  if(t<NBIN)  gcur[t]=ex;
}

// growptr from SORTED batch_index (boundary detection; handles empty graphs)
__global__ __launch_bounds__(256) void grow_kernel(const int* __restrict__ batch,
    int* __restrict__ growptr){
  int i=blockIdx.x*256+threadIdx.x;
  if(i>=NN) return;
  int bi=batch[i];
  int bp=(i==0)?-1:batch[i-1];
  for(int g=bp+1;g<=bi;++g) growptr[g]=i;
  if(i==NN-1){ for(int g=bi+1;g<=NG;++g) growptr[g]=NN; }
}

// ---------------- Pass A: counting-sort partition + fused edge_attr dots ----------------
__global__ __launch_bounds__(256) void part_kernel(const int* __restrict__ dst,
    const int* __restrict__ src, const float* __restrict__ edge_attr,
    const float* __restrict__ We0, const float* __restrict__ ae0,
    const float* __restrict__ We,  const float* __restrict__ ae,
    int* __restrict__ gcur,
    ull* __restrict__ pdst_src, float2* __restrict__ ped01, float2* __restrict__ ped23){
  __shared__ ull    ldst_src[PA_EDGES];      // 16KB
  __shared__ float2 led01[PA_EDGES];         // 16KB
  __shared__ float2 led23[PA_EDGES];         // 16KB
  __shared__ unsigned char lbin[PA_EDGES];   // 2KB
  __shared__ float tile[256*ED];             // 11KB
  __shared__ float sw[4][ED];
  __shared__ int hist[256], p[256], sc[256], lofs[256], bb[256];
  int t=threadIdx.x;
  hist[t]=0;
  if(t<4*ED){
    int l=t/ED, j=t%ED;
    const float* wp=(l==0)? (We0+(size_t)j*C) : (We+((size_t)(l-1)*ED+j)*C);
    const float* ap=(l==0)? ae0 : (ae+(size_t)(l-1)*C);
    float s=0.f;
    for(int c=0;c<C;++c) s+=wp[c]*ap[c];
    sw[l][j]=s;
  }
  __syncthreads();
  size_t e0=(size_t)blockIdx.x*PA_EDGES;
  int cnt=(int)min((size_t)PA_EDGES,(size_t)NE-e0);
  for(int i=t;i<cnt;i+=256) atomicAdd(&hist[dst[e0+i]>>8],1);
  __syncthreads();
  p[t]=hist[t]; __syncthreads();
  #pragma unroll
  for(int off=1;off<256;off<<=1){
    int u=(t>=off)?p[t-off]:0;
    __syncthreads(); p[t]+=u; __syncthreads();
  }
  sc[t]=p[t]-hist[t];
  lofs[t]=sc[t];
  bb[t]=(hist[t]>0)?atomicAdd(&gcur[t],hist[t]):0;
  __syncthreads();
  // per-256-edge slice: stage edge_attr (coalesced), compute dots, place bin-sorted
  for(int base=0;base<cnt;base+=256){
    int ccnt=min(256,cnt-base);
    for(int i=t;i<ccnt*ED;i+=256) tile[i]=edge_attr[(e0+base)*ED+i];
    __syncthreads();
    if(t<ccnt){
      int i=base+t;
      int d=dst[e0+i], s=src[e0+i];
      int b=d>>8;
      float d0=0,d1=0,d2=0,d3=0;
      #pragma unroll
      for(int j=0;j<ED;++j){
        float ev=tile[t*ED+j];
        d0=fmaf(ev,sw[0][j],d0);
        d1=fmaf(ev,sw[1][j],d1);
        d2=fmaf(ev,sw[2][j],d2);
        d3=fmaf(ev,sw[3][j],d3);
      }
      int slot=atomicAdd(&lofs[b],1);
      ldst_src[slot]=((ull)(unsigned)d<<32)|(unsigned)s;
      led01[slot]=make_float2(d0,d1);
      led23[slot]=make_float2(d2,d3);
      lbin[slot]=(unsigned char)b;
    }
    __syncthreads();
  }
  // coalesced flush
  for(int i=t;i<cnt;i+=256){
    int b=lbin[i];
    int g=bb[b]+i-sc[b];
    pdst_src[g]=ldst_src[i];
    ped01[g]=led01[i];
    ped23[g]=led23[i];
  }
}

// ---------------- Pass B: bin -> exact CSR slots; also emits rowptr ----------------
__global__ __launch_bounds__(256) void build_kernel(const ull* __restrict__ pdst_src,
    const float2* __restrict__ ped01, const float2* __restrict__ ped23,
    const int* __restrict__ bbase,
    int* __restrict__ rowptr, int* __restrict__ src_csr, float* __restrict__ edc){
  __shared__ int cnt[256], p[256], cur[256];
  int t=threadIdx.x, b=blockIdx.x;
  int n0=b<<8;
  cnt[t]=0;
  __syncthreads();
  int beg=bbase[b], endd=bbase[b+1];
  for(int j=beg+t;j<endd;j+=256)
    atomicAdd(&cnt[(int)(pdst_src[j]>>32)-n0],1);
  __syncthreads();
  int v=cnt[t];
  p[t]=v; __syncthreads();
  #pragma unroll
  for(int off=1;off<256;off<<=1){
    int u=(t>=off)?p[t-off]:0;
    __syncthreads(); p[t]+=u; __syncthreads();
  }
  int ex=p[t]-v;
  cur[t]=beg+ex;
  if(n0+t<NN) rowptr[n0+t]=beg+ex;
  if(b==0&&t==0) rowptr[NN]=NE;
  __syncthreads();
  for(int j=beg+t;j<endd;j+=256){
    ull ds=pdst_src[j];
    int d=(int)(ds>>32);
    int s=(int)(ds&0xffffffffu);
    int pos=atomicAdd(&cur[d-n0],1);
    src_csr[pos]=s;
    float2 a=ped01[j], c=ped23[j];
    edc[pos]=a.x;
    edc[(size_t)NE+pos]=a.y;
    edc[2*(size_t)NE+pos]=c.x;
    edc[3*(size_t)NE+pos]=c.y;
  }
}

// ---------------- per-layer features: register-blocked vector GEMM ----------------
template<int FIN, int SXS>
__global__ __launch_bounds__(256) void feat_kernel(const float* __restrict__ in,
    const float* __restrict__ W, const float* __restrict__ Wres,
    const float* __restrict__ bvec, const float* __restrict__ av_src,
    const float* __restrict__ av_dst,
    __half* __restrict__ hW16, float* __restrict__ outb,
    float* __restrict__ as_, float* __restrict__ ad_){
  __shared__ float sW[FIN*C], sR[FIN*C];
  __shared__ float sx[64*SXS];
  __shared__ float sb[C], ss[C], sd[C];
  int tid=threadIdx.x;
  if(tid<C){ sb[tid]=bvec[tid]; ss[tid]=av_src[tid]; sd[tid]=av_dst[tid]; }
  for(int i=tid;i<FIN*C;i+=256){ sW[i]=W[i]; sR[i]=Wres[i]; }
  int nbase=blockIdx.x*64;
  int nvalid=min(64,NN-nbase);
  if constexpr (FIN==64){
    const float4* in4=(const float4*)(in+(size_t)nbase*64);
    for(int i=tid;i<1024;i+=256){
      int n=i>>4, k=(i&15)*4;
      float4 v=(n<nvalid)?in4[i]:make_float4(0.f,0.f,0.f,0.f);
      *(float4*)&sx[n*SXS+k]=v;
    }
  } else {
    for(int i=tid;i<64*FIN;i+=256){
      int n=i/FIN, k=i-n*FIN;
      sx[n*SXS+k]=(n<nvalid)?in[(size_t)(nbase+n)*FIN+k]:0.f;
    }
  }
  __syncthreads();
  int w=tid>>6, lane=tid&63;
  int ng=lane>>4, cl=lane&15;
  int n0=w*16+ng*4;
  int c0=cl*4;
  float hw[4][4]={}, hr[4][4]={};
  const float* sxp=&sx[n0*SXS];
  #pragma unroll 4
  for(int k=0;k<FIN;++k){
    float4 wv=*(const float4*)&sW[k*C+c0];
    float4 rv=*(const float4*)&sR[k*C+c0];
    float xr[4]={sxp[k],sxp[SXS+k],sxp[2*SXS+k],sxp[3*SXS+k]};
    #pragma unroll
    for(int r=0;r<4;++r){
      hw[r][0]=fmaf(xr[r],wv.x,hw[r][0]);
      hw[r][1]=fmaf(xr[r],wv.y,hw[r][1]);
      hw[r][2]=fmaf(xr[r],wv.z,hw[r][2]);
      hw[r][3]=fmaf(xr[r],wv.w,hw[r][3]);
      hr[r][0]=fmaf(xr[r],rv.x,hr[r][0]);
      hr[r][1]=fmaf(xr[r],rv.y,hr[r][1]);
      hr[r][2]=fmaf(xr[r],rv.z,hr[r][2]);
      hr[r][3]=fmaf(xr[r],rv.w,hr[r][3]);
    }
  }
  float s0=ss[c0], s1=ss[c0+1], s2=ss[c0+2], s3=ss[c0+3];
  float d0=sd[c0], d1=sd[c0+1], d2=sd[c0+2], d3=sd[c0+3];
  float b0v=sb[c0], b1v=sb[c0+1], b2v=sb[c0+2], b3v=sb[c0+3];
  #pragma unroll
  for(int r=0;r<4;++r){
    int n=n0+r;
    float ps=hw[r][0]*s0+hw[r][1]*s1+hw[r][2]*s2+hw[r][3]*s3;
    float pd=hw[r][0]*d0+hw[r][1]*d1+hw[r][2]*d2+hw[r][3]*d3;
    #pragma unroll
    for(int off=1;off<16;off<<=1){ ps+=__shfl_xor(ps,off,64); pd+=__shfl_xor(pd,off,64); }
    if(n<nvalid){
      size_t gn=(size_t)(nbase+n);
      ushort4 hv;
      hv.x=__half_as_ushort(__float2half(hw[r][0]));
      hv.y=__half_as_ushort(__float2half(hw[r][1]));
      hv.z=__half_as_ushort(__float2half(hw[r][2]));
      hv.w=__half_as_ushort(__float2half(hw[r][3]));
      *(ushort4*)&hW16[gn*C+c0]=hv;
      float4 ov;
      ov.x=hr[r][0]+b0v; ov.y=hr[r][1]+b1v; ov.z=hr[r][2]+b2v; ov.w=hr[r][3]+b3v;
      *(float4*)&outb[gn*C+c0]=ov;
      if(cl==0){ as_[gn]=ps; ad_[gn]=pd; }
    }
  }
}

// ------- fused alpha + softmax aggregation, wave per dst node -------
// 8-lane groups x uint4 (16B) row slices: 8 edges in flight per load instr, 2x unroll.
__device__ __forceinline__ void acc8(float* a, float at, uint4 u){
  __half2 h0=*(__half2*)&u.x, h1=*(__half2*)&u.y, h2=*(__half2*)&u.z, h3=*(__half2*)&u.w;
  float2 f0=__half22float2(h0), f1=__half22float2(h1);
  float2 f2=__half22float2(h2), f3=__half22float2(h3);
  a[0]=fmaf(at,f0.x,a[0]); a[1]=fmaf(at,f0.y,a[1]);
  a[2]=fmaf(at,f1.x,a[2]); a[3]=fmaf(at,f1.y,a[3]);
  a[4]=fmaf(at,f2.x,a[4]); a[5]=fmaf(at,f2.y,a[5]);
  a[6]=fmaf(at,f3.x,a[6]); a[7]=fmaf(at,f3.y,a[7]);
}

__global__ __launch_bounds__(256) void agg_kernel(const int* __restrict__ rowptr,
    const int* __restrict__ src_csr, const float* __restrict__ edc_l,
    const float* __restrict__ as_, const float* __restrict__ ad_,
    const __half* __restrict__ hW16, float* __restrict__ outb, int relu){
  __shared__ float2 sws[4][64];          // per-wave (wl, sl-as-bits)
  int w=threadIdx.x>>6, lane=threadIdx.x&63;
  int nidx=blockIdx.x*4+w;
  if(nidx>=NN) return;
  int beg=rowptr[nidx], end=rowptr[nidx+1];
  int deg=end-beg;
  float ad_n=ad_[nidx];
  int g2=lane>>3, gl2=lane&7;
  const uint4* hw4=(const uint4*)hW16;   // row = 8 uint4 (8 halves each)
  float s=0.f;
  float acc[8]={0.f,0.f,0.f,0.f,0.f,0.f,0.f,0.f};

  if(deg<=64){
    int j=beg+lane;
    float al=-INFINITY; int sl=0;
    if(lane<deg){
      sl=src_csr[j];
      float a=as_[sl]+ad_n+edc_l[j];
      al=(a>0.f)?a:0.2f*a;               // leaky_relu 0.2
    }
    float mn=al;
    #pragma unroll
    for(int off=32;off;off>>=1) mn=fmaxf(mn,__shfl_xor(mn,off,64));
    float wl=(lane<deg)?__expf(al-mn):0.f;
    s=wl;
    #pragma unroll
    for(int off=32;off;off>>=1) s+=__shfl_xor(s,off,64);
    float2 pr; pr.x=wl; pr.y=__int_as_float(sl);
    sws[w][lane]=pr;                     // wave-private slice: no barrier
    int t=g2;
    for(; t+8<deg; t+=16){               // 2 independent loads in flight
      float2 r0=sws[w][t], r1=sws[w][t+8];
      uint4 u0=hw4[(size_t)__float_as_int(r0.y)*8+gl2];
      uint4 u1=hw4[(size_t)__float_as_int(r1.y)*8+gl2];
      acc8(acc,r0.x,u0);
      acc8(acc,r1.x,u1);
    }
    if(t<deg){
      float2 r=sws[w][t];
      uint4 u=hw4[(size_t)__float_as_int(r.y)*8+gl2];
      acc8(acc,r.x,u);
    }
  } else {
    // fallback: online softmax over 64-edge chunks (rare)
    float m=-INFINITY;
    for(int base=beg;base<end;base+=64){
      int j=base+lane;
      float al=-INFINITY; int sl=0;
      if(j<end){
        sl=src_csr[j];
        float a=as_[sl]+ad_n+edc_l[j];
        al=(a>0.f)?a:0.2f*a;
      }
      float cm=al;
      #pragma unroll
      for(int off=32;off;off>>=1) cm=fmaxf(cm,__shfl_xor(cm,off,64));
      float mn=fmaxf(m,cm);
      float scale=(m==-INFINITY)?0.f:__expf(m-mn);
      s*=scale;
      #pragma unroll
      for(int i=0;i<8;++i) acc[i]*=scale;
      float wl=(j<end)?__expf(al-mn):0.f;
      float cs=wl;
      #pragma unroll
      for(int off=32;off;off>>=1) cs+=__shfl_xor(cs,off,64);
      s+=cs; m=mn;
      float2 pr; pr.x=wl; pr.y=__int_as_float(sl);
      sws[w][lane]=pr;
      int cnt=min(64,end-base);
      int t=g2;
      for(; t+8<cnt; t+=16){
        float2 r0=sws[w][t], r1=sws[w][t+8];
        uint4 u0=hw4[(size_t)__float_as_int(r0.y)*8+gl2];
        uint4 u1=hw4[(size_t)__float_as_int(r1.y)*8+gl2];
        acc8(acc,r0.x,u0);
        acc8(acc,r1.x,u1);
      }
      if(t<cnt){
        float2 r=sws[w][t];
        uint4 u=hw4[(size_t)__float_as_int(r.y)*8+gl2];
        acc8(acc,r.x,u);
      }
    }
  }

  // combine the 8 groups (butterfly): lanes with same gl2 hold same channels
  #pragma unroll
  for(int off=8;off<64;off<<=1){
    #pragma unroll
    for(int i=0;i<8;++i) acc[i]+=__shfl_xor(acc[i],off,64);
  }
  if(g2==0){
    float denom=s+1e-16f;
    size_t o0=(size_t)nidx*C+gl2*8;
    float4 oa=*(float4*)&outb[o0];
    float4 ob=*(float4*)&outb[o0+4];
    float4 va,vb;
    va.x=acc[0]/denom+oa.x; va.y=acc[1]/denom+oa.y;
    va.z=acc[2]/denom+oa.z; va.w=acc[3]/denom+oa.w;
    vb.x=acc[4]/denom+ob.x; vb.y=acc[5]/denom+ob.y;
    vb.z=acc[6]/denom+ob.z; vb.w=acc[7]/denom+ob.w;
    if(relu){
      va.x=(va.x>0.f)?va.x:0.01f*va.x; va.y=(va.y>0.f)?va.y:0.01f*va.y;
      va.z=(va.z>0.f)?va.z:0.01f*va.z; va.w=(va.w>0.f)?va.w:0.01f*va.w;
      vb.x=(vb.x>0.f)?vb.x:0.01f*vb.x; vb.y=(vb.y>0.f)?vb.y:0.01f*vb.y;
      vb.z=(vb.z>0.f)?vb.z:0.01f*vb.z; vb.w=(vb.w>0.f)?vb.w:0.01f*vb.w;
    }
    *(float4*)&outb[o0]=va;
    *(float4*)&outb[o0+4]=vb;
  }
}

// ---------------- pooling (max + mean per graph) ----------------
__global__ __launch_bounds__(256) void pool_kernel(const float* __restrict__ h,
    const int* __restrict__ growptr, float* __restrict__ pooled){
  int w=threadIdx.x>>6, lane=threadIdx.x&63;
  int g=blockIdx.x*4+w;
  if(g>=NG) return;
  int beg=growptr[g], end=growptr[g+1];
  float mx=-INFINITY, sm=0.f;
  for(int n=beg;n<end;++n){ float v=h[(size_t)n*C+lane]; mx=fmaxf(mx,v); sm+=v; }
  int cnt=end-beg;
  float gm=(cnt==0)?0.f:mx;              // isfinite fix for empty graphs
  float mean=sm/fmaxf((float)cnt,1.f);
  gm=(gm>0.f)?gm:0.01f*gm;               // leaky_relu 0.01 on pooled
  mean=(mean>0.f)?mean:0.01f*mean;
  pooled[(size_t)g*128+lane]=gm;
  pooled[(size_t)g*128+64+lane]=mean;
}

// ---------------- final linear: [G,128] @ [128,256] + bias ----------------
__global__ __launch_bounds__(256) void out_kernel(const float* __restrict__ pooled,
    const float* __restrict__ Wout, const float* __restrict__ bout,
    float* __restrict__ out){
  __shared__ float sp[128];
  int g=blockIdx.x, d=threadIdx.x;
  if(d<128) sp[d]=pooled[(size_t)g*128+d];
  __syncthreads();
  float o=bout[d];
  for(int k=0;k<128;++k) o=fmaf(sp[k],Wout[k*DOUT+d],o);
  out[(size_t)g*DOUT+d]=o;
}

extern "C" void kernel_launch(void* const* d_in, const int* in_sizes, int n_in,
                              void* d_out, int out_size, void* d_ws, size_t ws_size,
                              hipStream_t stream){
  const float* x        =(const float*)d_in[0];
  const float* edge_attr=(const float*)d_in[1];
  const float* W0       =(const float*)d_in[2];
  const float* asrc0    =(const float*)d_in[3];
  const float* adst0    =(const float*)d_in[4];
  const float* We0      =(const float*)d_in[5];
  const float* ae0      =(const float*)d_in[6];
  const float* Wres0    =(const float*)d_in[7];
  const float* b0       =(const float*)d_in[8];
  const float* W        =(const float*)d_in[9];
  const float* asrc     =(const float*)d_in[10];
  const float* adst     =(const float*)d_in[11];
  const float* We       =(const float*)d_in[12];
  const float* ae       =(const float*)d_in[13];
  const float* Wres     =(const float*)d_in[14];
  const float* b        =(const float*)d_in[15];
  const float* Wout     =(const float*)d_in[16];
  const float* bout     =(const float*)d_in[17];
  const int* edge_index =(const int*)d_in[18];
  const int* batch_index=(const int*)d_in[19];
  const int* src=edge_index;
  const int* dst=edge_index+NE;

  // workspace carve (~64 MB, with aliased regions)
  char* p=(char*)d_ws;
  auto take=[&](size_t bytes)->void*{ void* r=(void*)p; p+=(bytes+255)&~(size_t)255; return r; };
  int* rowptr  =(int*)take((size_t)(NN+1)*4);
  int* growptr =(int*)take((size_t)(NG+1)*4);
  int* bcnt    =(int*)take((size_t)256*4);
  int* bbase   =(int*)take((size_t)256*4);
  int* gcur    =(int*)take((size_t)256*4);
  int* src_csr =(int*)take((size_t)NE*4);
  float* as_   =(float*)take((size_t)NN*4);
  float* ad_   =(float*)take((size_t)NN*4);
  float* edc   =(float*)take((size_t)NE*4*4);     // 4 layers x NE, CSR order (SoA)
  __half* hW16 =(__half*)take((size_t)NN*C*2);
  float* bufA  =(float*)take((size_t)NN*C*4);
  // region R2: pdst_src (8MB) -> later pooled (0.5MB)
  ull* pdst_src=(ull*)take((size_t)NE*8);
  float* pooled=(float*)pdst_src;
  // region R3: ped01+ped23 (16MB) -> later bufB (12.8MB)
  float2* ped01=(float2*)take((size_t)NE*8);
  float2* ped23=(float2*)take((size_t)NE*8);
  float* bufB  =(float*)ped01;
  (void)ws_size; (void)in_sizes; (void)n_in; (void)out_size;

  hipMemsetAsync(bcnt,0,(size_t)256*4,stream);
  hist196_kernel<<<1024,256,0,stream>>>(dst,bcnt);
  scan196_kernel<<<1,256,0,stream>>>(bcnt,bbase,gcur);
  grow_kernel<<<(NN+255)/256,256,0,stream>>>(batch_index,growptr);

  part_kernel<<<(NE+PA_EDGES-1)/PA_EDGES,256,0,stream>>>(dst,src,edge_attr,
      We0,ae0,We,ae,gcur,pdst_src,ped01,ped23);
  build_kernel<<<NBIN,256,0,stream>>>(pdst_src,ped01,ped23,bbase,rowptr,src_csr,edc);

  const int nblkF=(NN+63)/64;      // 782
  const int nblkA=(NN+3)/4;        // 12500
  // layer 0 (F=30, sx stride 36)
  feat_kernel<FIN0,36><<<nblkF,256,0,stream>>>(x,W0,Wres0,b0,asrc0,adst0,hW16,bufA,as_,ad_);
  agg_kernel<<<nblkA,256,0,stream>>>(rowptr,src_csr,edc,as_,ad_,hW16,bufA,1);
  // layers 1..3 (ping-pong; sx stride 68)
  float* bin=bufA; float* bo=bufB;
  for(int i=0;i<3;++i){
    feat_kernel<C,68><<<nblkF,256,0,stream>>>(bin,W+(size_t)i*C*C,Wres+(size_t)i*C*C,
        b+(size_t)i*C,asrc+(size_t)i*C,adst+(size_t)i*C,hW16,bo,as_,ad_);
    agg_kernel<<<nblkA,256,0,stream>>>(rowptr,src_csr,edc+(size_t)(i+1)*NE,as_,ad_,hW16,bo,(i<2)?1:0);
    float* t=bin; bin=bo; bo=t;
  }
  pool_kernel<<<(NG+3)/4,256,0,stream>>>(bin,growptr,pooled);
  out_kernel<<<NG,256,0,stream>>>(pooled,Wout,bout,(float*)d_out);
}

// Round 9
// 338.168 us; speedup vs baseline: 2.4409x; 1.0517x over previous
//
#include <hip/hip_runtime.h>
#include <hip/hip_fp16.h>

// Problem constants (from reference)
#define NN 50000
#define NE 1000000
#define FIN0 30
#define C 64
#define ED 11
#define NG 1024
#define DOUT 256
#define NBIN 196            // ceil(NN/256)
#define PA_EDGES 1024       // edges per partition block (LDS diet -> 4 wg/CU)

typedef unsigned long long ull;

// ---------------- bin histogram (196 bins, LDS-privatized) ----------------
__global__ __launch_bounds__(256) void hist196_kernel(const int* __restrict__ dst,
    int* __restrict__ bcnt){
  __shared__ int h[256];
  int t=threadIdx.x;
  h[t]=0;
  __syncthreads();
  for(int i=blockIdx.x*256+t;i<NE;i+=gridDim.x*256)
    atomicAdd(&h[dst[i]>>8],1);
  __syncthreads();
  if(h[t]) atomicAdd(&bcnt[t],h[t]);
}

// single block: exclusive scan of 256 bin counts -> bbase (197 used) + gcur copy
__global__ __launch_bounds__(256) void scan196_kernel(const int* __restrict__ bcnt,
    int* __restrict__ bbase, int* __restrict__ gcur){
  __shared__ int p[256];
  int t=threadIdx.x;
  int v=bcnt[t];
  p[t]=v; __syncthreads();
  #pragma unroll
  for(int off=1;off<256;off<<=1){
    int u=(t>=off)?p[t-off]:0;
    __syncthreads(); p[t]+=u; __syncthreads();
  }
  int ex=p[t]-v;
  if(t<=NBIN) bbase[t]=ex;
  if(t<NBIN)  gcur[t]=ex;
}

// growptr from SORTED batch_index (boundary detection; handles empty graphs)
__global__ __launch_bounds__(256) void grow_kernel(const int* __restrict__ batch,
    int* __restrict__ growptr){
  int i=blockIdx.x*256+threadIdx.x;
  if(i>=NN) return;
  int bi=batch[i];
  int bp=(i==0)?-1:batch[i-1];
  for(int g=bp+1;g<=bi;++g) growptr[g]=i;
  if(i==NN-1){ for(int g=bi+1;g<=NG;++g) growptr[g]=NN; }
}

// ---------------- Pass A: counting-sort partition + fused edge_attr dots ----------------
// Payload per edge: (dst,src) 8B + 4x half ed 8B. LDS ~33KB -> 4 wg/CU.
__global__ __launch_bounds__(256) void part_kernel(const int* __restrict__ dst,
    const int* __restrict__ src, const float* __restrict__ edge_attr,
    const float* __restrict__ We0, const float* __restrict__ ae0,
    const float* __restrict__ We,  const float* __restrict__ ae,
    int* __restrict__ gcur,
    ull* __restrict__ pdst_src, ushort4* __restrict__ ped){
  __shared__ ull     ldst_src[PA_EDGES];     // 8KB
  __shared__ ushort4 led[PA_EDGES];          // 8KB
  __shared__ unsigned char lbin[PA_EDGES];   // 1KB
  __shared__ float tile[256*ED];             // 11KB
  __shared__ float sw[4][ED];
  __shared__ int hist[256], p[256], sc[256], lofs[256], bb[256];
  int t=threadIdx.x;
  hist[t]=0;
  if(t<4*ED){
    int l=t/ED, j=t%ED;
    const float* wp=(l==0)? (We0+(size_t)j*C) : (We+((size_t)(l-1)*ED+j)*C);
    const float* ap=(l==0)? ae0 : (ae+(size_t)(l-1)*C);
    float s=0.f;
    for(int c=0;c<C;++c) s+=wp[c]*ap[c];
    sw[l][j]=s;
  }
  __syncthreads();
  size_t e0=(size_t)blockIdx.x*PA_EDGES;
  int cnt=(int)min((size_t)PA_EDGES,(size_t)NE-e0);
  for(int i=t;i<cnt;i+=256) atomicAdd(&hist[dst[e0+i]>>8],1);
  __syncthreads();
  p[t]=hist[t]; __syncthreads();
  #pragma unroll
  for(int off=1;off<256;off<<=1){
    int u=(t>=off)?p[t-off]:0;
    __syncthreads(); p[t]+=u; __syncthreads();
  }
  sc[t]=p[t]-hist[t];
  lofs[t]=sc[t];
  bb[t]=(hist[t]>0)?atomicAdd(&gcur[t],hist[t]):0;
  __syncthreads();
  // per-256-edge slice: stage edge_attr (coalesced), compute dots, place bin-sorted
  for(int base=0;base<cnt;base+=256){
    int ccnt=min(256,cnt-base);
    for(int i=t;i<ccnt*ED;i+=256) tile[i]=edge_attr[(e0+base)*ED+i];
    __syncthreads();
    if(t<ccnt){
      int i=base+t;
      int d=dst[e0+i], s=src[e0+i];
      int b=d>>8;
      float d0=0,d1=0,d2=0,d3=0;
      #pragma unroll
      for(int j=0;j<ED;++j){
        float ev=tile[t*ED+j];
        d0=fmaf(ev,sw[0][j],d0);
        d1=fmaf(ev,sw[1][j],d1);
        d2=fmaf(ev,sw[2][j],d2);
        d3=fmaf(ev,sw[3][j],d3);
      }
      int slot=atomicAdd(&lofs[b],1);
      ldst_src[slot]=((ull)(unsigned)d<<32)|(unsigned)s;
      ushort4 hv;
      hv.x=__half_as_ushort(__float2half(d0));
      hv.y=__half_as_ushort(__float2half(d1));
      hv.z=__half_as_ushort(__float2half(d2));
      hv.w=__half_as_ushort(__float2half(d3));
      led[slot]=hv;
      lbin[slot]=(unsigned char)b;
    }
    __syncthreads();
  }
  // coalesced flush
  for(int i=t;i<cnt;i+=256){
    int b=lbin[i];
    int g=bb[b]+i-sc[b];
    pdst_src[g]=ldst_src[i];
    ped[g]=led[i];
  }
}

// ---------------- Pass B: bin -> exact CSR slots; also emits rowptr ----------------
__global__ __launch_bounds__(256) void build_kernel(const ull* __restrict__ pdst_src,
    const ushort4* __restrict__ ped, const int* __restrict__ bbase,
    int* __restrict__ rowptr, int* __restrict__ src_csr, ushort* __restrict__ edch){
  __shared__ int cnt[256], p[256], cur[256];
  int t=threadIdx.x, b=blockIdx.x;
  int n0=b<<8;
  cnt[t]=0;
  __syncthreads();
  int beg=bbase[b], endd=bbase[b+1];
  for(int j=beg+t;j<endd;j+=256)
    atomicAdd(&cnt[(int)(pdst_src[j]>>32)-n0],1);
  __syncthreads();
  int v=cnt[t];
  p[t]=v; __syncthreads();
  #pragma unroll
  for(int off=1;off<256;off<<=1){
    int u=(t>=off)?p[t-off]:0;
    __syncthreads(); p[t]+=u; __syncthreads();
  }
  int ex=p[t]-v;
  cur[t]=beg+ex;
  if(n0+t<NN) rowptr[n0+t]=beg+ex;
  if(b==0&&t==0) rowptr[NN]=NE;
  __syncthreads();
  for(int j=beg+t;j<endd;j+=256){
    ull ds=pdst_src[j];
    int d=(int)(ds>>32);
    int s=(int)(ds&0xffffffffu);
    int pos=atomicAdd(&cur[d-n0],1);
    src_csr[pos]=s;
    ushort4 e=ped[j];
    edch[pos]=e.x;
    edch[(size_t)NE+pos]=e.y;
    edch[2*(size_t)NE+pos]=e.z;
    edch[3*(size_t)NE+pos]=e.w;
  }
}

// ---------------- per-layer features: register-blocked vector GEMM ----------------
template<int FIN, int SXS>
__global__ __launch_bounds__(256) void feat_kernel(const float* __restrict__ in,
    const float* __restrict__ W, const float* __restrict__ Wres,
    const float* __restrict__ bvec, const float* __restrict__ av_src,
    const float* __restrict__ av_dst,
    __half* __restrict__ hW16, float* __restrict__ outb,
    float* __restrict__ as_, float* __restrict__ ad_){
  __shared__ float sW[FIN*C], sR[FIN*C];
  __shared__ float sx[64*SXS];
  __shared__ float sb[C], ss[C], sd[C];
  int tid=threadIdx.x;
  if(tid<C){ sb[tid]=bvec[tid]; ss[tid]=av_src[tid]; sd[tid]=av_dst[tid]; }
  for(int i=tid;i<FIN*C;i+=256){ sW[i]=W[i]; sR[i]=Wres[i]; }
  int nbase=blockIdx.x*64;
  int nvalid=min(64,NN-nbase);
  if constexpr (FIN==64){
    const float4* in4=(const float4*)(in+(size_t)nbase*64);
    for(int i=tid;i<1024;i+=256){
      int n=i>>4, k=(i&15)*4;
      float4 v=(n<nvalid)?in4[i]:make_float4(0.f,0.f,0.f,0.f);
      *(float4*)&sx[n*SXS+k]=v;
    }
  } else {
    for(int i=tid;i<64*FIN;i+=256){
      int n=i/FIN, k=i-n*FIN;
      sx[n*SXS+k]=(n<nvalid)?in[(size_t)(nbase+n)*FIN+k]:0.f;
    }
  }
  __syncthreads();
  int w=tid>>6, lane=tid&63;
  int ng=lane>>4, cl=lane&15;
  int n0=w*16+ng*4;
  int c0=cl*4;
  float hw[4][4]={}, hr[4][4]={};
  const float* sxp=&sx[n0*SXS];
  #pragma unroll 2
  for(int k=0;k<FIN;k+=2){
    float4 wv0=*(const float4*)&sW[k*C+c0];
    float4 rv0=*(const float4*)&sR[k*C+c0];
    float4 wv1=*(const float4*)&sW[(k+1)*C+c0];
    float4 rv1=*(const float4*)&sR[(k+1)*C+c0];
    float2 x0=*(const float2*)&sxp[k];
    float2 x1=*(const float2*)&sxp[SXS+k];
    float2 x2=*(const float2*)&sxp[2*SXS+k];
    float2 x3=*(const float2*)&sxp[3*SXS+k];
    float xa[4]={x0.x,x1.x,x2.x,x3.x};
    float xb[4]={x0.y,x1.y,x2.y,x3.y};
    #pragma unroll
    for(int r=0;r<4;++r){
      hw[r][0]=fmaf(xa[r],wv0.x,hw[r][0]);
      hw[r][1]=fmaf(xa[r],wv0.y,hw[r][1]);
      hw[r][2]=fmaf(xa[r],wv0.z,hw[r][2]);
      hw[r][3]=fmaf(xa[r],wv0.w,hw[r][3]);
      hr[r][0]=fmaf(xa[r],rv0.x,hr[r][0]);
      hr[r][1]=fmaf(xa[r],rv0.y,hr[r][1]);
      hr[r][2]=fmaf(xa[r],rv0.z,hr[r][2]);
      hr[r][3]=fmaf(xa[r],rv0.w,hr[r][3]);
      hw[r][0]=fmaf(xb[r],wv1.x,hw[r][0]);
      hw[r][1]=fmaf(xb[r],wv1.y,hw[r][1]);
      hw[r][2]=fmaf(xb[r],wv1.z,hw[r][2]);
      hw[r][3]=fmaf(xb[r],wv1.w,hw[r][3]);
      hr[r][0]=fmaf(xb[r],rv1.x,hr[r][0]);
      hr[r][1]=fmaf(xb[r],rv1.y,hr[r][1]);
      hr[r][2]=fmaf(xb[r],rv1.z,hr[r][2]);
      hr[r][3]=fmaf(xb[r],rv1.w,hr[r][3]);
    }
  }
  float s0=ss[c0], s1=ss[c0+1], s2=ss[c0+2], s3=ss[c0+3];
  float d0=sd[c0], d1=sd[c0+1], d2=sd[c0+2], d3=sd[c0+3];
  float b0v=sb[c0], b1v=sb[c0+1], b2v=sb[c0+2], b3v=sb[c0+3];
  #pragma unroll
  for(int r=0;r<4;++r){
    int n=n0+r;
    float ps=hw[r][0]*s0+hw[r][1]*s1+hw[r][2]*s2+hw[r][3]*s3;
    float pd=hw[r][0]*d0+hw[r][1]*d1+hw[r][2]*d2+hw[r][3]*d3;
    #pragma unroll
    for(int off=1;off<16;off<<=1){ ps+=__shfl_xor(ps,off,64); pd+=__shfl_xor(pd,off,64); }
    if(n<nvalid){
      size_t gn=(size_t)(nbase+n);
      ushort4 hv;
      hv.x=__half_as_ushort(__float2half(hw[r][0]));
      hv.y=__half_as_ushort(__float2half(hw[r][1]));
      hv.z=__half_as_ushort(__float2half(hw[r][2]));
      hv.w=__half_as_ushort(__float2half(hw[r][3]));
      *(ushort4*)&hW16[gn*C+c0]=hv;
      float4 ov;
      ov.x=hr[r][0]+b0v; ov.y=hr[r][1]+b1v; ov.z=hr[r][2]+b2v; ov.w=hr[r][3]+b3v;
      *(float4*)&outb[gn*C+c0]=ov;
      if(cl==0){ as_[gn]=ps; ad_[gn]=pd; }
    }
  }
}

// ------- fused alpha + softmax aggregation, wave per dst node -------
__device__ __forceinline__ void acc8(float* a, float at, uint4 u){
  __half2 h0=*(__half2*)&u.x, h1=*(__half2*)&u.y, h2=*(__half2*)&u.z, h3=*(__half2*)&u.w;
  float2 f0=__half22float2(h0), f1=__half22float2(h1);
  float2 f2=__half22float2(h2), f3=__half22float2(h3);
  a[0]=fmaf(at,f0.x,a[0]); a[1]=fmaf(at,f0.y,a[1]);
  a[2]=fmaf(at,f1.x,a[2]); a[3]=fmaf(at,f1.y,a[3]);
  a[4]=fmaf(at,f2.x,a[4]); a[5]=fmaf(at,f2.y,a[5]);
  a[6]=fmaf(at,f3.x,a[6]); a[7]=fmaf(at,f3.y,a[7]);
}

__global__ __launch_bounds__(256) void agg_kernel(const int* __restrict__ rowptr,
    const int* __restrict__ src_csr, const ushort* __restrict__ edc_l,
    const float* __restrict__ as_, const float* __restrict__ ad_,
    const __half* __restrict__ hW16, float* __restrict__ outb, int relu){
  __shared__ float2 sws[4][64];          // per-wave (wl, sl-as-bits)
  int w=threadIdx.x>>6, lane=threadIdx.x&63;
  int nidx=blockIdx.x*4+w;
  if(nidx>=NN) return;
  int beg=rowptr[nidx], end=rowptr[nidx+1];
  int deg=end-beg;
  float ad_n=ad_[nidx];
  int g2=lane>>3, gl2=lane&7;
  const uint4* hw4=(const uint4*)hW16;   // row = 8 uint4 (8 halves each)
  float s=0.f;
  float acc[8]={0.f,0.f,0.f,0.f,0.f,0.f,0.f,0.f};

  if(deg<=64){
    int j=beg+lane;
    float al=-INFINITY; int sl=0;
    if(lane<deg){
      sl=src_csr[j];
      float a=as_[sl]+ad_n+__half2float(__ushort_as_half(edc_l[j]));
      al=(a>0.f)?a:0.2f*a;               // leaky_relu 0.2
    }
    float mn=al;
    #pragma unroll
    for(int off=32;off;off>>=1) mn=fmaxf(mn,__shfl_xor(mn,off,64));
    float wl=(lane<deg)?__expf(al-mn):0.f;
    s=wl;
    #pragma unroll
    for(int off=32;off;off>>=1) s+=__shfl_xor(s,off,64);
    float2 pr; pr.x=wl; pr.y=__int_as_float(sl);
    sws[w][lane]=pr;                     // wave-private slice: no barrier
    int t=g2;
    for(; t+8<deg; t+=16){               // 2 independent loads in flight
      float2 r0=sws[w][t], r1=sws[w][t+8];
      uint4 u0=hw4[(size_t)__float_as_int(r0.y)*8+gl2];
      uint4 u1=hw4[(size_t)__float_as_int(r1.y)*8+gl2];
      acc8(acc,r0.x,u0);
      acc8(acc,r1.x,u1);
    }
    if(t<deg){
      float2 r=sws[w][t];
      uint4 u=hw4[(size_t)__float_as_int(r.y)*8+gl2];
      acc8(acc,r.x,u);
    }
  } else {
    // fallback: online softmax over 64-edge chunks (rare)
    float m=-INFINITY;
    for(int base=beg;base<end;base+=64){
      int j=base+lane;
      float al=-INFINITY; int sl=0;
      if(j<end){
        sl=src_csr[j];
        float a=as_[sl]+ad_n+__half2float(__ushort_as_half(edc_l[j]));
        al=(a>0.f)?a:0.2f*a;
      }
      float cm=al;
      #pragma unroll
      for(int off=32;off;off>>=1) cm=fmaxf(cm,__shfl_xor(cm,off,64));
      float mn=fmaxf(m,cm);
      float scale=(m==-INFINITY)?0.f:__expf(m-mn);
      s*=scale;
      #pragma unroll
      for(int i=0;i<8;++i) acc[i]*=scale;
      float wl=(j<end)?__expf(al-mn):0.f;
      float cs=wl;
      #pragma unroll
      for(int off=32;off;off>>=1) cs+=__shfl_xor(cs,off,64);
      s+=cs; m=mn;
      float2 pr; pr.x=wl; pr.y=__int_as_float(sl);
      sws[w][lane]=pr;
      int cnt=min(64,end-base);
      int t=g2;
      for(; t+8<cnt; t+=16){
        float2 r0=sws[w][t], r1=sws[w][t+8];
        uint4 u0=hw4[(size_t)__float_as_int(r0.y)*8+gl2];
        uint4 u1=hw4[(size_t)__float_as_int(r1.y)*8+gl2];
        acc8(acc,r0.x,u0);
        acc8(acc,r1.x,u1);
      }
      if(t<cnt){
        float2 r=sws[w][t];
        uint4 u=hw4[(size_t)__float_as_int(r.y)*8+gl2];
        acc8(acc,r.x,u);
      }
    }
  }

  // combine the 8 groups (butterfly): lanes with same gl2 hold same channels
  #pragma unroll
  for(int off=8;off<64;off<<=1){
    #pragma unroll
    for(int i=0;i<8;++i) acc[i]+=__shfl_xor(acc[i],off,64);
  }
  if(g2==0){
    float denom=s+1e-16f;
    size_t o0=(size_t)nidx*C+gl2*8;
    float4 oa=*(float4*)&outb[o0];
    float4 ob=*(float4*)&outb[o0+4];
    float4 va,vb;
    va.x=acc[0]/denom+oa.x; va.y=acc[1]/denom+oa.y;
    va.z=acc[2]/denom+oa.z; va.w=acc[3]/denom+oa.w;
    vb.x=acc[4]/denom+ob.x; vb.y=acc[5]/denom+ob.y;
    vb.z=acc[6]/denom+ob.z; vb.w=acc[7]/denom+ob.w;
    if(relu){
      va.x=(va.x>0.f)?va.x:0.01f*va.x; va.y=(va.y>0.f)?va.y:0.01f*va.y;
      va.z=(va.z>0.f)?va.z:0.01f*va.z; va.w=(va.w>0.f)?va.w:0.01f*va.w;
      vb.x=(vb.x>0.f)?vb.x:0.01f*vb.x; vb.y=(vb.y>0.f)?vb.y:0.01f*vb.y;
      vb.z=(vb.z>0.f)?vb.z:0.01f*vb.z; vb.w=(vb.w>0.f)?vb.w:0.01f*vb.w;
    }
    *(float4*)&outb[o0]=va;
    *(float4*)&outb[o0+4]=vb;
  }
}

// ---------------- pooling (max + mean per graph) ----------------
__global__ __launch_bounds__(256) void pool_kernel(const float* __restrict__ h,
    const int* __restrict__ growptr, float* __restrict__ pooled){
  int w=threadIdx.x>>6, lane=threadIdx.x&63;
  int g=blockIdx.x*4+w;
  if(g>=NG) return;
  int beg=growptr[g], end=growptr[g+1];
  float mx=-INFINITY, sm=0.f;
  for(int n=beg;n<end;++n){ float v=h[(size_t)n*C+lane]; mx=fmaxf(mx,v); sm+=v; }
  int cnt=end-beg;
  float gm=(cnt==0)?0.f:mx;              // isfinite fix for empty graphs
  float mean=sm/fmaxf((float)cnt,1.f);
  gm=(gm>0.f)?gm:0.01f*gm;               // leaky_relu 0.01 on pooled
  mean=(mean>0.f)?mean:0.01f*mean;
  pooled[(size_t)g*128+lane]=gm;
  pooled[(size_t)g*128+64+lane]=mean;
}

// ---------------- final linear: [G,128] @ [128,256] + bias ----------------
__global__ __launch_bounds__(256) void out_kernel(const float* __restrict__ pooled,
    const float* __restrict__ Wout, const float* __restrict__ bout,
    float* __restrict__ out){
  __shared__ float sp[128];
  int g=blockIdx.x, d=threadIdx.x;
  if(d<128) sp[d]=pooled[(size_t)g*128+d];
  __syncthreads();
  float o=bout[d];
  for(int k=0;k<128;++k) o=fmaf(sp[k],Wout[k*DOUT+d],o);
  out[(size_t)g*DOUT+d]=o;
}

extern "C" void kernel_launch(void* const* d_in, const int* in_sizes, int n_in,
                              void* d_out, int out_size, void* d_ws, size_t ws_size,
                              hipStream_t stream){
  const float* x        =(const float*)d_in[0];
  const float* edge_attr=(const float*)d_in[1];
  const float* W0       =(const float*)d_in[2];
  const float* asrc0    =(const float*)d_in[3];
  const float* adst0    =(const float*)d_in[4];
  const float* We0      =(const float*)d_in[5];
  const float* ae0      =(const float*)d_in[6];
  const float* Wres0    =(const float*)d_in[7];
  const float* b0       =(const float*)d_in[8];
  const float* W        =(const float*)d_in[9];
  const float* asrc     =(const float*)d_in[10];
  const float* adst     =(const float*)d_in[11];
  const float* We       =(const float*)d_in[12];
  const float* ae       =(const float*)d_in[13];
  const float* Wres     =(const float*)d_in[14];
  const float* b        =(const float*)d_in[15];
  const float* Wout     =(const float*)d_in[16];
  const float* bout     =(const float*)d_in[17];
  const int* edge_index =(const int*)d_in[18];
  const int* batch_index=(const int*)d_in[19];
  const int* src=edge_index;
  const int* dst=edge_index+NE;

  // workspace carve (~53 MB, with aliased regions)
  char* p=(char*)d_ws;
  auto take=[&](size_t bytes)->void*{ void* r=(void*)p; p+=(bytes+255)&~(size_t)255; return r; };
  int* rowptr  =(int*)take((size_t)(NN+1)*4);
  int* growptr =(int*)take((size_t)(NG+1)*4);
  int* bcnt    =(int*)take((size_t)256*4);
  int* bbase   =(int*)take((size_t)256*4);
  int* gcur    =(int*)take((size_t)256*4);
  int* src_csr =(int*)take((size_t)NE*4);
  float* as_   =(float*)take((size_t)NN*4);
  float* ad_   =(float*)take((size_t)NN*4);
  ushort* edch =(ushort*)take((size_t)NE*4*2);    // 4 layers x NE half, CSR order (SoA)
  __half* hW16 =(__half*)take((size_t)NN*C*2);
  float* bufA  =(float*)take((size_t)NN*C*4);
  // region R2: pdst_src (8MB) -> later pooled (0.5MB)
  ull* pdst_src=(ull*)take((size_t)NE*8);
  float* pooled=(float*)pdst_src;
  // region R3: ped (8MB) -> later bufB (12.8MB); take max
  ushort4* ped =(ushort4*)take((size_t)NN*C*4);   // 12.8MB region
  float* bufB  =(float*)ped;
  (void)ws_size; (void)in_sizes; (void)n_in; (void)out_size;

  hipMemsetAsync(bcnt,0,(size_t)256*4,stream);
  hist196_kernel<<<1024,256,0,stream>>>(dst,bcnt);
  scan196_kernel<<<1,256,0,stream>>>(bcnt,bbase,gcur);
  grow_kernel<<<(NN+255)/256,256,0,stream>>>(batch_index,growptr);

  part_kernel<<<(NE+PA_EDGES-1)/PA_EDGES,256,0,stream>>>(dst,src,edge_attr,
      We0,ae0,We,ae,gcur,pdst_src,ped);
  build_kernel<<<NBIN,256,0,stream>>>(pdst_src,ped,bbase,rowptr,src_csr,edch);

  const int nblkF=(NN+63)/64;      // 782
  const int nblkA=(NN+3)/4;        // 12500
  // layer 0 (F=30, sx stride 36)
  feat_kernel<FIN0,36><<<nblkF,256,0,stream>>>(x,W0,Wres0,b0,asrc0,adst0,hW16,bufA,as_,ad_);
  agg_kernel<<<nblkA,256,0,stream>>>(rowptr,src_csr,edch,as_,ad_,hW16,bufA,1);
  // layers 1..3 (ping-pong; sx stride 68)
  float* bin=bufA; float* bo=bufB;
  for(int i=0;i<3;++i){
    feat_kernel<C,68><<<nblkF,256,0,stream>>>(bin,W+(size_t)i*C*C,Wres+(size_t)i*C*C,
        b+(size_t)i*C,asrc+(size_t)i*C,adst+(size_t)i*C,hW16,bo,as_,ad_);
    agg_kernel<<<nblkA,256,0,stream>>>(rowptr,src_csr,edch+(size_t)(i+1)*NE,as_,ad_,hW16,bo,(i<2)?1:0);
    float* t=bin; bin=bo; bo=t;
  }
  pool_kernel<<<(NG+3)/4,256,0,stream>>>(bin,growptr,pooled);
  out_kernel<<<NG,256,0,stream>>>(pooled,Wout,bout,(float*)d_out);
}

// Round 10
// 312.509 us; speedup vs baseline: 2.6413x; 1.0821x over previous
//
#include <hip/hip_runtime.h>
#include <hip/hip_fp16.h>

// Problem constants (from reference)
#define NN 50000
#define NE 1000000
#define FIN0 30
#define C 64
#define ED 11
#define NG 1024
#define DOUT 256
#define NBIN 196            // ceil(NN/256)
#define PA_EDGES 2048       // edges per partition block

typedef unsigned long long ull;

// ---------------- bin histogram (196 bins, LDS-privatized) ----------------
__global__ __launch_bounds__(256) void hist196_kernel(const int* __restrict__ dst,
    int* __restrict__ bcnt){
  __shared__ int h[256];
  int t=threadIdx.x;
  h[t]=0;
  __syncthreads();
  for(int i=blockIdx.x*256+t;i<NE;i+=gridDim.x*256)
    atomicAdd(&h[dst[i]>>8],1);
  __syncthreads();
  if(h[t]) atomicAdd(&bcnt[t],h[t]);
}

// single block: exclusive scan of 256 bin counts -> bbase (197 used) + gcur copy
__global__ __launch_bounds__(256) void scan196_kernel(const int* __restrict__ bcnt,
    int* __restrict__ bbase, int* __restrict__ gcur){
  __shared__ int p[256];
  int t=threadIdx.x;
  int v=bcnt[t];
  p[t]=v; __syncthreads();
  #pragma unroll
  for(int off=1;off<256;off<<=1){
    int u=(t>=off)?p[t-off]:0;
    __syncthreads(); p[t]+=u; __syncthreads();
  }
  int ex=p[t]-v;
  if(t<=NBIN) bbase[t]=ex;
  if(t<NBIN)  gcur[t]=ex;
}

// growptr from SORTED batch_index (boundary detection; handles empty graphs)
__global__ __launch_bounds__(256) void grow_kernel(const int* __restrict__ batch,
    int* __restrict__ growptr){
  int i=blockIdx.x*256+threadIdx.x;
  if(i>=NN) return;
  int bi=batch[i];
  int bp=(i==0)?-1:batch[i-1];
  for(int g=bp+1;g<=bi;++g) growptr[g]=i;
  if(i==NN-1){ for(int g=bi+1;g<=NG;++g) growptr[g]=NN; }
}

// ---------------- Pass A: counting-sort partition + fused edge_attr dots ----------------
// ONE packed record/edge: uint4{dst, src, ed0|ed1<<16, ed2|ed3<<16} (halves).
__global__ __launch_bounds__(256) void part_kernel(const int* __restrict__ dst,
    const int* __restrict__ src, const float* __restrict__ edge_attr,
    const float* __restrict__ We0, const float* __restrict__ ae0,
    const float* __restrict__ We,  const float* __restrict__ ae,
    int* __restrict__ gcur, uint4* __restrict__ prec){
  __shared__ uint4 lrec[PA_EDGES];           // 32KB
  __shared__ unsigned char lbin[PA_EDGES];   // 2KB
  __shared__ float tile[256*ED];             // 11KB
  __shared__ float sw[4][ED];
  __shared__ int hist[256], p[256], sc[256], lofs[256], bb[256];
  int t=threadIdx.x;
  hist[t]=0;
  if(t<4*ED){
    int l=t/ED, j=t%ED;
    const float* wp=(l==0)? (We0+(size_t)j*C) : (We+((size_t)(l-1)*ED+j)*C);
    const float* ap=(l==0)? ae0 : (ae+(size_t)(l-1)*C);
    float s=0.f;
    for(int c=0;c<C;++c) s+=wp[c]*ap[c];
    sw[l][j]=s;
  }
  __syncthreads();
  size_t e0=(size_t)blockIdx.x*PA_EDGES;
  int cnt=(int)min((size_t)PA_EDGES,(size_t)NE-e0);
  for(int i=t;i<cnt;i+=256) atomicAdd(&hist[dst[e0+i]>>8],1);
  __syncthreads();
  p[t]=hist[t]; __syncthreads();
  #pragma unroll
  for(int off=1;off<256;off<<=1){
    int u=(t>=off)?p[t-off]:0;
    __syncthreads(); p[t]+=u; __syncthreads();
  }
  sc[t]=p[t]-hist[t];
  lofs[t]=sc[t];
  bb[t]=(hist[t]>0)?atomicAdd(&gcur[t],hist[t]):0;
  __syncthreads();
  // per-256-edge slice: stage edge_attr (coalesced), compute dots, place bin-sorted
  for(int base=0;base<cnt;base+=256){
    int ccnt=min(256,cnt-base);
    for(int i=t;i<ccnt*ED;i+=256) tile[i]=edge_attr[(e0+base)*ED+i];
    __syncthreads();
    if(t<ccnt){
      int i=base+t;
      int d=dst[e0+i], s=src[e0+i];
      int b=d>>8;
      float d0=0,d1=0,d2=0,d3=0;
      #pragma unroll
      for(int j=0;j<ED;++j){
        float ev=tile[t*ED+j];
        d0=fmaf(ev,sw[0][j],d0);
        d1=fmaf(ev,sw[1][j],d1);
        d2=fmaf(ev,sw[2][j],d2);
        d3=fmaf(ev,sw[3][j],d3);
      }
      uint4 r;
      r.x=(unsigned)d; r.y=(unsigned)s;
      r.z=(unsigned)__half_as_ushort(__float2half(d0))
         |((unsigned)__half_as_ushort(__float2half(d1))<<16);
      r.w=(unsigned)__half_as_ushort(__float2half(d2))
         |((unsigned)__half_as_ushort(__float2half(d3))<<16);
      int slot=atomicAdd(&lofs[b],1);
      lrec[slot]=r;
      lbin[slot]=(unsigned char)b;
    }
    __syncthreads();
  }
  // coalesced flush (single packed array)
  for(int i=t;i<cnt;i+=256){
    int b=lbin[i];
    int g=bb[b]+i-sc[b];
    prec[g]=lrec[i];
  }
}

// ---------------- Pass B: bin -> exact CSR slots; also emits rowptr ----------------
__global__ __launch_bounds__(256) void build_kernel(const uint4* __restrict__ prec,
    const int* __restrict__ bbase,
    int* __restrict__ rowptr, int* __restrict__ src_csr, ushort* __restrict__ edch){
  __shared__ int cnt[256], p[256], cur[256];
  int t=threadIdx.x, b=blockIdx.x;
  int n0=b<<8;
  cnt[t]=0;
  __syncthreads();
  int beg=bbase[b], endd=bbase[b+1];
  for(int j=beg+t;j<endd;j+=256)
    atomicAdd(&cnt[(int)prec[j].x-n0],1);
  __syncthreads();
  int v=cnt[t];
  p[t]=v; __syncthreads();
  #pragma unroll
  for(int off=1;off<256;off<<=1){
    int u=(t>=off)?p[t-off]:0;
    __syncthreads(); p[t]+=u; __syncthreads();
  }
  int ex=p[t]-v;
  cur[t]=beg+ex;
  if(n0+t<NN) rowptr[n0+t]=beg+ex;
  if(b==0&&t==0) rowptr[NN]=NE;
  __syncthreads();
  for(int j=beg+t;j<endd;j+=256){
    uint4 r=prec[j];
    int d=(int)r.x, s=(int)r.y;
    int pos=atomicAdd(&cur[d-n0],1);
    src_csr[pos]=s;
    edch[pos]                =(ushort)(r.z&0xffffu);
    edch[(size_t)NE+pos]     =(ushort)(r.z>>16);
    edch[2*(size_t)NE+pos]   =(ushort)(r.w&0xffffu);
    edch[3*(size_t)NE+pos]   =(ushort)(r.w>>16);
  }
}

// ---------------- per-layer features: register-blocked vector GEMM ----------------
template<int FIN, int SXS>
__global__ __launch_bounds__(256) void feat_kernel(const float* __restrict__ in,
    const float* __restrict__ W, const float* __restrict__ Wres,
    const float* __restrict__ bvec, const float* __restrict__ av_src,
    const float* __restrict__ av_dst,
    __half* __restrict__ hW16, float* __restrict__ outb,
    float* __restrict__ as_, float* __restrict__ ad_){
  __shared__ float sW[FIN*C], sR[FIN*C];
  __shared__ float sx[64*SXS];
  __shared__ float sb[C], ss[C], sd[C];
  int tid=threadIdx.x;
  if(tid<C){ sb[tid]=bvec[tid]; ss[tid]=av_src[tid]; sd[tid]=av_dst[tid]; }
  for(int i=tid;i<FIN*C;i+=256){ sW[i]=W[i]; sR[i]=Wres[i]; }
  int nbase=blockIdx.x*64;
  int nvalid=min(64,NN-nbase);
  if constexpr (FIN==64){
    const float4* in4=(const float4*)(in+(size_t)nbase*64);
    for(int i=tid;i<1024;i+=256){
      int n=i>>4, k=(i&15)*4;
      float4 v=(n<nvalid)?in4[i]:make_float4(0.f,0.f,0.f,0.f);
      *(float4*)&sx[n*SXS+k]=v;
    }
  } else {
    for(int i=tid;i<64*FIN;i+=256){
      int n=i/FIN, k=i-n*FIN;
      sx[n*SXS+k]=(n<nvalid)?in[(size_t)(nbase+n)*FIN+k]:0.f;
    }
  }
  __syncthreads();
  int w=tid>>6, lane=tid&63;
  int ng=lane>>4, cl=lane&15;
  int n0=w*16+ng*4;
  int c0=cl*4;
  float hw[4][4]={}, hr[4][4]={};
  const float* sxp=&sx[n0*SXS];
  #pragma unroll 2
  for(int k=0;k<FIN;k+=2){
    float4 wv0=*(const float4*)&sW[k*C+c0];
    float4 rv0=*(const float4*)&sR[k*C+c0];
    float4 wv1=*(const float4*)&sW[(k+1)*C+c0];
    float4 rv1=*(const float4*)&sR[(k+1)*C+c0];
    float2 x0=*(const float2*)&sxp[k];
    float2 x1=*(const float2*)&sxp[SXS+k];
    float2 x2=*(const float2*)&sxp[2*SXS+k];
    float2 x3=*(const float2*)&sxp[3*SXS+k];
    float xa[4]={x0.x,x1.x,x2.x,x3.x};
    float xb[4]={x0.y,x1.y,x2.y,x3.y};
    #pragma unroll
    for(int r=0;r<4;++r){
      hw[r][0]=fmaf(xa[r],wv0.x,hw[r][0]);
      hw[r][1]=fmaf(xa[r],wv0.y,hw[r][1]);
      hw[r][2]=fmaf(xa[r],wv0.z,hw[r][2]);
      hw[r][3]=fmaf(xa[r],wv0.w,hw[r][3]);
      hr[r][0]=fmaf(xa[r],rv0.x,hr[r][0]);
      hr[r][1]=fmaf(xa[r],rv0.y,hr[r][1]);
      hr[r][2]=fmaf(xa[r],rv0.z,hr[r][2]);
      hr[r][3]=fmaf(xa[r],rv0.w,hr[r][3]);
      hw[r][0]=fmaf(xb[r],wv1.x,hw[r][0]);
      hw[r][1]=fmaf(xb[r],wv1.y,hw[r][1]);
      hw[r][2]=fmaf(xb[r],wv1.z,hw[r][2]);
      hw[r][3]=fmaf(xb[r],wv1.w,hw[r][3]);
      hr[r][0]=fmaf(xb[r],rv1.x,hr[r][0]);
      hr[r][1]=fmaf(xb[r],rv1.y,hr[r][1]);
      hr[r][2]=fmaf(xb[r],rv1.z,hr[r][2]);
      hr[r][3]=fmaf(xb[r],rv1.w,hr[r][3]);
    }
  }
  float s0=ss[c0], s1=ss[c0+1], s2=ss[c0+2], s3=ss[c0+3];
  float d0=sd[c0], d1=sd[c0+1], d2=sd[c0+2], d3=sd[c0+3];
  float b0v=sb[c0], b1v=sb[c0+1], b2v=sb[c0+2], b3v=sb[c0+3];
  #pragma unroll
  for(int r=0;r<4;++r){
    int n=n0+r;
    float ps=hw[r][0]*s0+hw[r][1]*s1+hw[r][2]*s2+hw[r][3]*s3;
    float pd=hw[r][0]*d0+hw[r][1]*d1+hw[r][2]*d2+hw[r][3]*d3;
    #pragma unroll
    for(int off=1;off<16;off<<=1){ ps+=__shfl_xor(ps,off,64); pd+=__shfl_xor(pd,off,64); }
    if(n<nvalid){
      size_t gn=(size_t)(nbase+n);
      ushort4 hv;
      hv.x=__half_as_ushort(__float2half(hw[r][0]));
      hv.y=__half_as_ushort(__float2half(hw[r][1]));
      hv.z=__half_as_ushort(__float2half(hw[r][2]));
      hv.w=__half_as_ushort(__float2half(hw[r][3]));
      *(ushort4*)&hW16[gn*C+c0]=hv;
      float4 ov;
      ov.x=hr[r][0]+b0v; ov.y=hr[r][1]+b1v; ov.z=hr[r][2]+b2v; ov.w=hr[r][3]+b3v;
      *(float4*)&outb[gn*C+c0]=ov;
      if(cl==0){ as_[gn]=ps; ad_[gn]=pd; }
    }
  }
}

// ------- fused alpha + softmax aggregation -------
__device__ __forceinline__ void acc8(float* a, float at, uint4 u){
  __half2 h0=*(__half2*)&u.x, h1=*(__half2*)&u.y, h2=*(__half2*)&u.z, h3=*(__half2*)&u.w;
  float2 f0=__half22float2(h0), f1=__half22float2(h1);
  float2 f2=__half22float2(h2), f3=__half22float2(h3);
  a[0]=fmaf(at,f0.x,a[0]); a[1]=fmaf(at,f0.y,a[1]);
  a[2]=fmaf(at,f1.x,a[2]); a[3]=fmaf(at,f1.y,a[3]);
  a[4]=fmaf(at,f2.x,a[4]); a[5]=fmaf(at,f2.y,a[5]);
  a[6]=fmaf(at,f3.x,a[6]); a[7]=fmaf(at,f3.y,a[7]);
}

// 2 nodes per wave (32-lane halves) when both deg<=32 (~99.4% of waves).
// One shfl instruction serves both halves (xor off<32 stays within half).
__global__ __launch_bounds__(256) void agg_kernel(const int* __restrict__ rowptr,
    const int* __restrict__ src_csr, const ushort* __restrict__ edc_l,
    const float* __restrict__ as_, const float* __restrict__ ad_,
    const __half* __restrict__ hW16, float* __restrict__ outb, int relu){
  __shared__ float2 sws[4][64];
  int w=threadIdx.x>>6, lane=threadIdx.x&63;
  int half=lane>>5, hl=lane&31;
  int n0=blockIdx.x*8+w*2;            // NN%8==0: always in range
  int nidx=n0+half;
  int beg=rowptr[nidx], end=rowptr[nidx+1];
  int deg=end-beg;
  const uint4* hw4=(const uint4*)hW16;   // row = 8 uint4 (8 halves each)

  if(__all(deg<=32)){
    // ---- dual path: each 32-lane half handles one node ----
    float ad_n=ad_[nidx];
    int j=beg+hl;
    float al=-INFINITY; int sl=0;
    if(hl<deg){
      sl=src_csr[j];
      float a=as_[sl]+ad_n+__half2float(__ushort_as_half(edc_l[j]));
      al=(a>0.f)?a:0.2f*a;               // leaky_relu 0.2
    }
    float mn=al;
    #pragma unroll
    for(int off=16;off;off>>=1) mn=fmaxf(mn,__shfl_xor(mn,off,64));
    float wl=(hl<deg)?__expf(al-mn):0.f;
    float s=wl;
    #pragma unroll
    for(int off=16;off;off>>=1) s+=__shfl_xor(s,off,64);
    float2 pr; pr.x=wl; pr.y=__int_as_float(sl);
    sws[w][lane]=pr;                     // wave-private: no barrier
    int g=hl>>3, gl=hl&7;                // 4 groups of 8 lanes per half
    float acc[8]={0.f,0.f,0.f,0.f,0.f,0.f,0.f,0.f};
    int base=half*32;
    int t=g;
    for(; t+4<deg; t+=8){                // 2 independent loads in flight
      float2 r0=sws[w][base+t], r1=sws[w][base+t+4];
      uint4 u0=hw4[(size_t)__float_as_int(r0.y)*8+gl];
      uint4 u1=hw4[(size_t)__float_as_int(r1.y)*8+gl];
      acc8(acc,r0.x,u0);
      acc8(acc,r1.x,u1);
    }
    if(t<deg){
      float2 r=sws[w][base+t];
      uint4 u=hw4[(size_t)__float_as_int(r.y)*8+gl];
      acc8(acc,r.x,u);
    }
    // combine 4 groups within half (off 8,16 stay inside the half)
    #pragma unroll
    for(int off=8;off<=16;off<<=1){
      #pragma unroll
      for(int i=0;i<8;++i) acc[i]+=__shfl_xor(acc[i],off,64);
    }
    if(hl<8){
      float denom=s+1e-16f;
      size_t o0=(size_t)nidx*C+hl*8;
      float4 oa=*(float4*)&outb[o0];
      float4 ob=*(float4*)&outb[o0+4];
      float4 va,vb;
      va.x=acc[0]/denom+oa.x; va.y=acc[1]/denom+oa.y;
      va.z=acc[2]/denom+oa.z; va.w=acc[3]/denom+oa.w;
      vb.x=acc[4]/denom+ob.x; vb.y=acc[5]/denom+ob.y;
      vb.z=acc[6]/denom+ob.z; vb.w=acc[7]/denom+ob.w;
      if(relu){
        va.x=(va.x>0.f)?va.x:0.01f*va.x; va.y=(va.y>0.f)?va.y:0.01f*va.y;
        va.z=(va.z>0.f)?va.z:0.01f*va.z; va.w=(va.w>0.f)?va.w:0.01f*va.w;
        vb.x=(vb.x>0.f)?vb.x:0.01f*vb.x; vb.y=(vb.y>0.f)?vb.y:0.01f*vb.y;
        vb.z=(vb.z>0.f)?vb.z:0.01f*vb.z; vb.w=(vb.w>0.f)?vb.w:0.01f*vb.w;
      }
      *(float4*)&outb[o0]=va;
      *(float4*)&outb[o0+4]=vb;
    }
    return;
  }

  // ---- fallback: whole wave per node, 2 nodes sequentially (rare) ----
  for(int h=0;h<2;++h){
    int m=n0+h;
    int bh=__shfl(beg,h*32,64);
    int dh=__shfl(deg,h*32,64);
    float ad_n=ad_[m];
    int g2=lane>>3, gl2=lane&7;
    float s=0.f;
    float acc[8]={0.f,0.f,0.f,0.f,0.f,0.f,0.f,0.f};
    if(dh<=64){
      int j=bh+lane;
      float al=-INFINITY; int sl=0;
      if(lane<dh){
        sl=src_csr[j];
        float a=as_[sl]+ad_n+__half2float(__ushort_as_half(edc_l[j]));
        al=(a>0.f)?a:0.2f*a;
      }
      float mn=al;
      #pragma unroll
      for(int off=32;off;off>>=1) mn=fmaxf(mn,__shfl_xor(mn,off,64));
      float wl=(lane<dh)?__expf(al-mn):0.f;
      s=wl;
      #pragma unroll
      for(int off=32;off;off>>=1) s+=__shfl_xor(s,off,64);
      float2 pr; pr.x=wl; pr.y=__int_as_float(sl);
      sws[w][lane]=pr;
      int t=g2;
      for(; t+8<dh; t+=16){
        float2 r0=sws[w][t], r1=sws[w][t+8];
        uint4 u0=hw4[(size_t)__float_as_int(r0.y)*8+gl2];
        uint4 u1=hw4[(size_t)__float_as_int(r1.y)*8+gl2];
        acc8(acc,r0.x,u0);
        acc8(acc,r1.x,u1);
      }
      if(t<dh){
        float2 r=sws[w][t];
        uint4 u=hw4[(size_t)__float_as_int(r.y)*8+gl2];
        acc8(acc,r.x,u);
      }
    } else {
      float m_=-INFINITY;
      for(int base=bh;base<bh+dh;base+=64){
        int j=base+lane;
        float al=-INFINITY; int sl=0;
        if(j<bh+dh){
          sl=src_csr[j];
          float a=as_[sl]+ad_n+__half2float(__ushort_as_half(edc_l[j]));
          al=(a>0.f)?a:0.2f*a;
        }
        float cm=al;
        #pragma unroll
        for(int off=32;off;off>>=1) cm=fmaxf(cm,__shfl_xor(cm,off,64));
        float mn=fmaxf(m_,cm);
        float scale=(m_==-INFINITY)?0.f:__expf(m_-mn);
        s*=scale;
        #pragma unroll
        for(int i=0;i<8;++i) acc[i]*=scale;
        float wl=(j<bh+dh)?__expf(al-mn):0.f;
        float cs=wl;
        #pragma unroll
        for(int off=32;off;off>>=1) cs+=__shfl_xor(cs,off,64);
        s+=cs; m_=mn;
        float2 pr; pr.x=wl; pr.y=__int_as_float(sl);
        sws[w][lane]=pr;
        int cnt=min(64,bh+dh-base);
        int t=g2;
        for(; t+8<cnt; t+=16){
          float2 r0=sws[w][t], r1=sws[w][t+8];
          uint4 u0=hw4[(size_t)__float_as_int(r0.y)*8+gl2];
          uint4 u1=hw4[(size_t)__float_as_int(r1.y)*8+gl2];
          acc8(acc,r0.x,u0);
          acc8(acc,r1.x,u1);
        }
        if(t<cnt){
          float2 r=sws[w][t];
          uint4 u=hw4[(size_t)__float_as_int(r.y)*8+gl2];
          acc8(acc,r.x,u);
        }
      }
    }
    #pragma unroll
    for(int off=8;off<64;off<<=1){
      #pragma unroll
      for(int i=0;i<8;++i) acc[i]+=__shfl_xor(acc[i],off,64);
    }
    if(g2==0){
      float denom=s+1e-16f;
      size_t o0=(size_t)m*C+gl2*8;
      float4 oa=*(float4*)&outb[o0];
      float4 ob=*(float4*)&outb[o0+4];
      float4 va,vb;
      va.x=acc[0]/denom+oa.x; va.y=acc[1]/denom+oa.y;
      va.z=acc[2]/denom+oa.z; va.w=acc[3]/denom+oa.w;
      vb.x=acc[4]/denom+ob.x; vb.y=acc[5]/denom+ob.y;
      vb.z=acc[6]/denom+ob.z; vb.w=acc[7]/denom+ob.w;
      if(relu){
        va.x=(va.x>0.f)?va.x:0.01f*va.x; va.y=(va.y>0.f)?va.y:0.01f*va.y;
        va.z=(va.z>0.f)?va.z:0.01f*va.z; va.w=(va.w>0.f)?va.w:0.01f*va.w;
        vb.x=(vb.x>0.f)?vb.x:0.01f*vb.x; vb.y=(vb.y>0.f)?vb.y:0.01f*vb.y;
        vb.z=(vb.z>0.f)?vb.z:0.01f*vb.z; vb.w=(vb.w>0.f)?vb.w:0.01f*vb.w;
      }
      *(float4*)&outb[o0]=va;
      *(float4*)&outb[o0+4]=vb;
    }
  }
}

// ---------------- pooling (max + mean per graph) ----------------
__global__ __launch_bounds__(256) void pool_kernel(const float* __restrict__ h,
    const int* __restrict__ growptr, float* __restrict__ pooled){
  int w=threadIdx.x>>6, lane=threadIdx.x&63;
  int g=blockIdx.x*4+w;
  if(g>=NG) return;
  int beg=growptr[g], end=growptr[g+1];
  float mx=-INFINITY, sm=0.f;
  for(int n=beg;n<end;++n){ float v=h[(size_t)n*C+lane]; mx=fmaxf(mx,v); sm+=v; }
  int cnt=end-beg;
  float gm=(cnt==0)?0.f:mx;              // isfinite fix for empty graphs
  float mean=sm/fmaxf((float)cnt,1.f);
  gm=(gm>0.f)?gm:0.01f*gm;               // leaky_relu 0.01 on pooled
  mean=(mean>0.f)?mean:0.01f*mean;
  pooled[(size_t)g*128+lane]=gm;
  pooled[(size_t)g*128+64+lane]=mean;
}

// ---------------- final linear: [G,128] @ [128,256] + bias ----------------
__global__ __launch_bounds__(256) void out_kernel(const float* __restrict__ pooled,
    const float* __restrict__ Wout, const float* __restrict__ bout,
    float* __restrict__ out){
  __shared__ float sp[128];
  int g=blockIdx.x, d=threadIdx.x;
  if(d<128) sp[d]=pooled[(size_t)g*128+d];
  __syncthreads();
  float o=bout[d];
  for(int k=0;k<128;++k) o=fmaf(sp[k],Wout[k*DOUT+d],o);
  out[(size_t)g*DOUT+d]=o;
}

extern "C" void kernel_launch(void* const* d_in, const int* in_sizes, int n_in,
                              void* d_out, int out_size, void* d_ws, size_t ws_size,
                              hipStream_t stream){
  const float* x        =(const float*)d_in[0];
  const float* edge_attr=(const float*)d_in[1];
  const float* W0       =(const float*)d_in[2];
  const float* asrc0    =(const float*)d_in[3];
  const float* adst0    =(const float*)d_in[4];
  const float* We0      =(const float*)d_in[5];
  const float* ae0      =(const float*)d_in[6];
  const float* Wres0    =(const float*)d_in[7];
  const float* b0       =(const float*)d_in[8];
  const float* W        =(const float*)d_in[9];
  const float* asrc     =(const float*)d_in[10];
  const float* adst     =(const float*)d_in[11];
  const float* We       =(const float*)d_in[12];
  const float* ae       =(const float*)d_in[13];
  const float* Wres     =(const float*)d_in[14];
  const float* b        =(const float*)d_in[15];
  const float* Wout     =(const float*)d_in[16];
  const float* bout     =(const float*)d_in[17];
  const int* edge_index =(const int*)d_in[18];
  const int* batch_index=(const int*)d_in[19];
  const int* src=edge_index;
  const int* dst=edge_index+NE;

  // workspace carve (~49 MB, prec region reused by bufB)
  char* p=(char*)d_ws;
  auto take=[&](size_t bytes)->void*{ void* r=(void*)p; p+=(bytes+255)&~(size_t)255; return r; };
  int* rowptr  =(int*)take((size_t)(NN+1)*4);
  int* growptr =(int*)take((size_t)(NG+1)*4);
  int* bcnt    =(int*)take((size_t)256*4);
  int* bbase   =(int*)take((size_t)256*4);
  int* gcur    =(int*)take((size_t)256*4);
  int* src_csr =(int*)take((size_t)NE*4);
  float* as_   =(float*)take((size_t)NN*4);
  float* ad_   =(float*)take((size_t)NN*4);
  ushort* edch =(ushort*)take((size_t)NE*4*2);    // 4 layers x NE half, CSR order (SoA)
  __half* hW16 =(__half*)take((size_t)NN*C*2);
  float* bufA  =(float*)take((size_t)NN*C*4);
  // region: prec (16MB, dead after build) -> later bufB (12.8MB)
  uint4* prec  =(uint4*)take((size_t)NE*16);
  float* bufB  =(float*)prec;
  float* pooled=(float*)take((size_t)NG*128*4);
  (void)ws_size; (void)in_sizes; (void)n_in; (void)out_size;

  hipMemsetAsync(bcnt,0,(size_t)256*4,stream);
  hist196_kernel<<<1024,256,0,stream>>>(dst,bcnt);
  scan196_kernel<<<1,256,0,stream>>>(bcnt,bbase,gcur);
  grow_kernel<<<(NN+255)/256,256,0,stream>>>(batch_index,growptr);

  part_kernel<<<(NE+PA_EDGES-1)/PA_EDGES,256,0,stream>>>(dst,src,edge_attr,
      We0,ae0,We,ae,gcur,prec);
  build_kernel<<<NBIN,256,0,stream>>>(prec,bbase,rowptr,src_csr,edch);

  const int nblkF=(NN+63)/64;      // 782
  const int nblkA=NN/8;            // 6250 (NN%8==0)
  // layer 0 (F=30, sx stride 36)
  feat_kernel<FIN0,36><<<nblkF,256,0,stream>>>(x,W0,Wres0,b0,asrc0,adst0,hW16,bufA,as_,ad_);
  agg_kernel<<<nblkA,256,0,stream>>>(rowptr,src_csr,edch,as_,ad_,hW16,bufA,1);
  // layers 1..3 (ping-pong; sx stride 68)
  float* bin=bufA; float* bo=bufB;
  for(int i=0;i<3;++i){
    feat_kernel<C,68><<<nblkF,256,0,stream>>>(bin,W+(size_t)i*C*C,Wres+(size_t)i*C*C,
        b+(size_t)i*C,asrc+(size_t)i*C,adst+(size_t)i*C,hW16,bo,as_,ad_);
    agg_kernel<<<nblkA,256,0,stream>>>(rowptr,src_csr,edch+(size_t)(i+1)*NE,as_,ad_,hW16,bo,(i<2)?1:0);
    float* t=bin; bin=bo; bo=t;
  }
  pool_kernel<<<(NG+3)/4,256,0,stream>>>(bin,growptr,pooled);
  out_kernel<<<NG,256,0,stream>>>(pooled,Wout,bout,(float*)d_out);
}

// Round 11
// 307.688 us; speedup vs baseline: 2.6827x; 1.0157x over previous
//
#include <hip/hip_runtime.h>
#include <hip/hip_fp16.h>

// Problem constants (from reference)
#define NN 50000
#define NE 1000000
#define FIN0 30
#define C 64
#define ED 11
#define NG 1024
#define DOUT 256
#define NBIN 196            // ceil(NN/256)
#define PA_EDGES 1024       // edges per partition block (4/thread)

typedef unsigned long long ull;

// ---------------- bin histogram (196 bins, LDS-privatized) ----------------
__global__ __launch_bounds__(256) void hist196_kernel(const int* __restrict__ dst,
    int* __restrict__ bcnt){
  __shared__ int h[256];
  int t=threadIdx.x;
  h[t]=0;
  __syncthreads();
  for(int i=blockIdx.x*256+t;i<NE;i+=gridDim.x*256)
    atomicAdd(&h[dst[i]>>8],1);
  __syncthreads();
  if(h[t]) atomicAdd(&bcnt[t],h[t]);
}

// single block: exclusive scan of 256 bin counts -> bbase (197 used) + gcur copy
__global__ __launch_bounds__(256) void scan196_kernel(const int* __restrict__ bcnt,
    int* __restrict__ bbase, int* __restrict__ gcur){
  __shared__ int p[256];
  int t=threadIdx.x;
  int v=bcnt[t];
  p[t]=v; __syncthreads();
  #pragma unroll
  for(int off=1;off<256;off<<=1){
    int u=(t>=off)?p[t-off]:0;
    __syncthreads(); p[t]+=u; __syncthreads();
  }
  int ex=p[t]-v;
  if(t<=NBIN) bbase[t]=ex;
  if(t<NBIN)  gcur[t]=ex;
}

// growptr from SORTED batch_index (boundary detection; handles empty graphs)
__global__ __launch_bounds__(256) void grow_kernel(const int* __restrict__ batch,
    int* __restrict__ growptr){
  int i=blockIdx.x*256+threadIdx.x;
  if(i>=NN) return;
  int bi=batch[i];
  int bp=(i==0)?-1:batch[i-1];
  for(int g=bp+1;g<=bi;++g) growptr[g]=i;
  if(i==NN-1){ for(int g=bi+1;g<=NG;++g) growptr[g]=NN; }
}

// ---------------- Pass A v3: low-barrier counting-sort partition ----------------
// 4 edges/thread in registers; wave-shfl scan (2 barriers); direct edge_attr reads.
__global__ __launch_bounds__(256) void part_kernel(const int* __restrict__ dst,
    const int* __restrict__ src, const float* __restrict__ edge_attr,
    const float* __restrict__ We0, const float* __restrict__ ae0,
    const float* __restrict__ We,  const float* __restrict__ ae,
    int* __restrict__ gcur, uint4* __restrict__ prec){
  __shared__ uint4 lrec[PA_EDGES];           // 16KB
  __shared__ float sw[4][ED];
  __shared__ int hist[256], sc[256], lofs[256], bb[256];
  __shared__ int wsum[4];
  int t=threadIdx.x;
  hist[t]=0;
  if(t<4*ED){
    int l=t/ED, j=t%ED;
    const float* wp=(l==0)? (We0+(size_t)j*C) : (We+((size_t)(l-1)*ED+j)*C);
    const float* ap=(l==0)? ae0 : (ae+(size_t)(l-1)*C);
    float s=0.f;
    for(int c=0;c<C;++c) s+=wp[c]*ap[c];
    sw[l][j]=s;
  }
  __syncthreads();
  size_t e0=(size_t)blockIdx.x*PA_EDGES;
  int cnt=(int)min((size_t)PA_EDGES,(size_t)NE-e0);
  int dreg[4], sreg[4];
  #pragma unroll
  for(int r=0;r<4;++r){
    int i=r*256+t;
    if(i<cnt){
      dreg[r]=dst[e0+i]; sreg[r]=src[e0+i];
      atomicAdd(&hist[dreg[r]>>8],1);
    } else dreg[r]=-1;
  }
  __syncthreads();
  // wave-level scan of 256 bins (2 barriers total)
  int v=hist[t];
  int inc=v;
  #pragma unroll
  for(int off=1;off<64;off<<=1){
    int u=__shfl_up(inc,off,64);
    if((t&63)>=off) inc+=u;
  }
  if((t&63)==63) wsum[t>>6]=inc;
  __syncthreads();
  int woff=0;
  int myw=t>>6;
  #pragma unroll
  for(int k=0;k<3;++k) if(k<myw) woff+=wsum[k];
  int ex=woff+inc-v;
  sc[t]=ex;
  lofs[t]=ex;
  bb[t]=(v>0)?atomicAdd(&gcur[t],v):0;
  __syncthreads();
  // place records bin-sorted into LDS (ed dots computed from direct reads)
  #pragma unroll
  for(int r=0;r<4;++r){
    int i=r*256+t;
    if(i<cnt){
      const float* ea=edge_attr+(e0+i)*(size_t)ED;
      float d0=0,d1=0,d2=0,d3=0;
      #pragma unroll
      for(int j=0;j<ED;++j){
        float ev=ea[j];
        d0=fmaf(ev,sw[0][j],d0);
        d1=fmaf(ev,sw[1][j],d1);
        d2=fmaf(ev,sw[2][j],d2);
        d3=fmaf(ev,sw[3][j],d3);
      }
      uint4 rec;
      rec.x=(unsigned)dreg[r]; rec.y=(unsigned)sreg[r];
      rec.z=(unsigned)__half_as_ushort(__float2half(d0))
           |((unsigned)__half_as_ushort(__float2half(d1))<<16);
      rec.w=(unsigned)__half_as_ushort(__float2half(d2))
           |((unsigned)__half_as_ushort(__float2half(d3))<<16);
      int slot=atomicAdd(&lofs[dreg[r]>>8],1);
      lrec[slot]=rec;
    }
  }
  __syncthreads();
  // coalesced flush (bin recomputed from record)
  for(int i=t;i<cnt;i+=256){
    uint4 rec=lrec[i];
    int b=(int)(rec.x>>8);
    int g=bb[b]+i-sc[b];
    prec[g]=rec;
  }
}

// ---------------- Pass B: bin -> exact CSR slots; also emits rowptr ----------------
__global__ __launch_bounds__(256) void build_kernel(const uint4* __restrict__ prec,
    const int* __restrict__ bbase,
    int* __restrict__ rowptr, int* __restrict__ src_csr, ushort* __restrict__ edch){
  __shared__ int cnt[256], p[256], cur[256];
  int t=threadIdx.x, b=blockIdx.x;
  int n0=b<<8;
  cnt[t]=0;
  __syncthreads();
  int beg=bbase[b], endd=bbase[b+1];
  for(int j=beg+t;j<endd;j+=256)
    atomicAdd(&cnt[(int)prec[j].x-n0],1);
  __syncthreads();
  int v=cnt[t];
  p[t]=v; __syncthreads();
  #pragma unroll
  for(int off=1;off<256;off<<=1){
    int u=(t>=off)?p[t-off]:0;
    __syncthreads(); p[t]+=u; __syncthreads();
  }
  int ex=p[t]-v;
  cur[t]=beg+ex;
  if(n0+t<NN) rowptr[n0+t]=beg+ex;
  if(b==0&&t==0) rowptr[NN]=NE;
  __syncthreads();
  for(int j=beg+t;j<endd;j+=256){
    uint4 r=prec[j];
    int d=(int)r.x, s=(int)r.y;
    int pos=atomicAdd(&cur[d-n0],1);
    src_csr[pos]=s;
    edch[pos]                =(ushort)(r.z&0xffffu);
    edch[(size_t)NE+pos]     =(ushort)(r.z>>16);
    edch[2*(size_t)NE+pos]   =(ushort)(r.w&0xffffu);
    edch[3*(size_t)NE+pos]   =(ushort)(r.w>>16);
  }
}

// ---------------- per-layer features: register-blocked vector GEMM ----------------
template<int FIN, int SXS>
__global__ __launch_bounds__(256) void feat_kernel(const float* __restrict__ in,
    const float* __restrict__ W, const float* __restrict__ Wres,
    const float* __restrict__ bvec, const float* __restrict__ av_src,
    const float* __restrict__ av_dst,
    __half* __restrict__ hW16, float* __restrict__ outb,
    float* __restrict__ as_, float* __restrict__ ad_){
  __shared__ float sW[FIN*C], sR[FIN*C];
  __shared__ float sx[64*SXS];
  __shared__ float sb[C], ss[C], sd[C];
  int tid=threadIdx.x;
  if(tid<C){ sb[tid]=bvec[tid]; ss[tid]=av_src[tid]; sd[tid]=av_dst[tid]; }
  for(int i=tid;i<FIN*C;i+=256){ sW[i]=W[i]; sR[i]=Wres[i]; }
  int nbase=blockIdx.x*64;
  int nvalid=min(64,NN-nbase);
  if constexpr (FIN==64){
    const float4* in4=(const float4*)(in+(size_t)nbase*64);
    for(int i=tid;i<1024;i+=256){
      int n=i>>4, k=(i&15)*4;
      float4 v=(n<nvalid)?in4[i]:make_float4(0.f,0.f,0.f,0.f);
      *(float4*)&sx[n*SXS+k]=v;
    }
  } else {
    for(int i=tid;i<64*FIN;i+=256){
      int n=i/FIN, k=i-n*FIN;
      sx[n*SXS+k]=(n<nvalid)?in[(size_t)(nbase+n)*FIN+k]:0.f;
    }
  }
  __syncthreads();
  int w=tid>>6, lane=tid&63;
  int ng=lane>>4, cl=lane&15;
  int n0=w*16+ng*4;
  int c0=cl*4;
  float hw[4][4]={}, hr[4][4]={};
  const float* sxp=&sx[n0*SXS];
  #pragma unroll 2
  for(int k=0;k<FIN;k+=2){
    float4 wv0=*(const float4*)&sW[k*C+c0];
    float4 rv0=*(const float4*)&sR[k*C+c0];
    float4 wv1=*(const float4*)&sW[(k+1)*C+c0];
    float4 rv1=*(const float4*)&sR[(k+1)*C+c0];
    float2 x0=*(const float2*)&sxp[k];
    float2 x1=*(const float2*)&sxp[SXS+k];
    float2 x2=*(const float2*)&sxp[2*SXS+k];
    float2 x3=*(const float2*)&sxp[3*SXS+k];
    float xa[4]={x0.x,x1.x,x2.x,x3.x};
    float xb[4]={x0.y,x1.y,x2.y,x3.y};
    #pragma unroll
    for(int r=0;r<4;++r){
      hw[r][0]=fmaf(xa[r],wv0.x,hw[r][0]);
      hw[r][1]=fmaf(xa[r],wv0.y,hw[r][1]);
      hw[r][2]=fmaf(xa[r],wv0.z,hw[r][2]);
      hw[r][3]=fmaf(xa[r],wv0.w,hw[r][3]);
      hr[r][0]=fmaf(xa[r],rv0.x,hr[r][0]);
      hr[r][1]=fmaf(xa[r],rv0.y,hr[r][1]);
      hr[r][2]=fmaf(xa[r],rv0.z,hr[r][2]);
      hr[r][3]=fmaf(xa[r],rv0.w,hr[r][3]);
      hw[r][0]=fmaf(xb[r],wv1.x,hw[r][0]);
      hw[r][1]=fmaf(xb[r],wv1.y,hw[r][1]);
      hw[r][2]=fmaf(xb[r],wv1.z,hw[r][2]);
      hw[r][3]=fmaf(xb[r],wv1.w,hw[r][3]);
      hr[r][0]=fmaf(xb[r],rv1.x,hr[r][0]);
      hr[r][1]=fmaf(xb[r],rv1.y,hr[r][1]);
      hr[r][2]=fmaf(xb[r],rv1.z,hr[r][2]);
      hr[r][3]=fmaf(xb[r],rv1.w,hr[r][3]);
    }
  }
  float s0=ss[c0], s1=ss[c0+1], s2=ss[c0+2], s3=ss[c0+3];
  float d0=sd[c0], d1=sd[c0+1], d2=sd[c0+2], d3=sd[c0+3];
  float b0v=sb[c0], b1v=sb[c0+1], b2v=sb[c0+2], b3v=sb[c0+3];
  #pragma unroll
  for(int r=0;r<4;++r){
    int n=n0+r;
    float ps=hw[r][0]*s0+hw[r][1]*s1+hw[r][2]*s2+hw[r][3]*s3;
    float pd=hw[r][0]*d0+hw[r][1]*d1+hw[r][2]*d2+hw[r][3]*d3;
    #pragma unroll
    for(int off=1;off<16;off<<=1){ ps+=__shfl_xor(ps,off,64); pd+=__shfl_xor(pd,off,64); }
    if(n<nvalid){
      size_t gn=(size_t)(nbase+n);
      ushort4 hv;
      hv.x=__half_as_ushort(__float2half(hw[r][0]));
      hv.y=__half_as_ushort(__float2half(hw[r][1]));
      hv.z=__half_as_ushort(__float2half(hw[r][2]));
      hv.w=__half_as_ushort(__float2half(hw[r][3]));
      *(ushort4*)&hW16[gn*C+c0]=hv;
      float4 ov;
      ov.x=hr[r][0]+b0v; ov.y=hr[r][1]+b1v; ov.z=hr[r][2]+b2v; ov.w=hr[r][3]+b3v;
      *(float4*)&outb[gn*C+c0]=ov;
      if(cl==0){ as_[gn]=ps; ad_[gn]=pd; }
    }
  }
}

// ------- fused alpha + softmax aggregation -------
__device__ __forceinline__ void acc8(float* a, float at, uint4 u){
  __half2 h0=*(__half2*)&u.x, h1=*(__half2*)&u.y, h2=*(__half2*)&u.z, h3=*(__half2*)&u.w;
  float2 f0=__half22float2(h0), f1=__half22float2(h1);
  float2 f2=__half22float2(h2), f3=__half22float2(h3);
  a[0]=fmaf(at,f0.x,a[0]); a[1]=fmaf(at,f0.y,a[1]);
  a[2]=fmaf(at,f1.x,a[2]); a[3]=fmaf(at,f1.y,a[3]);
  a[4]=fmaf(at,f2.x,a[4]); a[5]=fmaf(at,f2.y,a[5]);
  a[6]=fmaf(at,f3.x,a[6]); a[7]=fmaf(at,f3.y,a[7]);
}

// 2 nodes per wave (32-lane halves) when both deg<=32 (~99.4% of waves).
__global__ __launch_bounds__(256) void agg_kernel(const int* __restrict__ rowptr,
    const int* __restrict__ src_csr, const ushort* __restrict__ edc_l,
    const float* __restrict__ as_, const float* __restrict__ ad_,
    const __half* __restrict__ hW16, float* __restrict__ outb, int relu){
  __shared__ float2 sws[4][64];
  int w=threadIdx.x>>6, lane=threadIdx.x&63;
  int half=lane>>5, hl=lane&31;
  int n0=blockIdx.x*8+w*2;            // NN%8==0: always in range
  int nidx=n0+half;
  int beg=rowptr[nidx], end=rowptr[nidx+1];
  int deg=end-beg;
  const uint4* hw4=(const uint4*)hW16;   // row = 8 uint4 (8 halves each)

  if(__all(deg<=32)){
    float ad_n=ad_[nidx];
    int j=beg+hl;
    float al=-INFINITY; int sl=0;
    if(hl<deg){
      sl=src_csr[j];
      float a=as_[sl]+ad_n+__half2float(__ushort_as_half(edc_l[j]));
      al=(a>0.f)?a:0.2f*a;               // leaky_relu 0.2
    }
    float mn=al;
    #pragma unroll
    for(int off=16;off;off>>=1) mn=fmaxf(mn,__shfl_xor(mn,off,64));
    float wl=(hl<deg)?__expf(al-mn):0.f;
    float s=wl;
    #pragma unroll
    for(int off=16;off;off>>=1) s+=__shfl_xor(s,off,64);
    float2 pr; pr.x=wl; pr.y=__int_as_float(sl);
    sws[w][lane]=pr;                     // wave-private: no barrier
    int g=hl>>3, gl=hl&7;
    float acc[8]={0.f,0.f,0.f,0.f,0.f,0.f,0.f,0.f};
    int base=half*32;
    int t=g;
    for(; t+4<deg; t+=8){
      float2 r0=sws[w][base+t], r1=sws[w][base+t+4];
      uint4 u0=hw4[(size_t)__float_as_int(r0.y)*8+gl];
      uint4 u1=hw4[(size_t)__float_as_int(r1.y)*8+gl];
      acc8(acc,r0.x,u0);
      acc8(acc,r1.x,u1);
    }
    if(t<deg){
      float2 r=sws[w][base+t];
      uint4 u=hw4[(size_t)__float_as_int(r.y)*8+gl];
      acc8(acc,r.x,u);
    }
    #pragma unroll
    for(int off=8;off<=16;off<<=1){
      #pragma unroll
      for(int i=0;i<8;++i) acc[i]+=__shfl_xor(acc[i],off,64);
    }
    if(hl<8){
      float denom=s+1e-16f;
      size_t o0=(size_t)nidx*C+hl*8;
      float4 oa=*(float4*)&outb[o0];
      float4 ob=*(float4*)&outb[o0+4];
      float4 va,vb;
      va.x=acc[0]/denom+oa.x; va.y=acc[1]/denom+oa.y;
      va.z=acc[2]/denom+oa.z; va.w=acc[3]/denom+oa.w;
      vb.x=acc[4]/denom+ob.x; vb.y=acc[5]/denom+ob.y;
      vb.z=acc[6]/denom+ob.z; vb.w=acc[7]/denom+ob.w;
      if(relu){
        va.x=(va.x>0.f)?va.x:0.01f*va.x; va.y=(va.y>0.f)?va.y:0.01f*va.y;
        va.z=(va.z>0.f)?va.z:0.01f*va.z; va.w=(va.w>0.f)?va.w:0.01f*va.w;
        vb.x=(vb.x>0.f)?vb.x:0.01f*vb.x; vb.y=(vb.y>0.f)?vb.y:0.01f*vb.y;
        vb.z=(vb.z>0.f)?vb.z:0.01f*vb.z; vb.w=(vb.w>0.f)?vb.w:0.01f*vb.w;
      }
      *(float4*)&outb[o0]=va;
      *(float4*)&outb[o0+4]=vb;
    }
    return;
  }

  // ---- fallback: whole wave per node, 2 nodes sequentially (rare) ----
  for(int h=0;h<2;++h){
    int m=n0+h;
    int bh=__shfl(beg,h*32,64);
    int dh=__shfl(deg,h*32,64);
    float ad_n=ad_[m];
    int g2=lane>>3, gl2=lane&7;
    float s=0.f;
    float acc[8]={0.f,0.f,0.f,0.f,0.f,0.f,0.f,0.f};
    if(dh<=64){
      int j=bh+lane;
      float al=-INFINITY; int sl=0;
      if(lane<dh){
        sl=src_csr[j];
        float a=as_[sl]+ad_n+__half2float(__ushort_as_half(edc_l[j]));
        al=(a>0.f)?a:0.2f*a;
      }
      float mn=al;
      #pragma unroll
      for(int off=32;off;off>>=1) mn=fmaxf(mn,__shfl_xor(mn,off,64));
      float wl=(lane<dh)?__expf(al-mn):0.f;
      s=wl;
      #pragma unroll
      for(int off=32;off;off>>=1) s+=__shfl_xor(s,off,64);
      float2 pr; pr.x=wl; pr.y=__int_as_float(sl);
      sws[w][lane]=pr;
      int t=g2;
      for(; t+8<dh; t+=16){
        float2 r0=sws[w][t], r1=sws[w][t+8];
        uint4 u0=hw4[(size_t)__float_as_int(r0.y)*8+gl2];
        uint4 u1=hw4[(size_t)__float_as_int(r1.y)*8+gl2];
        acc8(acc,r0.x,u0);
        acc8(acc,r1.x,u1);
      }
      if(t<dh){
        float2 r=sws[w][t];
        uint4 u=hw4[(size_t)__float_as_int(r.y)*8+gl2];
        acc8(acc,r.x,u);
      }
    } else {
      float m_=-INFINITY;
      for(int base=bh;base<bh+dh;base+=64){
        int j=base+lane;
        float al=-INFINITY; int sl=0;
        if(j<bh+dh){
          sl=src_csr[j];
          float a=as_[sl]+ad_n+__half2float(__ushort_as_half(edc_l[j]));
          al=(a>0.f)?a:0.2f*a;
        }
        float cm=al;
        #pragma unroll
        for(int off=32;off;off>>=1) cm=fmaxf(cm,__shfl_xor(cm,off,64));
        float mn=fmaxf(m_,cm);
        float scale=(m_==-INFINITY)?0.f:__expf(m_-mn);
        s*=scale;
        #pragma unroll
        for(int i=0;i<8;++i) acc[i]*=scale;
        float wl=(j<bh+dh)?__expf(al-mn):0.f;
        float cs=wl;
        #pragma unroll
        for(int off=32;off;off>>=1) cs+=__shfl_xor(cs,off,64);
        s+=cs; m_=mn;
        float2 pr; pr.x=wl; pr.y=__int_as_float(sl);
        sws[w][lane]=pr;
        int cnt=min(64,bh+dh-base);
        int t=g2;
        for(; t+8<cnt; t+=16){
          float2 r0=sws[w][t], r1=sws[w][t+8];
          uint4 u0=hw4[(size_t)__float_as_int(r0.y)*8+gl2];
          uint4 u1=hw4[(size_t)__float_as_int(r1.y)*8+gl2];
          acc8(acc,r0.x,u0);
          acc8(acc,r1.x,u1);
        }
        if(t<cnt){
          float2 r=sws[w][t];
          uint4 u=hw4[(size_t)__float_as_int(r.y)*8+gl2];
          acc8(acc,r.x,u);
        }
      }
    }
    #pragma unroll
    for(int off=8;off<64;off<<=1){
      #pragma unroll
      for(int i=0;i<8;++i) acc[i]+=__shfl_xor(acc[i],off,64);
    }
    if(g2==0){
      float denom=s+1e-16f;
      size_t o0=(size_t)m*C+gl2*8;
      float4 oa=*(float4*)&outb[o0];
      float4 ob=*(float4*)&outb[o0+4];
      float4 va,vb;
      va.x=acc[0]/denom+oa.x; va.y=acc[1]/denom+oa.y;
      va.z=acc[2]/denom+oa.z; va.w=acc[3]/denom+oa.w;
      vb.x=acc[4]/denom+ob.x; vb.y=acc[5]/denom+ob.y;
      vb.z=acc[6]/denom+ob.z; vb.w=acc[7]/denom+ob.w;
      if(relu){
        va.x=(va.x>0.f)?va.x:0.01f*va.x; va.y=(va.y>0.f)?va.y:0.01f*va.y;
        va.z=(va.z>0.f)?va.z:0.01f*va.z; va.w=(va.w>0.f)?va.w:0.01f*va.w;
        vb.x=(vb.x>0.f)?vb.x:0.01f*vb.x; vb.y=(vb.y>0.f)?vb.y:0.01f*vb.y;
        vb.z=(vb.z>0.f)?vb.z:0.01f*vb.z; vb.w=(vb.w>0.f)?vb.w:0.01f*vb.w;
      }
      *(float4*)&outb[o0]=va;
      *(float4*)&outb[o0+4]=vb;
    }
  }
}

// ---------------- pooling (max + mean per graph) ----------------
__global__ __launch_bounds__(256) void pool_kernel(const float* __restrict__ h,
    const int* __restrict__ growptr, float* __restrict__ pooled){
  int w=threadIdx.x>>6, lane=threadIdx.x&63;
  int g=blockIdx.x*4+w;
  if(g>=NG) return;
  int beg=growptr[g], end=growptr[g+1];
  float mx=-INFINITY, sm=0.f;
  for(int n=beg;n<end;++n){ float v=h[(size_t)n*C+lane]; mx=fmaxf(mx,v); sm+=v; }
  int cnt=end-beg;
  float gm=(cnt==0)?0.f:mx;              // isfinite fix for empty graphs
  float mean=sm/fmaxf((float)cnt,1.f);
  gm=(gm>0.f)?gm:0.01f*gm;               // leaky_relu 0.01 on pooled
  mean=(mean>0.f)?mean:0.01f*mean;
  pooled[(size_t)g*128+lane]=gm;
  pooled[(size_t)g*128+64+lane]=mean;
}

// ---------------- final linear: [G,128] @ [128,256] + bias ----------------
__global__ __launch_bounds__(256) void out_kernel(const float* __restrict__ pooled,
    const float* __restrict__ Wout, const float* __restrict__ bout,
    float* __restrict__ out){
  __shared__ float sp[128];
  int g=blockIdx.x, d=threadIdx.x;
  if(d<128) sp[d]=pooled[(size_t)g*128+d];
  __syncthreads();
  float o=bout[d];
  for(int k=0;k<128;++k) o=fmaf(sp[k],Wout[k*DOUT+d],o);
  out[(size_t)g*DOUT+d]=o;
}

extern "C" void kernel_launch(void* const* d_in, const int* in_sizes, int n_in,
                              void* d_out, int out_size, void* d_ws, size_t ws_size,
                              hipStream_t stream){
  const float* x        =(const float*)d_in[0];
  const float* edge_attr=(const float*)d_in[1];
  const float* W0       =(const float*)d_in[2];
  const float* asrc0    =(const float*)d_in[3];
  const float* adst0    =(const float*)d_in[4];
  const float* We0      =(const float*)d_in[5];
  const float* ae0      =(const float*)d_in[6];
  const float* Wres0    =(const float*)d_in[7];
  const float* b0       =(const float*)d_in[8];
  const float* W        =(const float*)d_in[9];
  const float* asrc     =(const float*)d_in[10];
  const float* adst     =(const float*)d_in[11];
  const float* We       =(const float*)d_in[12];
  const float* ae       =(const float*)d_in[13];
  const float* Wres     =(const float*)d_in[14];
  const float* b        =(const float*)d_in[15];
  const float* Wout     =(const float*)d_in[16];
  const float* bout     =(const float*)d_in[17];
  const int* edge_index =(const int*)d_in[18];
  const int* batch_index=(const int*)d_in[19];
  const int* src=edge_index;
  const int* dst=edge_index+NE;

  // workspace carve (~49 MB, prec region reused by bufB)
  char* p=(char*)d_ws;
  auto take=[&](size_t bytes)->void*{ void* r=(void*)p; p+=(bytes+255)&~(size_t)255; return r; };
  int* rowptr  =(int*)take((size_t)(NN+1)*4);
  int* growptr =(int*)take((size_t)(NG+1)*4);
  int* bcnt    =(int*)take((size_t)256*4);
  int* bbase   =(int*)take((size_t)256*4);
  int* gcur    =(int*)take((size_t)256*4);
  int* src_csr =(int*)take((size_t)NE*4);
  float* as_   =(float*)take((size_t)NN*4);
  float* ad_   =(float*)take((size_t)NN*4);
  ushort* edch =(ushort*)take((size_t)NE*4*2);    // 4 layers x NE half, CSR order (SoA)
  __half* hW16 =(__half*)take((size_t)NN*C*2);
  float* bufA  =(float*)take((size_t)NN*C*4);
  // region: prec (16MB, dead after build) -> later bufB (12.8MB)
  uint4* prec  =(uint4*)take((size_t)NE*16);
  float* bufB  =(float*)prec;
  float* pooled=(float*)take((size_t)NG*128*4);
  (void)ws_size; (void)in_sizes; (void)n_in; (void)out_size;

  hipMemsetAsync(bcnt,0,(size_t)256*4,stream);
  hist196_kernel<<<1024,256,0,stream>>>(dst,bcnt);
  scan196_kernel<<<1,256,0,stream>>>(bcnt,bbase,gcur);
  grow_kernel<<<(NN+255)/256,256,0,stream>>>(batch_index,growptr);

  part_kernel<<<(NE+PA_EDGES-1)/PA_EDGES,256,0,stream>>>(dst,src,edge_attr,
      We0,ae0,We,ae,gcur,prec);
  build_kernel<<<NBIN,256,0,stream>>>(prec,bbase,rowptr,src_csr,edch);

  const int nblkF=(NN+63)/64;      // 782
  const int nblkA=NN/8;            // 6250 (NN%8==0)
  // layer 0 (F=30, sx stride 36)
  feat_kernel<FIN0,36><<<nblkF,256,0,stream>>>(x,W0,Wres0,b0,asrc0,adst0,hW16,bufA,as_,ad_);
  agg_kernel<<<nblkA,256,0,stream>>>(rowptr,src_csr,edch,as_,ad_,hW16,bufA,1);
  // layers 1..3 (ping-pong; sx stride 68)
  float* bin=bufA; float* bo=bufB;
  for(int i=0;i<3;++i){
    feat_kernel<C,68><<<nblkF,256,0,stream>>>(bin,W+(size_t)i*C*C,Wres+(size_t)i*C*C,
        b+(size_t)i*C,asrc+(size_t)i*C,adst+(size_t)i*C,hW16,bo,as_,ad_);
    agg_kernel<<<nblkA,256,0,stream>>>(rowptr,src_csr,edch+(size_t)(i+1)*NE,as_,ad_,hW16,bo,(i<2)?1:0);
    float* t=bin; bin=bo; bo=t;
  }
  pool_kernel<<<(NG+3)/4,256,0,stream>>>(bin,growptr,pooled);
  out_kernel<<<NG,256,0,stream>>>(pooled,Wout,bout,(float*)d_out);
}